// Round 9
// baseline (430.103 us; speedup 1.0000x reference)
//
#include <hip/hip_runtime.h>
#include <cstdint>
#include <cstddef>

#define NSEG 32769      // N_NODES + 1 (row 0 is the zero row)
#define NNODES 32768
#define NE 262144
#define PSZ ((size_t)NSEG * 64)   // one tf plane

using f4 = float4;

// ---------------- static device scratch ----------------
// planar planes 0..2 (final output cols, written by iter2 gemm), plane 3 = h_orig
__device__ ushort g_tfp[4 * PSZ];
__device__ uint   g_pkA[PSZ];      // (out0 | h)  after iter0 gemm
__device__ uint   g_pk01[PSZ];     // (out0 | out1) after iter1 gemm
__device__ ushort g_msg0h[(size_t)NE * 64];       // bf16 row-major
__device__ ushort g_msumh[(size_t)NSEG * 192];    // bf16 row-major (K width 192)
__device__ float  g_qe[NE];
__device__ float  g_q[NSEG];
__device__ float  g_p0[3][NSEG];
__device__ float  g_p1[3][NSEG];
__device__ float  g_w2[3][256];                   // w2 = W @ a2 in [0,d); c = a2.b at [255]
__device__ float  g_wq10[10];                     // W_dist @ w2_0
__device__ float  g_cq;                           // b_dist.w2_0 + c0
__device__ int    g_counts[NSEG];
__device__ int    g_excl[NSEG];
__device__ int    g_bsum[1024];
__device__ int    g_rowptr[NSEG + 1];
__device__ int    g_cur[NSEG];
__device__ int    g_csr[NE];
__device__ int    g_bc[128];       // size-bucket hist
__device__ int    g_bstart[128];
__device__ int    g_bcur[128];
__device__ int    g_sorder[NSEG];  // segments sorted by size

#define WREDUCE(x) { x += __shfl_xor(x, 32); x += __shfl_xor(x, 16); \
                     x += __shfl_xor(x, 8);  x += __shfl_xor(x, 4);  \
                     x += __shfl_xor(x, 2);  x += __shfl_xor(x, 1); }
#define WREDMAX(x) { x = fmaxf(x, __shfl_xor(x, 32)); x = fmaxf(x, __shfl_xor(x, 16)); \
                     x = fmaxf(x, __shfl_xor(x, 8));  x = fmaxf(x, __shfl_xor(x, 4));  \
                     x = fmaxf(x, __shfl_xor(x, 2));  x = fmaxf(x, __shfl_xor(x, 1)); }

__device__ __forceinline__ ushort f2bf(float x) {
    uint u = __float_as_uint(x);
    u += 0x7FFF + ((u >> 16) & 1);
    return (ushort)(u >> 16);
}
__device__ __forceinline__ float bfs(ushort u) { return __uint_as_float(((uint)u) << 16); }
__device__ __forceinline__ float bflo(uint u) { return __uint_as_float(u << 16); }
__device__ __forceinline__ float bfhi(uint u) { return __uint_as_float(u & 0xFFFF0000u); }

// ---------------- init: zero counts/cur/buckets ----------------
__global__ void k_init() {
    int i = blockIdx.x * 256 + threadIdx.x;
    if (i < NSEG) { g_counts[i] = 0; g_cur[i] = 0; }
    if (i < 128) { g_bc[i] = 0; g_bcur[i] = 0; }
}

// -------- h_orig (bf16, plane 3) = node_feats @ W_emb + b_emb ; fused p0/p1 --------
__global__ void k_emb(const float* __restrict__ node_feats,
                      const float* __restrict__ W, const float* __restrict__ b,
                      const float* __restrict__ a0, const float* __restrict__ a1,
                      const float* __restrict__ a2) {
    __shared__ float Ws[9 * 64];
    __shared__ float fs[4][9];
    int tid = threadIdx.x;
    for (int i = tid; i < 576; i += 256) Ws[i] = W[i];
    int r0 = blockIdx.x * 4;
    if (tid < 36) {
        int r = r0 + tid / 9, k = tid % 9;
        float v = 0.f;
        if (r >= 1 && r <= NNODES) v = node_feats[(size_t)(r - 1) * 9 + k];
        fs[tid / 9][k] = v;
    }
    __syncthreads();
    int r = tid >> 6, j = tid & 63;
    int row = r0 + r;
    if (row >= NSEG) return;
    float acc = b[j];
#pragma unroll
    for (int k = 0; k < 9; k++) acc += fs[r][k] * Ws[k * 64 + j];
    float v = (row == 0) ? 0.f : acc;
    g_tfp[3 * PSZ + (size_t)row * 64 + j] = f2bf(v);
    const float* A[3] = {a0, a1, a2};
#pragma unroll
    for (int i = 0; i < 3; i++) {
        float d0 = v * A[i][j];
        WREDUCE(d0);
        if (j == 0) g_p0[i][row] = d0;
        float d1 = v * A[i][64 + j];
        WREDUCE(d1);
        if (j == 0) g_p1[i][row] = d1;
    }
}

// ---------------- per-iter prep: w2 = W @ a2 ; c = a2.b (one block per iter) ----------------
__global__ void k_prep_all(const float* __restrict__ W0, const float* __restrict__ W1,
                           const float* __restrict__ W2, const float* __restrict__ a0,
                           const float* __restrict__ a1, const float* __restrict__ a2,
                           const float* __restrict__ b0, const float* __restrict__ b1,
                           const float* __restrict__ b2) {
    int it = blockIdx.x;
    const float* W = it == 0 ? W0 : (it == 1 ? W1 : W2);
    const float* a = it == 0 ? a0 : (it == 1 ? a1 : a2);
    const float* bias = it == 0 ? b0 : (it == 1 ? b1 : b2);
    int d = 64 * (it + 1);
    int k = threadIdx.x;
    if (k < d) {
        float s = 0.f;
        for (int j = 0; j < d; j++) s += W[(size_t)k * d + j] * a[128 + j];
        g_w2[it][k] = s;
    } else if (k == 255) {
        float c = 0.f;
        for (int j = 0; j < d; j++) c += a[128 + j] * bias[j];
        g_w2[it][255] = c;
    }
}

// ---------------- prep2: wq10 = W_dist @ w2_0 ; cq = b_dist.w2_0 + c0 ----------------
__global__ void k_prep2(const float* __restrict__ Wd, const float* __restrict__ bd) {
    int k = threadIdx.x;
    if (k < 10) {
        float s = 0.f;
        for (int j = 0; j < 64; j++) s += Wd[(size_t)k * 64 + j] * g_w2[0][j];
        g_wq10[k] = s;
    } else if (k == 63) {
        float s = 0.f;
        for (int j = 0; j < 64; j++) s += bd[j] * g_w2[0][j];
        g_cq = s + g_w2[0][255];
    }
}

// -------- msg0 (bf16) = [fdg | rij] @ W_dist + b_dist ; qe = x.wq10 + cq --------
__global__ __launch_bounds__(256) void k_msg0(const float* __restrict__ fdg,
                                              const float* __restrict__ rij,
                                              const float* __restrict__ W,
                                              const float* __restrict__ b) {
    __shared__ float Ws[10 * 64];
    __shared__ float bs[64];
    __shared__ float fs[64][10];
    int tid = threadIdx.x;
    for (int i = tid; i < 640; i += 256) Ws[i] = W[i];
    if (tid < 64) bs[tid] = b[tid];
    int e0 = blockIdx.x * 64;
    for (int i = tid; i < 576; i += 256) fs[i / 9][i % 9] = fdg[(size_t)e0 * 9 + i];
    if (tid < 64) fs[tid][9] = rij[e0 + tid];
    __syncthreads();
    int j = tid & 63;
#pragma unroll 4
    for (int p = 0; p < 16; p++) {
        int r = p * 4 + (tid >> 6);
        int e = e0 + r;
        float acc = bs[j];
#pragma unroll
        for (int k = 0; k < 10; k++) acc += fs[r][k] * Ws[k * 64 + j];
        g_msg0h[(size_t)e * 64 + j] = f2bf(acc);
        if (j == 0) {
            float q = g_cq;
#pragma unroll
            for (int k = 0; k < 10; k++) q += fs[r][k] * g_wq10[k];
            g_qe[e] = q;
        }
    }
}

// ---------------- CSR build over b_scope ----------------
__global__ void k_hist(const int* __restrict__ bs) {
    int e = blockIdx.x * 256 + threadIdx.x;
    if (e < NE) atomicAdd(&g_counts[bs[e]], 1);
}

__global__ void k_scan1() {
    __shared__ int s[256];
    int t = threadIdx.x, i = blockIdx.x * 256 + t;
    int v = (i < NSEG) ? g_counts[i] : 0;
    s[t] = v; __syncthreads();
    for (int off = 1; off < 256; off <<= 1) {
        int tmp = (t >= off) ? s[t - off] : 0;
        __syncthreads();
        s[t] += tmp;
        __syncthreads();
    }
    if (i < NSEG) g_excl[i] = s[t] - v;
    if (t == 255) g_bsum[blockIdx.x] = s[255];
}

__global__ void k_scan2(int nb) {
    __shared__ int s[256];
    int t = threadIdx.x;
    int v = (t < nb) ? g_bsum[t] : 0;
    s[t] = v; __syncthreads();
    for (int off = 1; off < 256; off <<= 1) {
        int tmp = (t >= off) ? s[t - off] : 0;
        __syncthreads();
        s[t] += tmp;
        __syncthreads();
    }
    if (t < nb) g_bsum[t] = s[t] - v;   // exclusive
}

__global__ void k_scan3() {
    int i = blockIdx.x * 256 + threadIdx.x;
    if (i < NSEG) g_rowptr[i] = g_excl[i] + g_bsum[i >> 8];
    if (i == NSEG) g_rowptr[NSEG] = NE;
}

__global__ void k_scatter(const int* __restrict__ bs) {
    int e = blockIdx.x * 256 + threadIdx.x;
    if (e < NE) {
        int seg = bs[e];
        int pos = g_rowptr[seg] + atomicAdd(&g_cur[seg], 1);
        g_csr[pos] = e;
    }
}

// ---------------- size-sorted segment order (counting sort by cnt) ----------------
__global__ void k_bhist() {
    __shared__ int h[128];
    int tid = threadIdx.x;
    if (tid < 128) h[tid] = 0;
    __syncthreads();
    int seg = blockIdx.x * 256 + tid;
    if (seg < NSEG) {
        int cnt = g_rowptr[seg + 1] - g_rowptr[seg];
        atomicAdd(&h[cnt > 127 ? 127 : cnt], 1);
    }
    __syncthreads();
    if (tid < 128 && h[tid]) atomicAdd(&g_bc[tid], h[tid]);
}

__global__ void k_bscan() {
    __shared__ int s[128];
    int t = threadIdx.x;
    int v = g_bc[t];
    s[t] = v; __syncthreads();
    for (int off = 1; off < 128; off <<= 1) {
        int tmp = (t >= off) ? s[t - off] : 0;
        __syncthreads();
        s[t] += tmp;
        __syncthreads();
    }
    g_bstart[t] = s[t] - v;
}

__global__ void k_bscatter() {
    int seg = blockIdx.x * 256 + threadIdx.x;
    if (seg < NSEG) {
        int cnt = g_rowptr[seg + 1] - g_rowptr[seg];
        int bin = cnt > 127 ? 127 : cnt;
        int pos = g_bstart[bin] + atomicAdd(&g_bcur[bin], 1);
        g_sorder[pos] = seg;
    }
}

// -------- segment softmax (logits fused) + alpha-weighted message sum --------
template <int NCM, bool GATHER>
__global__ __launch_bounds__(256) void k_attend3(const int* __restrict__ g1,
                                                 const int* __restrict__ g2,
                                                 const int* __restrict__ see, int it) {
    int lane = threadIdx.x & 63;
    int sidx = blockIdx.x * 4 + (threadIdx.x >> 6);
    if (sidx >= NSEG) return;
    int seg = g_sorder[sidx];
    int beg = g_rowptr[seg], end = g_rowptr[seg + 1];
    int cnt = end - beg;
    float acc[NCM];
#pragma unroll
    for (int c = 0; c < NCM; c++) acc[c] = 0.f;

    if (cnt > 0 && cnt <= 64) {
        float l = -1e30f;
        int i1 = 0, i2 = 0;
        if (lane < cnt) {
            int e = g_csr[beg + lane];
            float qv;
            if (GATHER) {
                i1 = g1[e]; i2 = g2[e];
                qv = 0.5f * (g_q[i1] + g_q[i2]);
            } else {
                i1 = e;
                qv = g_qe[e];
            }
            l = qv + g_p0[it][see[2 * (size_t)e]] + g_p1[it][see[2 * (size_t)e + 1]];
            l = l > 0.f ? l : 0.2f * l;
        }
        float m = l;
        WREDMAX(m);
        float ex = (lane < cnt) ? __expf(l - m) : 0.f;
        float den = ex;
        WREDUCE(den);
        float w = ex / den;    // exactly 0 for lanes >= cnt

        // 8-way unrolled, two-phase (issue all loads, then FMA). Clamped slots have w==0.
        for (int t0 = 0; t0 < cnt; t0 += 8) {
            float wt[8];
            int a1[8], a2[8];
#pragma unroll
            for (int u = 0; u < 8; u++) {
                int su = t0 + u; su = su > 63 ? 63 : su;
                wt[u] = __shfl(w, su);
                a1[u] = __shfl(i1, su);
                if (GATHER) a2[u] = __shfl(i2, su);
            }
            if (!GATHER) {
                ushort vm[8];
#pragma unroll
                for (int u = 0; u < 8; u++)
                    vm[u] = g_msg0h[(size_t)a1[u] * 64 + lane];
#pragma unroll
                for (int u = 0; u < 8; u++)
                    acc[0] += wt[u] * bfs(vm[u]);
            } else if (NCM == 2) {
                uint ua[8], ub[8];
#pragma unroll
                for (int u = 0; u < 8; u++) {
                    ua[u] = g_pkA[(size_t)a1[u] * 64 + lane];
                    ub[u] = g_pkA[(size_t)a2[u] * 64 + lane];
                }
#pragma unroll
                for (int u = 0; u < 8; u++) {
                    float wh = 0.5f * wt[u];
                    acc[0] += wh * (bflo(ua[u]) + bflo(ub[u]));
                    acc[1] += wh * (bfhi(ua[u]) + bfhi(ub[u]));
                }
            } else {
                uint ua[8], ub[8];
                ushort ha[8], hb[8];
#pragma unroll
                for (int u = 0; u < 8; u++) {
                    size_t b1 = (size_t)a1[u] * 64 + lane, b2 = (size_t)a2[u] * 64 + lane;
                    ua[u] = g_pk01[b1]; ub[u] = g_pk01[b2];
                    ha[u] = g_tfp[3 * PSZ + b1]; hb[u] = g_tfp[3 * PSZ + b2];
                }
#pragma unroll
                for (int u = 0; u < 8; u++) {
                    float wh = 0.5f * wt[u];
                    acc[0] += wh * (bflo(ua[u]) + bflo(ub[u]));
                    acc[1] += wh * (bfhi(ua[u]) + bfhi(ub[u]));
                    acc[2] += wh * (bfs(ha[u]) + bfs(hb[u]));
                }
            }
        }
    } else if (cnt > 64) {
        // rare fallback: two-pass serial with packed reads
        float m = -1e30f;
        for (int t = beg + lane; t < end; t += 64) {
            int e = g_csr[t];
            float qv = GATHER ? 0.5f * (g_q[g1[e]] + g_q[g2[e]]) : g_qe[e];
            float l = qv + g_p0[it][see[2 * (size_t)e]] + g_p1[it][see[2 * (size_t)e + 1]];
            l = l > 0.f ? l : 0.2f * l;
            m = fmaxf(m, l);
        }
        WREDMAX(m);
        float den = 0.f;
        for (int t = beg + lane; t < end; t += 64) {
            int e = g_csr[t];
            float qv = GATHER ? 0.5f * (g_q[g1[e]] + g_q[g2[e]]) : g_qe[e];
            float l = qv + g_p0[it][see[2 * (size_t)e]] + g_p1[it][see[2 * (size_t)e + 1]];
            l = l > 0.f ? l : 0.2f * l;
            den += __expf(l - m);
        }
        WREDUCE(den);
        float rden = 1.f / den;
        for (int t = beg; t < end; t++) {
            int e = g_csr[t];
            float qv = GATHER ? 0.5f * (g_q[g1[e]] + g_q[g2[e]]) : g_qe[e];
            float l = qv + g_p0[it][see[2 * (size_t)e]] + g_p1[it][see[2 * (size_t)e + 1]];
            l = l > 0.f ? l : 0.2f * l;
            float w = __expf(l - m) * rden;
            if (GATHER) {
                float wh = 0.5f * w;
                size_t b1 = (size_t)g1[e] * 64 + lane, b2 = (size_t)g2[e] * 64 + lane;
                if (NCM == 3) {
                    uint ua = g_pk01[b1], ub = g_pk01[b2];
                    acc[0] += wh * (bflo(ua) + bflo(ub));
                    acc[1] += wh * (bfhi(ua) + bfhi(ub));
                    acc[2] += wh * (bfs(g_tfp[3 * PSZ + b1]) + bfs(g_tfp[3 * PSZ + b2]));
                } else {
                    uint ua = g_pkA[b1], ub = g_pkA[b2];
                    acc[0] += wh * (bflo(ua) + bflo(ub));
                    acc[1] += wh * (bfhi(ua) + bfhi(ub));
                }
            } else {
                acc[0] += w * bfs(g_msg0h[(size_t)e * 64 + lane]);
            }
        }
    }
#pragma unroll
    for (int c = 0; c < NCM; c++)
        g_msumh[(size_t)seg * 192 + lane + 64 * c] = f2bf(acc[c]);
}

// ----- iter0 GEMM: 32x64 tiles, K=64; writes pkA=(out0|h); fused q (w2[1]) -----
__global__ __launch_bounds__(256) void k_gemmA(const float* __restrict__ W,
                                               const float* __restrict__ bias) {
    __shared__ float As[64][36];   // [k][row]
    __shared__ float Bs[64][68];   // [k][col]
    int tid = threadIdx.x;
    int rb0 = blockIdx.x * 32;
    {   // stage A: full K=64 for 32 rows
        int row = tid & 31, k8 = (tid >> 5) * 8;
        uint4 u = make_uint4(0, 0, 0, 0);
        if (rb0 + row < NSEG)
            u = *(const uint4*)&g_msumh[(size_t)(rb0 + row) * 192 + k8];
        As[k8 + 0][row] = bfs((ushort)(u.x & 0xFFFF));
        As[k8 + 1][row] = bfs((ushort)(u.x >> 16));
        As[k8 + 2][row] = bfs((ushort)(u.y & 0xFFFF));
        As[k8 + 3][row] = bfs((ushort)(u.y >> 16));
        As[k8 + 4][row] = bfs((ushort)(u.z & 0xFFFF));
        As[k8 + 5][row] = bfs((ushort)(u.z >> 16));
        As[k8 + 6][row] = bfs((ushort)(u.w & 0xFFFF));
        As[k8 + 7][row] = bfs((ushort)(u.w >> 16));
    }
    {   // stage B: 64x64 W
        int bk = tid >> 2, bc = (tid & 3) * 16;
#pragma unroll
        for (int q = 0; q < 4; q++)
            *(f4*)&Bs[bk][bc + q * 4] = *(const f4*)&W[(size_t)bk * 64 + bc + q * 4];
    }
    __syncthreads();
    int ty = tid >> 4, tx = tid & 15;
    float acc[2][4] = {{0.f, 0.f, 0.f, 0.f}, {0.f, 0.f, 0.f, 0.f}};
#pragma unroll 16
    for (int k = 0; k < 64; k++) {
        float a0 = As[k][ty * 2], a1 = As[k][ty * 2 + 1];
        f4 b = *(const f4*)&Bs[k][tx * 4];
        acc[0][0] += a0 * b.x; acc[0][1] += a0 * b.y; acc[0][2] += a0 * b.z; acc[0][3] += a0 * b.w;
        acc[1][0] += a1 * b.x; acc[1][1] += a1 * b.y; acc[1][2] += a1 * b.z; acc[1][3] += a1 * b.w;
    }
#pragma unroll
    for (int r = 0; r < 2; r++) {
        int row = rb0 + ty * 2 + r;
        bool valid = row < NSEG;
        bool nonempty = valid && (g_rowptr[row + 1] > g_rowptr[row]);
        ushort4 h4 = make_ushort4(0, 0, 0, 0);
        if (valid) h4 = *(const ushort4*)&g_tfp[3 * PSZ + (size_t)row * 64 + tx * 4];
        const ushort hb[4] = {h4.x, h4.y, h4.z, h4.w};
        uint pk[4];
        float qp = 0.f;
#pragma unroll
        for (int j = 0; j < 4; j++) {
            float v = acc[r][j] + bias[tx * 4 + j];
            if (!nonempty) v = 0.f;
            v = v > 0.f ? v : (__expf(v) - 1.f);
            pk[j] = (uint)f2bf(v) | ((uint)hb[j] << 16);
            qp += v * g_w2[1][tx * 4 + j] + bfs(hb[j]) * g_w2[1][64 + tx * 4 + j];
        }
        if (valid) {
            uint4 o; o.x = pk[0]; o.y = pk[1]; o.z = pk[2]; o.w = pk[3];
            *(uint4*)&g_pkA[(size_t)row * 64 + tx * 4] = o;
        }
        qp += __shfl_xor(qp, 1); qp += __shfl_xor(qp, 2);
        qp += __shfl_xor(qp, 4); qp += __shfl_xor(qp, 8);
        if (valid && tx == 0) g_q[row] = qp + g_w2[1][255];
    }
}

// ----- iter1 GEMM: 32x128 tiles, K=128; writes pk01=(out0|out1); fused q (w2[2]) -----
__global__ __launch_bounds__(256) void k_gemmB(const float* __restrict__ W,
                                               const float* __restrict__ bias) {
    __shared__ float As[32][36];    // [k][row]
    __shared__ float Bs[32][132];   // [k][col]
    int tid = threadIdx.x;
    int rb0 = blockIdx.x * 32;
    int ty = tid >> 4, tx = tid & 15;
    float aclo[2][4] = {{0.f,0.f,0.f,0.f},{0.f,0.f,0.f,0.f}};
    float achi[2][4] = {{0.f,0.f,0.f,0.f},{0.f,0.f,0.f,0.f}};
    for (int kk = 0; kk < 128; kk += 32) {
        {
            int row = tid & 31, k4 = (tid >> 5) * 4;
            uint2 u = make_uint2(0, 0);
            if (rb0 + row < NSEG)
                u = *(const uint2*)&g_msumh[(size_t)(rb0 + row) * 192 + kk + k4];
            As[k4 + 0][row] = bfs((ushort)(u.x & 0xFFFF));
            As[k4 + 1][row] = bfs((ushort)(u.x >> 16));
            As[k4 + 2][row] = bfs((ushort)(u.y & 0xFFFF));
            As[k4 + 3][row] = bfs((ushort)(u.y >> 16));
        }
        {
            int bk = tid >> 3, bc = (tid & 7) * 16;
#pragma unroll
            for (int q = 0; q < 4; q++)
                *(f4*)&Bs[bk][bc + q * 4] = *(const f4*)&W[(size_t)(kk + bk) * 128 + bc + q * 4];
        }
        __syncthreads();
#pragma unroll
        for (int k = 0; k < 32; k++) {
            float a0 = As[k][ty * 2], a1 = As[k][ty * 2 + 1];
            f4 bl = *(const f4*)&Bs[k][tx * 4];
            f4 bh = *(const f4*)&Bs[k][64 + tx * 4];
            aclo[0][0] += a0 * bl.x; aclo[0][1] += a0 * bl.y; aclo[0][2] += a0 * bl.z; aclo[0][3] += a0 * bl.w;
            aclo[1][0] += a1 * bl.x; aclo[1][1] += a1 * bl.y; aclo[1][2] += a1 * bl.z; aclo[1][3] += a1 * bl.w;
            achi[0][0] += a0 * bh.x; achi[0][1] += a0 * bh.y; achi[0][2] += a0 * bh.z; achi[0][3] += a0 * bh.w;
            achi[1][0] += a1 * bh.x; achi[1][1] += a1 * bh.y; achi[1][2] += a1 * bh.z; achi[1][3] += a1 * bh.w;
        }
        __syncthreads();
    }
#pragma unroll
    for (int r = 0; r < 2; r++) {
        int row = rb0 + ty * 2 + r;
        bool valid = row < NSEG;
        bool nonempty = valid && (g_rowptr[row + 1] > g_rowptr[row]);
        ushort4 h4 = make_ushort4(0, 0, 0, 0);
        if (valid) h4 = *(const ushort4*)&g_tfp[3 * PSZ + (size_t)row * 64 + tx * 4];
        const ushort hb[4] = {h4.x, h4.y, h4.z, h4.w};
        uint pk[4];
        float qp = 0.f;
#pragma unroll
        for (int j = 0; j < 4; j++) {
            float vl = aclo[r][j] + bias[tx * 4 + j];
            float vh = achi[r][j] + bias[64 + tx * 4 + j];
            if (!nonempty) { vl = 0.f; vh = 0.f; }
            vl = vl > 0.f ? vl : (__expf(vl) - 1.f);
            vh = vh > 0.f ? vh : (__expf(vh) - 1.f);
            pk[j] = (uint)f2bf(vl) | ((uint)f2bf(vh) << 16);
            qp += vl * g_w2[2][tx * 4 + j] + vh * g_w2[2][64 + tx * 4 + j] +
                  bfs(hb[j]) * g_w2[2][128 + tx * 4 + j];
        }
        if (valid) {
            uint4 o; o.x = pk[0]; o.y = pk[1]; o.z = pk[2]; o.w = pk[3];
            *(uint4*)&g_pk01[(size_t)row * 64 + tx * 4] = o;
        }
        qp += __shfl_xor(qp, 1); qp += __shfl_xor(qp, 2);
        qp += __shfl_xor(qp, 4); qp += __shfl_xor(qp, 8);
        if (valid && tx == 0) g_q[row] = qp + g_w2[2][255];
    }
}

// ----- iter2 GEMM (64-row x 64-col split tiles, K=192): plane cslot = mask*elu(msumh @ W + b) -----
__global__ __launch_bounds__(256) void k_gemmC(const float* __restrict__ W,
                                               const float* __restrict__ bias) {
    constexpr int D = 192;
    __shared__ float As[32][68];   // [k][row]
    __shared__ float Bs[32][68];   // [k][col]
    int tid = threadIdx.x;
    int rb0 = blockIdx.x * 64;
    int cslot = blockIdx.y;
    int cb0 = cslot * 64;
    int ty = tid >> 4, tx = tid & 15;
    float acc[4][4];
#pragma unroll
    for (int r = 0; r < 4; r++)
#pragma unroll
        for (int j = 0; j < 4; j++) acc[r][j] = 0.f;

    int arow = tid & 63, aoct = tid >> 6;
    int bk = tid >> 3, bc8 = (tid & 7) * 8;
    for (int kk = 0; kk < D; kk += 32) {
        {
            uint4 u = make_uint4(0, 0, 0, 0);
            if (rb0 + arow < NSEG)
                u = *(const uint4*)&g_msumh[(size_t)(rb0 + arow) * 192 + kk + aoct * 8];
            int kb = aoct * 8;
            As[kb + 0][arow] = bfs((ushort)(u.x & 0xFFFF));
            As[kb + 1][arow] = bfs((ushort)(u.x >> 16));
            As[kb + 2][arow] = bfs((ushort)(u.y & 0xFFFF));
            As[kb + 3][arow] = bfs((ushort)(u.y >> 16));
            As[kb + 4][arow] = bfs((ushort)(u.z & 0xFFFF));
            As[kb + 5][arow] = bfs((ushort)(u.z >> 16));
            As[kb + 6][arow] = bfs((ushort)(u.w & 0xFFFF));
            As[kb + 7][arow] = bfs((ushort)(u.w >> 16));
        }
        {
            f4 b0 = *(const f4*)&W[(size_t)(kk + bk) * D + cb0 + bc8];
            f4 b1 = *(const f4*)&W[(size_t)(kk + bk) * D + cb0 + bc8 + 4];
            *(f4*)&Bs[bk][bc8] = b0;
            *(f4*)&Bs[bk][bc8 + 4] = b1;
        }
        __syncthreads();
#pragma unroll
        for (int k = 0; k < 32; k++) {
            f4 a = *(const f4*)&As[k][ty * 4];
            f4 b = *(const f4*)&Bs[k][tx * 4];
            acc[0][0] += a.x * b.x; acc[0][1] += a.x * b.y; acc[0][2] += a.x * b.z; acc[0][3] += a.x * b.w;
            acc[1][0] += a.y * b.x; acc[1][1] += a.y * b.y; acc[1][2] += a.y * b.z; acc[1][3] += a.y * b.w;
            acc[2][0] += a.z * b.x; acc[2][1] += a.z * b.y; acc[2][2] += a.z * b.z; acc[2][3] += a.z * b.w;
            acc[3][0] += a.w * b.x; acc[3][1] += a.w * b.y; acc[3][2] += a.w * b.z; acc[3][3] += a.w * b.w;
        }
        __syncthreads();
    }
#pragma unroll
    for (int r = 0; r < 4; r++) {
        int row = rb0 + ty * 4 + r;
        if (row >= NSEG) continue;
        bool nonempty = g_rowptr[row + 1] > g_rowptr[row];
        ushort4 pk;
        ushort* p = (ushort*)&pk;
#pragma unroll
        for (int j = 0; j < 4; j++) {
            float v = acc[r][j] + bias[cb0 + tx * 4 + j];
            if (!nonempty) v = 0.f;
            v = v > 0.f ? v : (__expf(v) - 1.f);
            p[j] = f2bf(v);
        }
        *(ushort4*)&g_tfp[(size_t)cslot * PSZ + (size_t)row * 64 + tx * 4] = pk;
    }
}

// ---------------- final: per-molecule gather-sum (bf16 planes in, f32 out) ----------------
__global__ void k_final(const int* __restrict__ lscope, float* __restrict__ out) {
    __shared__ int idx[32];
    __shared__ float sm[4][256];
    int m = blockIdx.x, tid = threadIdx.x, w = tid >> 6, lane = tid & 63;
    if (tid < 32) idx[tid] = lscope[m * 32 + tid];
    __syncthreads();
    float a0 = 0.f, a1 = 0.f, a2 = 0.f, a3 = 0.f;
#pragma unroll
    for (int j = w * 8; j < w * 8 + 8; j++) {
        size_t base = (size_t)idx[j] * 64 + lane;
        a0 += bfs(g_tfp[base]);
        a1 += bfs(g_tfp[PSZ + base]);
        a2 += bfs(g_tfp[2 * PSZ + base]);
        a3 += bfs(g_tfp[3 * PSZ + base]);
    }
    sm[w][lane] = a0; sm[w][64 + lane] = a1; sm[w][128 + lane] = a2; sm[w][192 + lane] = a3;
    __syncthreads();
    out[(size_t)m * 256 + tid] = sm[0][tid] + sm[1][tid] + sm[2][tid] + sm[3][tid];
}

extern "C" void kernel_launch(void* const* d_in, const int* in_sizes, int n_in,
                              void* d_out, int out_size, void* d_ws, size_t ws_size,
                              hipStream_t stream) {
    const float* node_feats = (const float*)d_in[0];
    const float* fdg        = (const float*)d_in[1];
    const float* rij        = (const float*)d_in[2];
    const int*   see        = (const int*)d_in[3];
    const int*   b_scope    = (const int*)d_in[4];
    const int*   scope_up   = (const int*)d_in[5];
    const int*   scope_lig  = (const int*)d_in[6];
    const int*   l_scope    = (const int*)d_in[7];
    const float* W_emb      = (const float*)d_in[8];
    const float* b_emb      = (const float*)d_in[9];
    const float* W_dist     = (const float*)d_in[10];
    const float* b_dist     = (const float*)d_in[11];
    const float* fc_W[3]   = {(const float*)d_in[12], (const float*)d_in[15], (const float*)d_in[18]};
    const float* fc_b[3]   = {(const float*)d_in[13], (const float*)d_in[16], (const float*)d_in[19]};
    const float* attn_a[3] = {(const float*)d_in[14], (const float*)d_in[17], (const float*)d_in[20]};

    k_init<<<129, 256, 0, stream>>>();
    k_emb<<<8193, 256, 0, stream>>>(node_feats, W_emb, b_emb,
                                    attn_a[0], attn_a[1], attn_a[2]);
    k_prep_all<<<3, 256, 0, stream>>>(fc_W[0], fc_W[1], fc_W[2],
                                      attn_a[0], attn_a[1], attn_a[2],
                                      fc_b[0], fc_b[1], fc_b[2]);
    k_prep2<<<1, 64, 0, stream>>>(W_dist, b_dist);
    k_msg0<<<NE / 64, 256, 0, stream>>>(fdg, rij, W_dist, b_dist);
    k_hist<<<NE / 256, 256, 0, stream>>>(b_scope);
    k_scan1<<<129, 256, 0, stream>>>();
    k_scan2<<<1, 256, 0, stream>>>(129);
    k_scan3<<<129, 256, 0, stream>>>();
    k_scatter<<<NE / 256, 256, 0, stream>>>(b_scope);
    k_bhist<<<129, 256, 0, stream>>>();
    k_bscan<<<1, 128, 0, stream>>>();
    k_bscatter<<<129, 256, 0, stream>>>();

    // iter 0 (message width 64)
    k_attend3<1, false><<<8193, 256, 0, stream>>>(nullptr, nullptr, see, 0);
    k_gemmA<<<1025, 256, 0, stream>>>(fc_W[0], fc_b[0]);
    // iter 1 (message width 128)
    k_attend3<2, true><<<8193, 256, 0, stream>>>(scope_lig, scope_up, see, 1);
    k_gemmB<<<1025, 256, 0, stream>>>(fc_W[1], fc_b[1]);
    // iter 2 (message width 192)
    k_attend3<3, true><<<8193, 256, 0, stream>>>(scope_lig, scope_up, see, 2);
    k_gemmC<<<dim3(513, 3), 256, 0, stream>>>(fc_W[2], fc_b[2]);

    k_final<<<2048, 256, 0, stream>>>(l_scope, (float*)d_out);
}

// Round 10
// 318.778 us; speedup vs baseline: 1.3492x; 1.3492x over previous
//
#include <hip/hip_runtime.h>
#include <cstdint>
#include <cstddef>

#define NSEG 32769      // N_NODES + 1 (row 0 is the zero row)
#define NNODES 32768
#define NE 262144
#define PSZ ((size_t)NSEG * 64)   // one tf plane

using f4 = float4;

// ---------------- static device scratch ----------------
// planar planes 0..2 (final output cols, written by iter2 gemm), plane 3 = h_orig
__device__ ushort g_tfp[4 * PSZ];
__device__ uint   g_pkA[PSZ];      // (out0 | h)  after iter0 gemm
__device__ uint   g_pk01[PSZ];     // (out0 | out1) after iter1 gemm
__device__ ushort g_msg0h[(size_t)NE * 64];       // bf16 row-major
__device__ ushort g_msumh[(size_t)NSEG * 192];    // bf16 row-major (K width 192)
__device__ float  g_qe[NE];
__device__ float  g_q[NSEG];
__device__ float  g_p0[3][NSEG];
__device__ float  g_p1[3][NSEG];
__device__ float  g_w2[3][256];                   // w2 = W @ a2 in [0,d); c = a2.b at [255]
__device__ float  g_wq10[10];                     // W_dist @ w2_0
__device__ float  g_cq;                           // b_dist.w2_0 + c0
__device__ int    g_counts[NSEG];
__device__ int    g_excl[NSEG];
__device__ int    g_bsum[1024];
__device__ int    g_rowptr[NSEG + 1];
__device__ int    g_cur[NSEG];
__device__ int    g_csr[NE];
__device__ int    g_bc[128];       // size-bucket hist
__device__ int    g_bstart[128];
__device__ int    g_bcur[128];
__device__ int    g_sorder[NSEG];  // segments sorted by size

#define WREDUCE(x) { x += __shfl_xor(x, 32); x += __shfl_xor(x, 16); \
                     x += __shfl_xor(x, 8);  x += __shfl_xor(x, 4);  \
                     x += __shfl_xor(x, 2);  x += __shfl_xor(x, 1); }
#define WREDMAX(x) { x = fmaxf(x, __shfl_xor(x, 32)); x = fmaxf(x, __shfl_xor(x, 16)); \
                     x = fmaxf(x, __shfl_xor(x, 8));  x = fmaxf(x, __shfl_xor(x, 4));  \
                     x = fmaxf(x, __shfl_xor(x, 2));  x = fmaxf(x, __shfl_xor(x, 1)); }

__device__ __forceinline__ ushort f2bf(float x) {
    uint u = __float_as_uint(x);
    u += 0x7FFF + ((u >> 16) & 1);
    return (ushort)(u >> 16);
}
__device__ __forceinline__ float bfs(ushort u) { return __uint_as_float(((uint)u) << 16); }
__device__ __forceinline__ float bflo(uint u) { return __uint_as_float(u << 16); }
__device__ __forceinline__ float bfhi(uint u) { return __uint_as_float(u & 0xFFFF0000u); }

// ---------------- init: zero counts/cur/buckets ----------------
__global__ void k_init() {
    int i = blockIdx.x * 256 + threadIdx.x;
    if (i < NSEG) { g_counts[i] = 0; g_cur[i] = 0; }
    if (i < 128) { g_bc[i] = 0; g_bcur[i] = 0; }
}

// -------- h_orig (bf16, plane 3) = node_feats @ W_emb + b_emb ; fused p0/p1 --------
__global__ void k_emb(const float* __restrict__ node_feats,
                      const float* __restrict__ W, const float* __restrict__ b,
                      const float* __restrict__ a0, const float* __restrict__ a1,
                      const float* __restrict__ a2) {
    __shared__ float Ws[9 * 64];
    __shared__ float fs[4][9];
    int tid = threadIdx.x;
    for (int i = tid; i < 576; i += 256) Ws[i] = W[i];
    int r0 = blockIdx.x * 4;
    if (tid < 36) {
        int r = r0 + tid / 9, k = tid % 9;
        float v = 0.f;
        if (r >= 1 && r <= NNODES) v = node_feats[(size_t)(r - 1) * 9 + k];
        fs[tid / 9][k] = v;
    }
    __syncthreads();
    int r = tid >> 6, j = tid & 63;
    int row = r0 + r;
    if (row >= NSEG) return;
    float acc = b[j];
#pragma unroll
    for (int k = 0; k < 9; k++) acc += fs[r][k] * Ws[k * 64 + j];
    float v = (row == 0) ? 0.f : acc;
    g_tfp[3 * PSZ + (size_t)row * 64 + j] = f2bf(v);
    const float* A[3] = {a0, a1, a2};
#pragma unroll
    for (int i = 0; i < 3; i++) {
        float d0 = v * A[i][j];
        WREDUCE(d0);
        if (j == 0) g_p0[i][row] = d0;
        float d1 = v * A[i][64 + j];
        WREDUCE(d1);
        if (j == 0) g_p1[i][row] = d1;
    }
}

// ---------------- per-iter prep: w2 = W @ a2 ; c = a2.b (one block per iter) ----------------
__global__ void k_prep_all(const float* __restrict__ W0, const float* __restrict__ W1,
                           const float* __restrict__ W2, const float* __restrict__ a0,
                           const float* __restrict__ a1, const float* __restrict__ a2,
                           const float* __restrict__ b0, const float* __restrict__ b1,
                           const float* __restrict__ b2) {
    int it = blockIdx.x;
    const float* W = it == 0 ? W0 : (it == 1 ? W1 : W2);
    const float* a = it == 0 ? a0 : (it == 1 ? a1 : a2);
    const float* bias = it == 0 ? b0 : (it == 1 ? b1 : b2);
    int d = 64 * (it + 1);
    int k = threadIdx.x;
    if (k < d) {
        float s = 0.f;
        for (int j = 0; j < d; j++) s += W[(size_t)k * d + j] * a[128 + j];
        g_w2[it][k] = s;
    } else if (k == 255) {
        float c = 0.f;
        for (int j = 0; j < d; j++) c += a[128 + j] * bias[j];
        g_w2[it][255] = c;
    }
}

// ---------------- prep2: wq10 = W_dist @ w2_0 ; cq = b_dist.w2_0 + c0 ----------------
__global__ void k_prep2(const float* __restrict__ Wd, const float* __restrict__ bd) {
    int k = threadIdx.x;
    if (k < 10) {
        float s = 0.f;
        for (int j = 0; j < 64; j++) s += Wd[(size_t)k * 64 + j] * g_w2[0][j];
        g_wq10[k] = s;
    } else if (k == 63) {
        float s = 0.f;
        for (int j = 0; j < 64; j++) s += bd[j] * g_w2[0][j];
        g_cq = s + g_w2[0][255];
    }
}

// -------- msg0 (bf16) = [fdg | rij] @ W_dist + b_dist ; qe = x.wq10 + cq --------
__global__ __launch_bounds__(256) void k_msg0(const float* __restrict__ fdg,
                                              const float* __restrict__ rij,
                                              const float* __restrict__ W,
                                              const float* __restrict__ b) {
    __shared__ float Ws[10 * 64];
    __shared__ float bs[64];
    __shared__ float fs[64][10];
    int tid = threadIdx.x;
    for (int i = tid; i < 640; i += 256) Ws[i] = W[i];
    if (tid < 64) bs[tid] = b[tid];
    int e0 = blockIdx.x * 64;
    for (int i = tid; i < 576; i += 256) fs[i / 9][i % 9] = fdg[(size_t)e0 * 9 + i];
    if (tid < 64) fs[tid][9] = rij[e0 + tid];
    __syncthreads();
    int j = tid & 63;
#pragma unroll 4
    for (int p = 0; p < 16; p++) {
        int r = p * 4 + (tid >> 6);
        int e = e0 + r;
        float acc = bs[j];
#pragma unroll
        for (int k = 0; k < 10; k++) acc += fs[r][k] * Ws[k * 64 + j];
        g_msg0h[(size_t)e * 64 + j] = f2bf(acc);
        if (j == 0) {
            float q = g_cq;
#pragma unroll
            for (int k = 0; k < 10; k++) q += fs[r][k] * g_wq10[k];
            g_qe[e] = q;
        }
    }
}

// ---------------- CSR build over b_scope ----------------
__global__ void k_hist(const int* __restrict__ bs) {
    int e = blockIdx.x * 256 + threadIdx.x;
    if (e < NE) atomicAdd(&g_counts[bs[e]], 1);
}

__global__ void k_scan1() {
    __shared__ int s[256];
    int t = threadIdx.x, i = blockIdx.x * 256 + t;
    int v = (i < NSEG) ? g_counts[i] : 0;
    s[t] = v; __syncthreads();
    for (int off = 1; off < 256; off <<= 1) {
        int tmp = (t >= off) ? s[t - off] : 0;
        __syncthreads();
        s[t] += tmp;
        __syncthreads();
    }
    if (i < NSEG) g_excl[i] = s[t] - v;
    if (t == 255) g_bsum[blockIdx.x] = s[255];
}

__global__ void k_scan2(int nb) {
    __shared__ int s[256];
    int t = threadIdx.x;
    int v = (t < nb) ? g_bsum[t] : 0;
    s[t] = v; __syncthreads();
    for (int off = 1; off < 256; off <<= 1) {
        int tmp = (t >= off) ? s[t - off] : 0;
        __syncthreads();
        s[t] += tmp;
        __syncthreads();
    }
    if (t < nb) g_bsum[t] = s[t] - v;   // exclusive
}

__global__ void k_scan3() {
    int i = blockIdx.x * 256 + threadIdx.x;
    if (i < NSEG) g_rowptr[i] = g_excl[i] + g_bsum[i >> 8];
    if (i == NSEG) g_rowptr[NSEG] = NE;
}

__global__ void k_scatter(const int* __restrict__ bs) {
    int e = blockIdx.x * 256 + threadIdx.x;
    if (e < NE) {
        int seg = bs[e];
        int pos = g_rowptr[seg] + atomicAdd(&g_cur[seg], 1);
        g_csr[pos] = e;
    }
}

// ---------------- size-sorted segment order (counting sort by cnt) ----------------
__global__ void k_bhist() {
    __shared__ int h[128];
    int tid = threadIdx.x;
    if (tid < 128) h[tid] = 0;
    __syncthreads();
    int seg = blockIdx.x * 256 + tid;
    if (seg < NSEG) {
        int cnt = g_rowptr[seg + 1] - g_rowptr[seg];
        atomicAdd(&h[cnt > 127 ? 127 : cnt], 1);
    }
    __syncthreads();
    if (tid < 128 && h[tid]) atomicAdd(&g_bc[tid], h[tid]);
}

__global__ void k_bscan() {
    __shared__ int s[128];
    int t = threadIdx.x;
    int v = g_bc[t];
    s[t] = v; __syncthreads();
    for (int off = 1; off < 128; off <<= 1) {
        int tmp = (t >= off) ? s[t - off] : 0;
        __syncthreads();
        s[t] += tmp;
        __syncthreads();
    }
    g_bstart[t] = s[t] - v;
}

// two-level scatter: shared-hist local positions + one global chunk-reserve per (block,bin)
__global__ void k_bscatter() {
    __shared__ int lh[128];
    __shared__ int lbase[128];
    int tid = threadIdx.x;
    if (tid < 128) lh[tid] = 0;
    __syncthreads();
    int seg = blockIdx.x * 256 + tid;
    int bin = 0, lpos = 0;
    bool valid = seg < NSEG;
    if (valid) {
        int cnt = g_rowptr[seg + 1] - g_rowptr[seg];
        bin = cnt > 127 ? 127 : cnt;
        lpos = atomicAdd(&lh[bin], 1);          // shared atomic (fast)
    }
    __syncthreads();
    if (tid < 128 && lh[tid] > 0)
        lbase[tid] = atomicAdd(&g_bcur[tid], lh[tid]);   // ~25 global atomics/block
    __syncthreads();
    if (valid)
        g_sorder[g_bstart[bin] + lbase[bin] + lpos] = seg;
}

// -------- segment softmax (logits fused) + alpha-weighted message sum --------
template <int NCM, bool GATHER>
__global__ __launch_bounds__(256) void k_attend3(const int* __restrict__ g1,
                                                 const int* __restrict__ g2,
                                                 const int* __restrict__ see, int it) {
    int lane = threadIdx.x & 63;
    int sidx = blockIdx.x * 4 + (threadIdx.x >> 6);
    if (sidx >= NSEG) return;
    int seg = g_sorder[sidx];
    int beg = g_rowptr[seg], end = g_rowptr[seg + 1];
    int cnt = end - beg;
    float acc[NCM];
#pragma unroll
    for (int c = 0; c < NCM; c++) acc[c] = 0.f;

    if (cnt > 0 && cnt <= 64) {
        float l = -1e30f;
        int i1 = 0, i2 = 0;
        if (lane < cnt) {
            int e = g_csr[beg + lane];
            float qv;
            if (GATHER) {
                i1 = g1[e]; i2 = g2[e];
                qv = 0.5f * (g_q[i1] + g_q[i2]);
            } else {
                i1 = e;
                qv = g_qe[e];
            }
            l = qv + g_p0[it][see[2 * (size_t)e]] + g_p1[it][see[2 * (size_t)e + 1]];
            l = l > 0.f ? l : 0.2f * l;
        }
        float m = l;
        WREDMAX(m);
        float ex = (lane < cnt) ? __expf(l - m) : 0.f;
        float den = ex;
        WREDUCE(den);
        float w = ex / den;    // exactly 0 for lanes >= cnt

        // 8-way unrolled, two-phase (issue all loads, then FMA). Clamped slots have w==0.
        for (int t0 = 0; t0 < cnt; t0 += 8) {
            float wt[8];
            int a1[8], a2[8];
#pragma unroll
            for (int u = 0; u < 8; u++) {
                int su = t0 + u; su = su > 63 ? 63 : su;
                wt[u] = __shfl(w, su);
                a1[u] = __shfl(i1, su);
                if (GATHER) a2[u] = __shfl(i2, su);
            }
            if (!GATHER) {
                ushort vm[8];
#pragma unroll
                for (int u = 0; u < 8; u++)
                    vm[u] = g_msg0h[(size_t)a1[u] * 64 + lane];
#pragma unroll
                for (int u = 0; u < 8; u++)
                    acc[0] += wt[u] * bfs(vm[u]);
            } else if (NCM == 2) {
                uint ua[8], ub[8];
#pragma unroll
                for (int u = 0; u < 8; u++) {
                    ua[u] = g_pkA[(size_t)a1[u] * 64 + lane];
                    ub[u] = g_pkA[(size_t)a2[u] * 64 + lane];
                }
#pragma unroll
                for (int u = 0; u < 8; u++) {
                    float wh = 0.5f * wt[u];
                    acc[0] += wh * (bflo(ua[u]) + bflo(ub[u]));
                    acc[1] += wh * (bfhi(ua[u]) + bfhi(ub[u]));
                }
            } else {
                uint ua[8], ub[8];
                ushort ha[8], hb[8];
#pragma unroll
                for (int u = 0; u < 8; u++) {
                    size_t b1 = (size_t)a1[u] * 64 + lane, b2 = (size_t)a2[u] * 64 + lane;
                    ua[u] = g_pk01[b1]; ub[u] = g_pk01[b2];
                    ha[u] = g_tfp[3 * PSZ + b1]; hb[u] = g_tfp[3 * PSZ + b2];
                }
#pragma unroll
                for (int u = 0; u < 8; u++) {
                    float wh = 0.5f * wt[u];
                    acc[0] += wh * (bflo(ua[u]) + bflo(ub[u]));
                    acc[1] += wh * (bfhi(ua[u]) + bfhi(ub[u]));
                    acc[2] += wh * (bfs(ha[u]) + bfs(hb[u]));
                }
            }
        }
    } else if (cnt > 64) {
        // rare fallback: two-pass serial with packed reads
        float m = -1e30f;
        for (int t = beg + lane; t < end; t += 64) {
            int e = g_csr[t];
            float qv = GATHER ? 0.5f * (g_q[g1[e]] + g_q[g2[e]]) : g_qe[e];
            float l = qv + g_p0[it][see[2 * (size_t)e]] + g_p1[it][see[2 * (size_t)e + 1]];
            l = l > 0.f ? l : 0.2f * l;
            m = fmaxf(m, l);
        }
        WREDMAX(m);
        float den = 0.f;
        for (int t = beg + lane; t < end; t += 64) {
            int e = g_csr[t];
            float qv = GATHER ? 0.5f * (g_q[g1[e]] + g_q[g2[e]]) : g_qe[e];
            float l = qv + g_p0[it][see[2 * (size_t)e]] + g_p1[it][see[2 * (size_t)e + 1]];
            l = l > 0.f ? l : 0.2f * l;
            den += __expf(l - m);
        }
        WREDUCE(den);
        float rden = 1.f / den;
        for (int t = beg; t < end; t++) {
            int e = g_csr[t];
            float qv = GATHER ? 0.5f * (g_q[g1[e]] + g_q[g2[e]]) : g_qe[e];
            float l = qv + g_p0[it][see[2 * (size_t)e]] + g_p1[it][see[2 * (size_t)e + 1]];
            l = l > 0.f ? l : 0.2f * l;
            float w = __expf(l - m) * rden;
            if (GATHER) {
                float wh = 0.5f * w;
                size_t b1 = (size_t)g1[e] * 64 + lane, b2 = (size_t)g2[e] * 64 + lane;
                if (NCM == 3) {
                    uint ua = g_pk01[b1], ub = g_pk01[b2];
                    acc[0] += wh * (bflo(ua) + bflo(ub));
                    acc[1] += wh * (bfhi(ua) + bfhi(ub));
                    acc[2] += wh * (bfs(g_tfp[3 * PSZ + b1]) + bfs(g_tfp[3 * PSZ + b2]));
                } else {
                    uint ua = g_pkA[b1], ub = g_pkA[b2];
                    acc[0] += wh * (bflo(ua) + bflo(ub));
                    acc[1] += wh * (bfhi(ua) + bfhi(ub));
                }
            } else {
                acc[0] += w * bfs(g_msg0h[(size_t)e * 64 + lane]);
            }
        }
    }
#pragma unroll
    for (int c = 0; c < NCM; c++)
        g_msumh[(size_t)seg * 192 + lane + 64 * c] = f2bf(acc[c]);
}

// ----- iter0 GEMM: 32x64 tiles, K=64; writes pkA=(out0|h); fused q (w2[1]) -----
__global__ __launch_bounds__(256) void k_gemmA(const float* __restrict__ W,
                                               const float* __restrict__ bias) {
    __shared__ float As[64][36];   // [k][row]
    __shared__ float Bs[64][68];   // [k][col]
    int tid = threadIdx.x;
    int rb0 = blockIdx.x * 32;
    {   // stage A: full K=64 for 32 rows
        int row = tid & 31, k8 = (tid >> 5) * 8;
        uint4 u = make_uint4(0, 0, 0, 0);
        if (rb0 + row < NSEG)
            u = *(const uint4*)&g_msumh[(size_t)(rb0 + row) * 192 + k8];
        As[k8 + 0][row] = bfs((ushort)(u.x & 0xFFFF));
        As[k8 + 1][row] = bfs((ushort)(u.x >> 16));
        As[k8 + 2][row] = bfs((ushort)(u.y & 0xFFFF));
        As[k8 + 3][row] = bfs((ushort)(u.y >> 16));
        As[k8 + 4][row] = bfs((ushort)(u.z & 0xFFFF));
        As[k8 + 5][row] = bfs((ushort)(u.z >> 16));
        As[k8 + 6][row] = bfs((ushort)(u.w & 0xFFFF));
        As[k8 + 7][row] = bfs((ushort)(u.w >> 16));
    }
    {   // stage B: 64x64 W
        int bk = tid >> 2, bc = (tid & 3) * 16;
#pragma unroll
        for (int q = 0; q < 4; q++)
            *(f4*)&Bs[bk][bc + q * 4] = *(const f4*)&W[(size_t)bk * 64 + bc + q * 4];
    }
    __syncthreads();
    int ty = tid >> 4, tx = tid & 15;
    float acc[2][4] = {{0.f, 0.f, 0.f, 0.f}, {0.f, 0.f, 0.f, 0.f}};
#pragma unroll 16
    for (int k = 0; k < 64; k++) {
        float a0 = As[k][ty * 2], a1 = As[k][ty * 2 + 1];
        f4 b = *(const f4*)&Bs[k][tx * 4];
        acc[0][0] += a0 * b.x; acc[0][1] += a0 * b.y; acc[0][2] += a0 * b.z; acc[0][3] += a0 * b.w;
        acc[1][0] += a1 * b.x; acc[1][1] += a1 * b.y; acc[1][2] += a1 * b.z; acc[1][3] += a1 * b.w;
    }
#pragma unroll
    for (int r = 0; r < 2; r++) {
        int row = rb0 + ty * 2 + r;
        bool valid = row < NSEG;
        bool nonempty = valid && (g_rowptr[row + 1] > g_rowptr[row]);
        ushort4 h4 = make_ushort4(0, 0, 0, 0);
        if (valid) h4 = *(const ushort4*)&g_tfp[3 * PSZ + (size_t)row * 64 + tx * 4];
        const ushort hb[4] = {h4.x, h4.y, h4.z, h4.w};
        uint pk[4];
        float qp = 0.f;
#pragma unroll
        for (int j = 0; j < 4; j++) {
            float v = acc[r][j] + bias[tx * 4 + j];
            if (!nonempty) v = 0.f;
            v = v > 0.f ? v : (__expf(v) - 1.f);
            pk[j] = (uint)f2bf(v) | ((uint)hb[j] << 16);
            qp += v * g_w2[1][tx * 4 + j] + bfs(hb[j]) * g_w2[1][64 + tx * 4 + j];
        }
        if (valid) {
            uint4 o; o.x = pk[0]; o.y = pk[1]; o.z = pk[2]; o.w = pk[3];
            *(uint4*)&g_pkA[(size_t)row * 64 + tx * 4] = o;
        }
        qp += __shfl_xor(qp, 1); qp += __shfl_xor(qp, 2);
        qp += __shfl_xor(qp, 4); qp += __shfl_xor(qp, 8);
        if (valid && tx == 0) g_q[row] = qp + g_w2[1][255];
    }
}

// ----- iter1 GEMM: 32x128 tiles, K=128; writes pk01=(out0|out1); fused q (w2[2]) -----
__global__ __launch_bounds__(256) void k_gemmB(const float* __restrict__ W,
                                               const float* __restrict__ bias) {
    __shared__ float As[32][36];    // [k][row]
    __shared__ float Bs[32][132];   // [k][col]
    int tid = threadIdx.x;
    int rb0 = blockIdx.x * 32;
    int ty = tid >> 4, tx = tid & 15;
    float aclo[2][4] = {{0.f,0.f,0.f,0.f},{0.f,0.f,0.f,0.f}};
    float achi[2][4] = {{0.f,0.f,0.f,0.f},{0.f,0.f,0.f,0.f}};
    for (int kk = 0; kk < 128; kk += 32) {
        {
            int row = tid & 31, k4 = (tid >> 5) * 4;
            uint2 u = make_uint2(0, 0);
            if (rb0 + row < NSEG)
                u = *(const uint2*)&g_msumh[(size_t)(rb0 + row) * 192 + kk + k4];
            As[k4 + 0][row] = bfs((ushort)(u.x & 0xFFFF));
            As[k4 + 1][row] = bfs((ushort)(u.x >> 16));
            As[k4 + 2][row] = bfs((ushort)(u.y & 0xFFFF));
            As[k4 + 3][row] = bfs((ushort)(u.y >> 16));
        }
        {
            int bk = tid >> 3, bc = (tid & 7) * 16;
#pragma unroll
            for (int q = 0; q < 4; q++)
                *(f4*)&Bs[bk][bc + q * 4] = *(const f4*)&W[(size_t)(kk + bk) * 128 + bc + q * 4];
        }
        __syncthreads();
#pragma unroll
        for (int k = 0; k < 32; k++) {
            float a0 = As[k][ty * 2], a1 = As[k][ty * 2 + 1];
            f4 bl = *(const f4*)&Bs[k][tx * 4];
            f4 bh = *(const f4*)&Bs[k][64 + tx * 4];
            aclo[0][0] += a0 * bl.x; aclo[0][1] += a0 * bl.y; aclo[0][2] += a0 * bl.z; aclo[0][3] += a0 * bl.w;
            aclo[1][0] += a1 * bl.x; aclo[1][1] += a1 * bl.y; aclo[1][2] += a1 * bl.z; aclo[1][3] += a1 * bl.w;
            achi[0][0] += a0 * bh.x; achi[0][1] += a0 * bh.y; achi[0][2] += a0 * bh.z; achi[0][3] += a0 * bh.w;
            achi[1][0] += a1 * bh.x; achi[1][1] += a1 * bh.y; achi[1][2] += a1 * bh.z; achi[1][3] += a1 * bh.w;
        }
        __syncthreads();
    }
#pragma unroll
    for (int r = 0; r < 2; r++) {
        int row = rb0 + ty * 2 + r;
        bool valid = row < NSEG;
        bool nonempty = valid && (g_rowptr[row + 1] > g_rowptr[row]);
        ushort4 h4 = make_ushort4(0, 0, 0, 0);
        if (valid) h4 = *(const ushort4*)&g_tfp[3 * PSZ + (size_t)row * 64 + tx * 4];
        const ushort hb[4] = {h4.x, h4.y, h4.z, h4.w};
        uint pk[4];
        float qp = 0.f;
#pragma unroll
        for (int j = 0; j < 4; j++) {
            float vl = aclo[r][j] + bias[tx * 4 + j];
            float vh = achi[r][j] + bias[64 + tx * 4 + j];
            if (!nonempty) { vl = 0.f; vh = 0.f; }
            vl = vl > 0.f ? vl : (__expf(vl) - 1.f);
            vh = vh > 0.f ? vh : (__expf(vh) - 1.f);
            pk[j] = (uint)f2bf(vl) | ((uint)f2bf(vh) << 16);
            qp += vl * g_w2[2][tx * 4 + j] + vh * g_w2[2][64 + tx * 4 + j] +
                  bfs(hb[j]) * g_w2[2][128 + tx * 4 + j];
        }
        if (valid) {
            uint4 o; o.x = pk[0]; o.y = pk[1]; o.z = pk[2]; o.w = pk[3];
            *(uint4*)&g_pk01[(size_t)row * 64 + tx * 4] = o;
        }
        qp += __shfl_xor(qp, 1); qp += __shfl_xor(qp, 2);
        qp += __shfl_xor(qp, 4); qp += __shfl_xor(qp, 8);
        if (valid && tx == 0) g_q[row] = qp + g_w2[2][255];
    }
}

// ----- iter2 GEMM (64-row x 64-col split tiles, K=192): plane cslot = mask*elu(msumh @ W + b) -----
__global__ __launch_bounds__(256) void k_gemmC(const float* __restrict__ W,
                                               const float* __restrict__ bias) {
    constexpr int D = 192;
    __shared__ float As[32][68];   // [k][row]
    __shared__ float Bs[32][68];   // [k][col]
    int tid = threadIdx.x;
    int rb0 = blockIdx.x * 64;
    int cslot = blockIdx.y;
    int cb0 = cslot * 64;
    int ty = tid >> 4, tx = tid & 15;
    float acc[4][4];
#pragma unroll
    for (int r = 0; r < 4; r++)
#pragma unroll
        for (int j = 0; j < 4; j++) acc[r][j] = 0.f;

    int arow = tid & 63, aoct = tid >> 6;
    int bk = tid >> 3, bc8 = (tid & 7) * 8;
    for (int kk = 0; kk < D; kk += 32) {
        {
            uint4 u = make_uint4(0, 0, 0, 0);
            if (rb0 + arow < NSEG)
                u = *(const uint4*)&g_msumh[(size_t)(rb0 + arow) * 192 + kk + aoct * 8];
            int kb = aoct * 8;
            As[kb + 0][arow] = bfs((ushort)(u.x & 0xFFFF));
            As[kb + 1][arow] = bfs((ushort)(u.x >> 16));
            As[kb + 2][arow] = bfs((ushort)(u.y & 0xFFFF));
            As[kb + 3][arow] = bfs((ushort)(u.y >> 16));
            As[kb + 4][arow] = bfs((ushort)(u.z & 0xFFFF));
            As[kb + 5][arow] = bfs((ushort)(u.z >> 16));
            As[kb + 6][arow] = bfs((ushort)(u.w & 0xFFFF));
            As[kb + 7][arow] = bfs((ushort)(u.w >> 16));
        }
        {
            f4 b0 = *(const f4*)&W[(size_t)(kk + bk) * D + cb0 + bc8];
            f4 b1 = *(const f4*)&W[(size_t)(kk + bk) * D + cb0 + bc8 + 4];
            *(f4*)&Bs[bk][bc8] = b0;
            *(f4*)&Bs[bk][bc8 + 4] = b1;
        }
        __syncthreads();
#pragma unroll
        for (int k = 0; k < 32; k++) {
            f4 a = *(const f4*)&As[k][ty * 4];
            f4 b = *(const f4*)&Bs[k][tx * 4];
            acc[0][0] += a.x * b.x; acc[0][1] += a.x * b.y; acc[0][2] += a.x * b.z; acc[0][3] += a.x * b.w;
            acc[1][0] += a.y * b.x; acc[1][1] += a.y * b.y; acc[1][2] += a.y * b.z; acc[1][3] += a.y * b.w;
            acc[2][0] += a.z * b.x; acc[2][1] += a.z * b.y; acc[2][2] += a.z * b.z; acc[2][3] += a.z * b.w;
            acc[3][0] += a.w * b.x; acc[3][1] += a.w * b.y; acc[3][2] += a.w * b.z; acc[3][3] += a.w * b.w;
        }
        __syncthreads();
    }
#pragma unroll
    for (int r = 0; r < 4; r++) {
        int row = rb0 + ty * 4 + r;
        if (row >= NSEG) continue;
        bool nonempty = g_rowptr[row + 1] > g_rowptr[row];
        ushort4 pk;
        ushort* p = (ushort*)&pk;
#pragma unroll
        for (int j = 0; j < 4; j++) {
            float v = acc[r][j] + bias[cb0 + tx * 4 + j];
            if (!nonempty) v = 0.f;
            v = v > 0.f ? v : (__expf(v) - 1.f);
            p[j] = f2bf(v);
        }
        *(ushort4*)&g_tfp[(size_t)cslot * PSZ + (size_t)row * 64 + tx * 4] = pk;
    }
}

// ---------------- final: per-molecule gather-sum (bf16 planes in, f32 out) ----------------
__global__ void k_final(const int* __restrict__ lscope, float* __restrict__ out) {
    __shared__ int idx[32];
    __shared__ float sm[4][256];
    int m = blockIdx.x, tid = threadIdx.x, w = tid >> 6, lane = tid & 63;
    if (tid < 32) idx[tid] = lscope[m * 32 + tid];
    __syncthreads();
    float a0 = 0.f, a1 = 0.f, a2 = 0.f, a3 = 0.f;
#pragma unroll
    for (int j = w * 8; j < w * 8 + 8; j++) {
        size_t base = (size_t)idx[j] * 64 + lane;
        a0 += bfs(g_tfp[base]);
        a1 += bfs(g_tfp[PSZ + base]);
        a2 += bfs(g_tfp[2 * PSZ + base]);
        a3 += bfs(g_tfp[3 * PSZ + base]);
    }
    sm[w][lane] = a0; sm[w][64 + lane] = a1; sm[w][128 + lane] = a2; sm[w][192 + lane] = a3;
    __syncthreads();
    out[(size_t)m * 256 + tid] = sm[0][tid] + sm[1][tid] + sm[2][tid] + sm[3][tid];
}

extern "C" void kernel_launch(void* const* d_in, const int* in_sizes, int n_in,
                              void* d_out, int out_size, void* d_ws, size_t ws_size,
                              hipStream_t stream) {
    const float* node_feats = (const float*)d_in[0];
    const float* fdg        = (const float*)d_in[1];
    const float* rij        = (const float*)d_in[2];
    const int*   see        = (const int*)d_in[3];
    const int*   b_scope    = (const int*)d_in[4];
    const int*   scope_up   = (const int*)d_in[5];
    const int*   scope_lig  = (const int*)d_in[6];
    const int*   l_scope    = (const int*)d_in[7];
    const float* W_emb      = (const float*)d_in[8];
    const float* b_emb      = (const float*)d_in[9];
    const float* W_dist     = (const float*)d_in[10];
    const float* b_dist     = (const float*)d_in[11];
    const float* fc_W[3]   = {(const float*)d_in[12], (const float*)d_in[15], (const float*)d_in[18]};
    const float* fc_b[3]   = {(const float*)d_in[13], (const float*)d_in[16], (const float*)d_in[19]};
    const float* attn_a[3] = {(const float*)d_in[14], (const float*)d_in[17], (const float*)d_in[20]};

    k_init<<<129, 256, 0, stream>>>();
    k_emb<<<8193, 256, 0, stream>>>(node_feats, W_emb, b_emb,
                                    attn_a[0], attn_a[1], attn_a[2]);
    k_prep_all<<<3, 256, 0, stream>>>(fc_W[0], fc_W[1], fc_W[2],
                                      attn_a[0], attn_a[1], attn_a[2],
                                      fc_b[0], fc_b[1], fc_b[2]);
    k_prep2<<<1, 64, 0, stream>>>(W_dist, b_dist);
    k_msg0<<<NE / 64, 256, 0, stream>>>(fdg, rij, W_dist, b_dist);
    k_hist<<<NE / 256, 256, 0, stream>>>(b_scope);
    k_scan1<<<129, 256, 0, stream>>>();
    k_scan2<<<1, 256, 0, stream>>>(129);
    k_scan3<<<129, 256, 0, stream>>>();
    k_scatter<<<NE / 256, 256, 0, stream>>>(b_scope);
    k_bhist<<<129, 256, 0, stream>>>();
    k_bscan<<<1, 128, 0, stream>>>();
    k_bscatter<<<129, 256, 0, stream>>>();

    // iter 0 (message width 64)
    k_attend3<1, false><<<8193, 256, 0, stream>>>(nullptr, nullptr, see, 0);
    k_gemmA<<<1025, 256, 0, stream>>>(fc_W[0], fc_b[0]);
    // iter 1 (message width 128)
    k_attend3<2, true><<<8193, 256, 0, stream>>>(scope_lig, scope_up, see, 1);
    k_gemmB<<<1025, 256, 0, stream>>>(fc_W[1], fc_b[1]);
    // iter 2 (message width 192)
    k_attend3<3, true><<<8193, 256, 0, stream>>>(scope_lig, scope_up, see, 2);
    k_gemmC<<<dim3(513, 3), 256, 0, stream>>>(fc_W[2], fc_b[2]);

    k_final<<<2048, 256, 0, stream>>>(l_scope, (float*)d_out);
}

// Round 12
// 308.413 us; speedup vs baseline: 1.3946x; 1.0336x over previous
//
#include <hip/hip_runtime.h>
#include <cstdint>
#include <cstddef>

#define NSEG 32769      // N_NODES + 1 (row 0 is the zero row)
#define NNODES 32768
#define NE 262144
#define PSZ ((size_t)NSEG * 64)   // one tf plane

using f4 = float4;

// ---------------- static device scratch ----------------
__device__ ushort g_tfp[4 * PSZ];                 // planes 0..2 out cols (iter2), plane 3 h_orig
__device__ uint   g_pkA[PSZ];                     // (out0 | h)  after iter0 gemm
__device__ uint   g_pk01[PSZ];                    // (out0 | out1) after iter1 gemm
__device__ ushort g_msg0s[(size_t)NE * 64];       // bf16, CSR-sorted rows
__device__ float  g_lb0[NE];                      // iter-0 full logit base, CSR-sorted
__device__ ushort g_msumh[(size_t)NSEG * 192];    // bf16 row-major (K width 192)
__device__ float  g_q[NSEG];
__device__ float  g_p0[3][NSEG];
__device__ float  g_p1[3][NSEG];
__device__ float  g_w2[3][256];                   // w2 = W @ a2 in [0,d); c = a2.b at [255]
__device__ float  g_wq10[10];                     // W_dist @ w2_0
__device__ float  g_cq;                           // b_dist.w2_0 + a2.b
__device__ int    g_counts[NSEG];
__device__ int    g_excl[NSEG];
__device__ int    g_bsum[1024];
__device__ int    g_rowptr[NSEG + 1];
__device__ int    g_cur[NSEG];
__device__ int    g_csr[NE];
__device__ int    g_epos[NE];                     // edge -> csr position
__device__ int    g_g1s[NE];                      // gather indices, CSR-sorted
__device__ int    g_g2s[NE];
__device__ float  g_pe1[NE];                      // p0[1][s0]+p1[1][s1], CSR-sorted
__device__ float  g_pe2[NE];                      // p0[2][s0]+p1[2][s1], CSR-sorted
__device__ int    g_bc[128];
__device__ int    g_bcur[128];
__device__ int    g_sorder[NSEG];

#define WREDUCE(x) { x += __shfl_xor(x, 32); x += __shfl_xor(x, 16); \
                     x += __shfl_xor(x, 8);  x += __shfl_xor(x, 4);  \
                     x += __shfl_xor(x, 2);  x += __shfl_xor(x, 1); }
#define WREDMAX(x) { x = fmaxf(x, __shfl_xor(x, 32)); x = fmaxf(x, __shfl_xor(x, 16)); \
                     x = fmaxf(x, __shfl_xor(x, 8));  x = fmaxf(x, __shfl_xor(x, 4));  \
                     x = fmaxf(x, __shfl_xor(x, 2));  x = fmaxf(x, __shfl_xor(x, 1)); }

__device__ __forceinline__ ushort f2bf(float x) {
    uint u = __float_as_uint(x);
    u += 0x7FFF + ((u >> 16) & 1);
    return (ushort)(u >> 16);
}
__device__ __forceinline__ float bfs(ushort u) { return __uint_as_float(((uint)u) << 16); }
__device__ __forceinline__ float bflo(uint u) { return __uint_as_float(u << 16); }
__device__ __forceinline__ float bfhi(uint u) { return __uint_as_float(u & 0xFFFF0000u); }

// -------- h_orig (plane 3) = node_feats @ W_emb + b_emb ; fused p0/p1 ; fused init --------
__global__ void k_emb(const float* __restrict__ node_feats,
                      const float* __restrict__ W, const float* __restrict__ b,
                      const float* __restrict__ a0, const float* __restrict__ a1,
                      const float* __restrict__ a2) {
    __shared__ float Ws[9 * 64];
    __shared__ float fs[4][9];
    int tid = threadIdx.x;
    // fused zero-init (blocks 0..128 cover NSEG; block 0 covers buckets)
    if (blockIdx.x < 129) {
        int i = blockIdx.x * 256 + tid;
        if (i < NSEG) { g_counts[i] = 0; g_cur[i] = 0; }
        if (blockIdx.x == 0 && tid < 128) { g_bc[tid] = 0; g_bcur[tid] = 0; }
    }
    for (int i = tid; i < 576; i += 256) Ws[i] = W[i];
    int r0 = blockIdx.x * 4;
    if (tid < 36) {
        int r = r0 + tid / 9, k = tid % 9;
        float v = 0.f;
        if (r >= 1 && r <= NNODES) v = node_feats[(size_t)(r - 1) * 9 + k];
        fs[tid / 9][k] = v;
    }
    __syncthreads();
    int r = tid >> 6, j = tid & 63;
    int row = r0 + r;
    if (row >= NSEG) return;
    float acc = b[j];
#pragma unroll
    for (int k = 0; k < 9; k++) acc += fs[r][k] * Ws[k * 64 + j];
    float v = (row == 0) ? 0.f : acc;
    g_tfp[3 * PSZ + (size_t)row * 64 + j] = f2bf(v);
    const float* A[3] = {a0, a1, a2};
#pragma unroll
    for (int i = 0; i < 3; i++) {
        float d0 = v * A[i][j];
        WREDUCE(d0);
        if (j == 0) g_p0[i][row] = d0;
        float d1 = v * A[i][64 + j];
        WREDUCE(d1);
        if (j == 0) g_p1[i][row] = d1;
    }
}

// ---- prep (grid 4): blocks 0-2: w2[it] = W @ a2, c = a2.b ; block 3: wq10/cq ----
__global__ void k_prep_all(const float* __restrict__ W0, const float* __restrict__ W1,
                           const float* __restrict__ W2, const float* __restrict__ a0,
                           const float* __restrict__ a1, const float* __restrict__ a2,
                           const float* __restrict__ b0, const float* __restrict__ b1,
                           const float* __restrict__ b2,
                           const float* __restrict__ Wd, const float* __restrict__ bd) {
    int k = threadIdx.x;
    if (blockIdx.x < 3) {
        int it = blockIdx.x;
        const float* W = it == 0 ? W0 : (it == 1 ? W1 : W2);
        const float* a = it == 0 ? a0 : (it == 1 ? a1 : a2);
        const float* bias = it == 0 ? b0 : (it == 1 ? b1 : b2);
        int d = 64 * (it + 1);
        if (k < d) {
            float s = 0.f;
            for (int j = 0; j < d; j++) s += W[(size_t)k * d + j] * a[128 + j];
            g_w2[it][k] = s;
        } else if (k == 255) {
            float c = 0.f;
            for (int j = 0; j < d; j++) c += a[128 + j] * bias[j];
            g_w2[it][255] = c;
        }
    } else {
        // recompute w2_0 locally, then wq10 = W_dist @ w2_0, cq = b_dist.w2_0 + a0.b0
        __shared__ float w2s[64];
        if (k < 64) {
            float s = 0.f;
            for (int j = 0; j < 64; j++) s += W0[(size_t)k * 64 + j] * a0[128 + j];
            w2s[k] = s;
        }
        __syncthreads();
        if (k < 10) {
            float s = 0.f;
            for (int j = 0; j < 64; j++) s += Wd[(size_t)k * 64 + j] * w2s[j];
            g_wq10[k] = s;
        } else if (k == 64) {
            float s = 0.f, c = 0.f;
            for (int j = 0; j < 64; j++) { s += bd[j] * w2s[j]; c += a0[128 + j] * b0[j]; }
            g_cq = s + c;
        }
    }
}

// ---------------- CSR build over b_scope ----------------
__global__ void k_hist(const int* __restrict__ bs) {
    int e = blockIdx.x * 256 + threadIdx.x;
    if (e < NE) atomicAdd(&g_counts[bs[e]], 1);
}

__global__ void k_scan1() {
    __shared__ int s[256];
    int t = threadIdx.x, i = blockIdx.x * 256 + t;
    int v = (i < NSEG) ? g_counts[i] : 0;
    s[t] = v; __syncthreads();
    for (int off = 1; off < 256; off <<= 1) {
        int tmp = (t >= off) ? s[t - off] : 0;
        __syncthreads();
        s[t] += tmp;
        __syncthreads();
    }
    if (i < NSEG) g_excl[i] = s[t] - v;
    if (t == 255) g_bsum[blockIdx.x] = s[255];
}

__global__ void k_scan2(int nb) {
    __shared__ int s[256];
    int t = threadIdx.x;
    int v = (t < nb) ? g_bsum[t] : 0;
    s[t] = v; __syncthreads();
    for (int off = 1; off < 256; off <<= 1) {
        int tmp = (t >= off) ? s[t - off] : 0;
        __syncthreads();
        s[t] += tmp;
        __syncthreads();
    }
    if (t < nb) g_bsum[t] = s[t] - v;   // exclusive
}

// scan3 + fused bucket histogram
__global__ void k_scan3() {
    __shared__ int lh[128];
    int t = threadIdx.x;
    if (t < 128) lh[t] = 0;
    __syncthreads();
    int i = blockIdx.x * 256 + t;
    if (i < NSEG) {
        g_rowptr[i] = g_excl[i] + g_bsum[i >> 8];
        int cnt = g_counts[i];
        atomicAdd(&lh[cnt > 127 ? 127 : cnt], 1);
    }
    if (i == NSEG) g_rowptr[NSEG] = NE;
    __syncthreads();
    if (t < 128 && lh[t]) atomicAdd(&g_bc[t], lh[t]);
}

__global__ void k_scatter(const int* __restrict__ bs) {
    int e = blockIdx.x * 256 + threadIdx.x;
    if (e < NE) {
        int seg = bs[e];
        int pos = g_rowptr[seg] + atomicAdd(&g_cur[seg], 1);
        g_csr[pos] = e;
        g_epos[e] = pos;
    }
}

// two-level scatter with per-block local scan of bucket starts (no separate bscan)
__global__ void k_bscatter() {
    __shared__ int sc[128];
    __shared__ int lh[128];
    __shared__ int lbase[128];
    int tid = threadIdx.x;
    int bcv = 0;
    if (tid < 128) { bcv = g_bc[tid]; sc[tid] = bcv; lh[tid] = 0; }
    __syncthreads();
    for (int off = 1; off < 128; off <<= 1) {
        int tmp = (tid >= off && tid < 128) ? sc[tid - off] : 0;
        __syncthreads();
        if (tid < 128) sc[tid] += tmp;
        __syncthreads();
    }
    int seg = blockIdx.x * 256 + tid;
    int bin = 0, lpos = 0;
    bool valid = seg < NSEG;
    if (valid) {
        int cnt = g_rowptr[seg + 1] - g_rowptr[seg];
        bin = cnt > 127 ? 127 : cnt;
        lpos = atomicAdd(&lh[bin], 1);
    }
    __syncthreads();
    if (tid < 128 && lh[tid] > 0)
        lbase[tid] = atomicAdd(&g_bcur[tid], lh[tid]);
    __syncthreads();
    if (valid) {
        int bstart = sc[bin] - g_bc[bin];
        g_sorder[bstart + lbase[bin] + lpos] = seg;
    }
}

// ---- sorted index/logit-base arrays for attend<2/3> ----
__global__ void k_sortidx(const int* __restrict__ g1, const int* __restrict__ g2,
                          const int* __restrict__ see) {
    int pos = blockIdx.x * 256 + threadIdx.x;
    if (pos >= NE) return;
    int e = g_csr[pos];
    int a = g1[e], b = g2[e];
    g_g1s[pos] = a; g_g2s[pos] = b;
    int s0 = see[2 * (size_t)e], s1 = see[2 * (size_t)e + 1];
    g_pe1[pos] = g_p0[1][s0] + g_p1[1][s1];
    g_pe2[pos] = g_p0[2][s0] + g_p1[2][s1];
}

// -------- msg0 (bf16, CSR-sorted) + full iter-0 logit base lb0 --------
__global__ __launch_bounds__(256) void k_msg0(const float* __restrict__ fdg,
                                              const float* __restrict__ rij,
                                              const float* __restrict__ W,
                                              const float* __restrict__ b,
                                              const int* __restrict__ see) {
    __shared__ float Ws[10 * 64];
    __shared__ float bs[64];
    __shared__ float fs[64][10];
    __shared__ int eps[64];
    int tid = threadIdx.x;
    for (int i = tid; i < 640; i += 256) Ws[i] = W[i];
    if (tid < 64) bs[tid] = b[tid];
    int e0 = blockIdx.x * 64;
    for (int i = tid; i < 576; i += 256) fs[i / 9][i % 9] = fdg[(size_t)e0 * 9 + i];
    if (tid < 64) { fs[tid][9] = rij[e0 + tid]; eps[tid] = g_epos[e0 + tid]; }
    __syncthreads();
    int j = tid & 63;
#pragma unroll 4
    for (int p = 0; p < 16; p++) {
        int r = p * 4 + (tid >> 6);
        int e = e0 + r;
        int pos = eps[r];
        float acc = bs[j];
#pragma unroll
        for (int k = 0; k < 10; k++) acc += fs[r][k] * Ws[k * 64 + j];
        g_msg0s[(size_t)pos * 64 + j] = f2bf(acc);
        if (j == 0) {
            float q = g_cq;
#pragma unroll
            for (int k = 0; k < 10; k++) q += fs[r][k] * g_wq10[k];
            int s0 = see[2 * (size_t)e], s1 = see[2 * (size_t)e + 1];
            g_lb0[pos] = q + g_p0[0][s0] + g_p1[0][s1];
        }
    }
}

// -------- attend iter 0: fully streaming (CSR-sorted msg0 rows + lb0) --------
__global__ __launch_bounds__(256) void k_attend0() {
    int lane = threadIdx.x & 63;
    int sidx = blockIdx.x * 4 + (threadIdx.x >> 6);
    if (sidx >= NSEG) return;
    int seg = g_sorder[sidx];
    int beg = g_rowptr[seg], end = g_rowptr[seg + 1];
    int cnt = end - beg;
    float acc = 0.f;
    if (cnt > 0 && cnt <= 64) {
        float l = -1e30f;
        if (lane < cnt) {
            l = g_lb0[beg + lane];
            l = l > 0.f ? l : 0.2f * l;
        }
        float m = l;
        WREDMAX(m);
        float ex = (lane < cnt) ? __expf(l - m) : 0.f;
        float den = ex;
        WREDUCE(den);
        float w = ex / den;
        for (int t0 = 0; t0 < cnt; t0 += 8) {
            float wt[8]; int rw[8];
#pragma unroll
            for (int u = 0; u < 8; u++) {
                int su = t0 + u; su = su > 63 ? 63 : su;
                wt[u] = __shfl(w, su);
                int rr = t0 + u; rr = rr >= cnt ? cnt - 1 : rr;  // clamped row: cache-hot, w==0
                rw[u] = beg + rr;
            }
            ushort vm[8];
#pragma unroll
            for (int u = 0; u < 8; u++) vm[u] = g_msg0s[(size_t)rw[u] * 64 + lane];
#pragma unroll
            for (int u = 0; u < 8; u++) acc += wt[u] * bfs(vm[u]);
        }
    } else if (cnt > 64) {
        float m = -1e30f;
        for (int t = beg + lane; t < end; t += 64) {
            float l = g_lb0[t];
            l = l > 0.f ? l : 0.2f * l;
            m = fmaxf(m, l);
        }
        WREDMAX(m);
        float den = 0.f;
        for (int t = beg + lane; t < end; t += 64) {
            float l = g_lb0[t];
            l = l > 0.f ? l : 0.2f * l;
            den += __expf(l - m);
        }
        WREDUCE(den);
        float rden = 1.f / den;
        for (int t = beg; t < end; t++) {
            float l = g_lb0[t];
            l = l > 0.f ? l : 0.2f * l;
            acc += __expf(l - m) * rden * bfs(g_msg0s[(size_t)t * 64 + lane]);
        }
    }
    g_msumh[(size_t)seg * 192 + lane] = f2bf(acc);
}

// -------- attend iters 1/2: sorted index arrays, packed gathers --------
template <int NCM>
__global__ __launch_bounds__(256) void k_attendG() {
    const float* __restrict__ pe = (NCM == 2) ? g_pe1 : g_pe2;
    int lane = threadIdx.x & 63;
    int sidx = blockIdx.x * 4 + (threadIdx.x >> 6);
    if (sidx >= NSEG) return;
    int seg = g_sorder[sidx];
    int beg = g_rowptr[seg], end = g_rowptr[seg + 1];
    int cnt = end - beg;
    float acc[NCM];
#pragma unroll
    for (int c = 0; c < NCM; c++) acc[c] = 0.f;

    if (cnt > 0 && cnt <= 64) {
        float l = -1e30f;
        int i1 = 0, i2 = 0;
        if (lane < cnt) {
            i1 = g_g1s[beg + lane]; i2 = g_g2s[beg + lane];
            l = 0.5f * (g_q[i1] + g_q[i2]) + pe[beg + lane];
            l = l > 0.f ? l : 0.2f * l;
        }
        float m = l;
        WREDMAX(m);
        float ex = (lane < cnt) ? __expf(l - m) : 0.f;
        float den = ex;
        WREDUCE(den);
        float w = ex / den;
        for (int t0 = 0; t0 < cnt; t0 += 8) {
            float wt[8]; int a1[8], a2[8];
#pragma unroll
            for (int u = 0; u < 8; u++) {
                int su = t0 + u; su = su > 63 ? 63 : su;
                wt[u] = __shfl(w, su);
                a1[u] = __shfl(i1, su);    // 0 for lanes >= cnt -> row 0, cache-hot
                a2[u] = __shfl(i2, su);
            }
            if (NCM == 2) {
                uint ua[8], ub[8];
#pragma unroll
                for (int u = 0; u < 8; u++) {
                    ua[u] = g_pkA[(size_t)a1[u] * 64 + lane];
                    ub[u] = g_pkA[(size_t)a2[u] * 64 + lane];
                }
#pragma unroll
                for (int u = 0; u < 8; u++) {
                    float wh = 0.5f * wt[u];
                    acc[0] += wh * (bflo(ua[u]) + bflo(ub[u]));
                    acc[1] += wh * (bfhi(ua[u]) + bfhi(ub[u]));
                }
            } else {
                uint ua[8], ub[8];
                ushort ha[8], hb[8];
#pragma unroll
                for (int u = 0; u < 8; u++) {
                    size_t b1 = (size_t)a1[u] * 64 + lane, b2 = (size_t)a2[u] * 64 + lane;
                    ua[u] = g_pk01[b1]; ub[u] = g_pk01[b2];
                    ha[u] = g_tfp[3 * PSZ + b1]; hb[u] = g_tfp[3 * PSZ + b2];
                }
#pragma unroll
                for (int u = 0; u < 8; u++) {
                    float wh = 0.5f * wt[u];
                    acc[0] += wh * (bflo(ua[u]) + bflo(ub[u]));
                    acc[1] += wh * (bfhi(ua[u]) + bfhi(ub[u]));
                    acc[2] += wh * (bfs(ha[u]) + bfs(hb[u]));
                }
            }
        }
    } else if (cnt > 64) {
        float m = -1e30f;
        for (int t = beg + lane; t < end; t += 64) {
            float l = 0.5f * (g_q[g_g1s[t]] + g_q[g_g2s[t]]) + pe[t];
            l = l > 0.f ? l : 0.2f * l;
            m = fmaxf(m, l);
        }
        WREDMAX(m);
        float den = 0.f;
        for (int t = beg + lane; t < end; t += 64) {
            float l = 0.5f * (g_q[g_g1s[t]] + g_q[g_g2s[t]]) + pe[t];
            l = l > 0.f ? l : 0.2f * l;
            den += __expf(l - m);
        }
        WREDUCE(den);
        float rden = 1.f / den;
        for (int t = beg; t < end; t++) {
            float l = 0.5f * (g_q[g_g1s[t]] + g_q[g_g2s[t]]) + pe[t];
            l = l > 0.f ? l : 0.2f * l;
            float w = __expf(l - m) * rden;
            float wh = 0.5f * w;
            size_t b1 = (size_t)g_g1s[t] * 64 + lane, b2 = (size_t)g_g2s[t] * 64 + lane;
            if (NCM == 3) {
                uint ua = g_pk01[b1], ub = g_pk01[b2];
                acc[0] += wh * (bflo(ua) + bflo(ub));
                acc[1] += wh * (bfhi(ua) + bfhi(ub));
                acc[2] += wh * (bfs(g_tfp[3 * PSZ + b1]) + bfs(g_tfp[3 * PSZ + b2]));
            } else {
                uint ua = g_pkA[b1], ub = g_pkA[b2];
                acc[0] += wh * (bflo(ua) + bflo(ub));
                acc[1] += wh * (bfhi(ua) + bfhi(ub));
            }
        }
    }
#pragma unroll
    for (int c = 0; c < NCM; c++)
        g_msumh[(size_t)seg * 192 + lane + 64 * c] = f2bf(acc[c]);
}

// ----- iter0 GEMM: 32x64 tiles, K=64; writes pkA=(out0|h); fused q (w2[1]) -----
__global__ __launch_bounds__(256) void k_gemmA(const float* __restrict__ W,
                                               const float* __restrict__ bias) {
    __shared__ float As[64][36];   // [k][row]
    __shared__ float Bs[64][68];   // [k][col]
    int tid = threadIdx.x;
    int rb0 = blockIdx.x * 32;
    {
        int row = tid & 31, k8 = (tid >> 5) * 8;
        uint4 u = make_uint4(0, 0, 0, 0);
        if (rb0 + row < NSEG)
            u = *(const uint4*)&g_msumh[(size_t)(rb0 + row) * 192 + k8];
        As[k8 + 0][row] = bfs((ushort)(u.x & 0xFFFF));
        As[k8 + 1][row] = bfs((ushort)(u.x >> 16));
        As[k8 + 2][row] = bfs((ushort)(u.y & 0xFFFF));
        As[k8 + 3][row] = bfs((ushort)(u.y >> 16));
        As[k8 + 4][row] = bfs((ushort)(u.z & 0xFFFF));
        As[k8 + 5][row] = bfs((ushort)(u.z >> 16));
        As[k8 + 6][row] = bfs((ushort)(u.w & 0xFFFF));
        As[k8 + 7][row] = bfs((ushort)(u.w >> 16));
    }
    {
        int bk = tid >> 2, bc = (tid & 3) * 16;
#pragma unroll
        for (int q = 0; q < 4; q++)
            *(f4*)&Bs[bk][bc + q * 4] = *(const f4*)&W[(size_t)bk * 64 + bc + q * 4];
    }
    __syncthreads();
    int ty = tid >> 4, tx = tid & 15;
    float acc[2][4] = {{0.f, 0.f, 0.f, 0.f}, {0.f, 0.f, 0.f, 0.f}};
#pragma unroll 16
    for (int k = 0; k < 64; k++) {
        float a0 = As[k][ty * 2], a1 = As[k][ty * 2 + 1];
        f4 b = *(const f4*)&Bs[k][tx * 4];
        acc[0][0] += a0 * b.x; acc[0][1] += a0 * b.y; acc[0][2] += a0 * b.z; acc[0][3] += a0 * b.w;
        acc[1][0] += a1 * b.x; acc[1][1] += a1 * b.y; acc[1][2] += a1 * b.z; acc[1][3] += a1 * b.w;
    }
#pragma unroll
    for (int r = 0; r < 2; r++) {
        int row = rb0 + ty * 2 + r;
        bool valid = row < NSEG;
        bool nonempty = valid && (g_rowptr[row + 1] > g_rowptr[row]);
        ushort4 h4 = make_ushort4(0, 0, 0, 0);
        if (valid) h4 = *(const ushort4*)&g_tfp[3 * PSZ + (size_t)row * 64 + tx * 4];
        const ushort hb[4] = {h4.x, h4.y, h4.z, h4.w};
        uint pk[4];
        float qp = 0.f;
#pragma unroll
        for (int j = 0; j < 4; j++) {
            float v = acc[r][j] + bias[tx * 4 + j];
            if (!nonempty) v = 0.f;
            v = v > 0.f ? v : (__expf(v) - 1.f);
            pk[j] = (uint)f2bf(v) | ((uint)hb[j] << 16);
            qp += v * g_w2[1][tx * 4 + j] + bfs(hb[j]) * g_w2[1][64 + tx * 4 + j];
        }
        if (valid) {
            uint4 o; o.x = pk[0]; o.y = pk[1]; o.z = pk[2]; o.w = pk[3];
            *(uint4*)&g_pkA[(size_t)row * 64 + tx * 4] = o;
        }
        qp += __shfl_xor(qp, 1); qp += __shfl_xor(qp, 2);
        qp += __shfl_xor(qp, 4); qp += __shfl_xor(qp, 8);
        if (valid && tx == 0) g_q[row] = qp + g_w2[1][255];
    }
}

// ----- iter1 GEMM: 32x128 tiles, K=128; writes pk01=(out0|out1); fused q (w2[2]) -----
__global__ __launch_bounds__(256) void k_gemmB(const float* __restrict__ W,
                                               const float* __restrict__ bias) {
    __shared__ float As[32][36];
    __shared__ float Bs[32][132];
    int tid = threadIdx.x;
    int rb0 = blockIdx.x * 32;
    int ty = tid >> 4, tx = tid & 15;
    float aclo[2][4] = {{0.f,0.f,0.f,0.f},{0.f,0.f,0.f,0.f}};
    float achi[2][4] = {{0.f,0.f,0.f,0.f},{0.f,0.f,0.f,0.f}};
    for (int kk = 0; kk < 128; kk += 32) {
        {
            int row = tid & 31, k4 = (tid >> 5) * 4;
            uint2 u = make_uint2(0, 0);
            if (rb0 + row < NSEG)
                u = *(const uint2*)&g_msumh[(size_t)(rb0 + row) * 192 + kk + k4];
            As[k4 + 0][row] = bfs((ushort)(u.x & 0xFFFF));
            As[k4 + 1][row] = bfs((ushort)(u.x >> 16));
            As[k4 + 2][row] = bfs((ushort)(u.y & 0xFFFF));
            As[k4 + 3][row] = bfs((ushort)(u.y >> 16));
        }
        {
            int bk = tid >> 3, bc = (tid & 7) * 16;
#pragma unroll
            for (int q = 0; q < 4; q++)
                *(f4*)&Bs[bk][bc + q * 4] = *(const f4*)&W[(size_t)(kk + bk) * 128 + bc + q * 4];
        }
        __syncthreads();
#pragma unroll
        for (int k = 0; k < 32; k++) {
            float a0 = As[k][ty * 2], a1 = As[k][ty * 2 + 1];
            f4 bl = *(const f4*)&Bs[k][tx * 4];
            f4 bh = *(const f4*)&Bs[k][64 + tx * 4];
            aclo[0][0] += a0 * bl.x; aclo[0][1] += a0 * bl.y; aclo[0][2] += a0 * bl.z; aclo[0][3] += a0 * bl.w;
            aclo[1][0] += a1 * bl.x; aclo[1][1] += a1 * bl.y; aclo[1][2] += a1 * bl.z; aclo[1][3] += a1 * bl.w;
            achi[0][0] += a0 * bh.x; achi[0][1] += a0 * bh.y; achi[0][2] += a0 * bh.z; achi[0][3] += a0 * bh.w;
            achi[1][0] += a1 * bh.x; achi[1][1] += a1 * bh.y; achi[1][2] += a1 * bh.z; achi[1][3] += a1 * bh.w;
        }
        __syncthreads();
    }
#pragma unroll
    for (int r = 0; r < 2; r++) {
        int row = rb0 + ty * 2 + r;
        bool valid = row < NSEG;
        bool nonempty = valid && (g_rowptr[row + 1] > g_rowptr[row]);
        ushort4 h4 = make_ushort4(0, 0, 0, 0);
        if (valid) h4 = *(const ushort4*)&g_tfp[3 * PSZ + (size_t)row * 64 + tx * 4];
        const ushort hb[4] = {h4.x, h4.y, h4.z, h4.w};
        uint pk[4];
        float qp = 0.f;
#pragma unroll
        for (int j = 0; j < 4; j++) {
            float vl = aclo[r][j] + bias[tx * 4 + j];
            float vh = achi[r][j] + bias[64 + tx * 4 + j];
            if (!nonempty) { vl = 0.f; vh = 0.f; }
            vl = vl > 0.f ? vl : (__expf(vl) - 1.f);
            vh = vh > 0.f ? vh : (__expf(vh) - 1.f);
            pk[j] = (uint)f2bf(vl) | ((uint)f2bf(vh) << 16);
            qp += vl * g_w2[2][tx * 4 + j] + vh * g_w2[2][64 + tx * 4 + j] +
                  bfs(hb[j]) * g_w2[2][128 + tx * 4 + j];
        }
        if (valid) {
            uint4 o; o.x = pk[0]; o.y = pk[1]; o.z = pk[2]; o.w = pk[3];
            *(uint4*)&g_pk01[(size_t)row * 64 + tx * 4] = o;
        }
        qp += __shfl_xor(qp, 1); qp += __shfl_xor(qp, 2);
        qp += __shfl_xor(qp, 4); qp += __shfl_xor(qp, 8);
        if (valid && tx == 0) g_q[row] = qp + g_w2[2][255];
    }
}

// ----- iter2 GEMM (64x64 col-split tiles, K=192): plane cslot = mask*elu(msumh @ W + b) -----
__global__ __launch_bounds__(256) void k_gemmC(const float* __restrict__ W,
                                               const float* __restrict__ bias) {
    constexpr int D = 192;
    __shared__ float As[32][68];
    __shared__ float Bs[32][68];
    int tid = threadIdx.x;
    int rb0 = blockIdx.x * 64;
    int cslot = blockIdx.y;
    int cb0 = cslot * 64;
    int ty = tid >> 4, tx = tid & 15;
    float acc[4][4];
#pragma unroll
    for (int r = 0; r < 4; r++)
#pragma unroll
        for (int j = 0; j < 4; j++) acc[r][j] = 0.f;

    int arow = tid & 63, aoct = tid >> 6;
    int bk = tid >> 3, bc8 = (tid & 7) * 8;
    for (int kk = 0; kk < D; kk += 32) {
        {
            uint4 u = make_uint4(0, 0, 0, 0);
            if (rb0 + arow < NSEG)
                u = *(const uint4*)&g_msumh[(size_t)(rb0 + arow) * 192 + kk + aoct * 8];
            int kb = aoct * 8;
            As[kb + 0][arow] = bfs((ushort)(u.x & 0xFFFF));
            As[kb + 1][arow] = bfs((ushort)(u.x >> 16));
            As[kb + 2][arow] = bfs((ushort)(u.y & 0xFFFF));
            As[kb + 3][arow] = bfs((ushort)(u.y >> 16));
            As[kb + 4][arow] = bfs((ushort)(u.z & 0xFFFF));
            As[kb + 5][arow] = bfs((ushort)(u.z >> 16));
            As[kb + 6][arow] = bfs((ushort)(u.w & 0xFFFF));
            As[kb + 7][arow] = bfs((ushort)(u.w >> 16));
        }
        {
            f4 b0 = *(const f4*)&W[(size_t)(kk + bk) * D + cb0 + bc8];
            f4 b1 = *(const f4*)&W[(size_t)(kk + bk) * D + cb0 + bc8 + 4];
            *(f4*)&Bs[bk][bc8] = b0;
            *(f4*)&Bs[bk][bc8 + 4] = b1;
        }
        __syncthreads();
#pragma unroll
        for (int k = 0; k < 32; k++) {
            f4 a = *(const f4*)&As[k][ty * 4];
            f4 b = *(const f4*)&Bs[k][tx * 4];
            acc[0][0] += a.x * b.x; acc[0][1] += a.x * b.y; acc[0][2] += a.x * b.z; acc[0][3] += a.x * b.w;
            acc[1][0] += a.y * b.x; acc[1][1] += a.y * b.y; acc[1][2] += a.y * b.z; acc[1][3] += a.y * b.w;
            acc[2][0] += a.z * b.x; acc[2][1] += a.z * b.y; acc[2][2] += a.z * b.z; acc[2][3] += a.z * b.w;
            acc[3][0] += a.w * b.x; acc[3][1] += a.w * b.y; acc[3][2] += a.w * b.z; acc[3][3] += a.w * b.w;
        }
        __syncthreads();
    }
#pragma unroll
    for (int r = 0; r < 4; r++) {
        int row = rb0 + ty * 4 + r;
        if (row >= NSEG) continue;
        bool nonempty = g_rowptr[row + 1] > g_rowptr[row];
        ushort4 pk;
        ushort* p = (ushort*)&pk;
#pragma unroll
        for (int j = 0; j < 4; j++) {
            float v = acc[r][j] + bias[cb0 + tx * 4 + j];
            if (!nonempty) v = 0.f;
            v = v > 0.f ? v : (__expf(v) - 1.f);
            p[j] = f2bf(v);
        }
        *(ushort4*)&g_tfp[(size_t)cslot * PSZ + (size_t)row * 64 + tx * 4] = pk;
    }
}

// ---------------- final: per-molecule gather-sum ----------------
__global__ void k_final(const int* __restrict__ lscope, float* __restrict__ out) {
    __shared__ int idx[32];
    __shared__ float sm[4][256];
    int m = blockIdx.x, tid = threadIdx.x, w = tid >> 6, lane = tid & 63;
    if (tid < 32) idx[tid] = lscope[m * 32 + tid];
    __syncthreads();
    float a0 = 0.f, a1 = 0.f, a2 = 0.f, a3 = 0.f;
#pragma unroll
    for (int j = w * 8; j < w * 8 + 8; j++) {
        size_t base = (size_t)idx[j] * 64 + lane;
        a0 += bfs(g_tfp[base]);
        a1 += bfs(g_tfp[PSZ + base]);
        a2 += bfs(g_tfp[2 * PSZ + base]);
        a3 += bfs(g_tfp[3 * PSZ + base]);
    }
    sm[w][lane] = a0; sm[w][64 + lane] = a1; sm[w][128 + lane] = a2; sm[w][192 + lane] = a3;
    __syncthreads();
    out[(size_t)m * 256 + tid] = sm[0][tid] + sm[1][tid] + sm[2][tid] + sm[3][tid];
}

extern "C" void kernel_launch(void* const* d_in, const int* in_sizes, int n_in,
                              void* d_out, int out_size, void* d_ws, size_t ws_size,
                              hipStream_t stream) {
    const float* node_feats = (const float*)d_in[0];
    const float* fdg        = (const float*)d_in[1];
    const float* rij        = (const float*)d_in[2];
    const int*   see        = (const int*)d_in[3];
    const int*   b_scope    = (const int*)d_in[4];
    const int*   scope_up   = (const int*)d_in[5];
    const int*   scope_lig  = (const int*)d_in[6];
    const int*   l_scope    = (const int*)d_in[7];
    const float* W_emb      = (const float*)d_in[8];
    const float* b_emb      = (const float*)d_in[9];
    const float* W_dist     = (const float*)d_in[10];
    const float* b_dist     = (const float*)d_in[11];
    const float* fc_W[3]   = {(const float*)d_in[12], (const float*)d_in[15], (const float*)d_in[18]};
    const float* fc_b[3]   = {(const float*)d_in[13], (const float*)d_in[16], (const float*)d_in[19]};
    const float* attn_a[3] = {(const float*)d_in[14], (const float*)d_in[17], (const float*)d_in[20]};

    k_emb<<<8193, 256, 0, stream>>>(node_feats, W_emb, b_emb,
                                    attn_a[0], attn_a[1], attn_a[2]);
    k_prep_all<<<4, 256, 0, stream>>>(fc_W[0], fc_W[1], fc_W[2],
                                      attn_a[0], attn_a[1], attn_a[2],
                                      fc_b[0], fc_b[1], fc_b[2], W_dist, b_dist);
    k_hist<<<NE / 256, 256, 0, stream>>>(b_scope);
    k_scan1<<<129, 256, 0, stream>>>();
    k_scan2<<<1, 256, 0, stream>>>(129);
    k_scan3<<<129, 256, 0, stream>>>();
    k_scatter<<<NE / 256, 256, 0, stream>>>(b_scope);
    k_bscatter<<<129, 256, 0, stream>>>();
    k_sortidx<<<NE / 256, 256, 0, stream>>>(scope_lig, scope_up, see);
    k_msg0<<<NE / 64, 256, 0, stream>>>(fdg, rij, W_dist, b_dist, see);

    // iter 0 (streaming)
    k_attend0<<<8193, 256, 0, stream>>>();
    k_gemmA<<<1025, 256, 0, stream>>>(fc_W[0], fc_b[0]);
    // iter 1
    k_attendG<2><<<8193, 256, 0, stream>>>();
    k_gemmB<<<1025, 256, 0, stream>>>(fc_W[1], fc_b[1]);
    // iter 2
    k_attendG<3><<<8193, 256, 0, stream>>>();
    k_gemmC<<<dim3(513, 3), 256, 0, stream>>>(fc_W[2], fc_b[2]);

    k_final<<<2048, 256, 0, stream>>>(l_scope, (float*)d_out);
}

// Round 13
// 294.233 us; speedup vs baseline: 1.4618x; 1.0482x over previous
//
#include <hip/hip_runtime.h>
#include <cstdint>
#include <cstddef>

#define NSEG 32769      // N_NODES + 1 (row 0 is the zero row)
#define NNODES 32768
#define NE 262144
#define PSZ ((size_t)NSEG * 64)   // one tf plane

using f4 = float4;

// ---------------- static device scratch ----------------
__device__ ushort g_tfp[4 * PSZ];                 // planes 0..2 out cols (iter2), plane 3 h_orig
__device__ uint   g_pkA[PSZ];                     // (out0 | h)  after iter0
__device__ uint   g_pk01[PSZ];                    // (out0 | out1) after iter1 gemm
__device__ float  g_lb0[NE];                      // iter-0 full logit, CSR-sorted
__device__ f4     g_xs0[NE];                      // x0..3  (CSR-sorted edge features)
__device__ f4     g_xs1[NE];                      // x4..7
__device__ float2 g_xs2[NE];                      // x8,x9
__device__ ushort g_msumh[(size_t)NSEG * 192];    // bf16 row-major (K width 192)
__device__ float  g_q[NSEG];
__device__ float  g_p0[3][NSEG];
__device__ float  g_p1[3][NSEG];
__device__ float  g_w2[3][256];                   // w2 = W @ a2 in [0,d); c = a2.b at [255]
__device__ float  g_wq10[10];                     // W_dist @ w2_0
__device__ float  g_cq;                           // b_dist.w2_0 + a0.b0
__device__ float  g_wc[640];                      // Wc = W_dist @ fc_W0 (10x64)
__device__ float  g_bcc[64];                      // b_dist @ fc_W0 + fc_b0
__device__ int    g_counts[NSEG];
__device__ int    g_excl[NSEG];
__device__ int    g_bsum[1024];
__device__ int    g_rowptr[NSEG + 1];
__device__ int    g_cur[NSEG];
__device__ int    g_csr[NE];
__device__ int    g_g1s[NE];                      // gather indices, CSR-sorted
__device__ int    g_g2s[NE];
__device__ float  g_pe1[NE];                      // p0[1][s0]+p1[1][s1], CSR-sorted
__device__ float  g_pe2[NE];                      // p0[2][s0]+p1[2][s1], CSR-sorted
__device__ int    g_bc[128];
__device__ int    g_bcur[128];
__device__ int    g_sorder[NSEG];

#define WREDUCE(x) { x += __shfl_xor(x, 32); x += __shfl_xor(x, 16); \
                     x += __shfl_xor(x, 8);  x += __shfl_xor(x, 4);  \
                     x += __shfl_xor(x, 2);  x += __shfl_xor(x, 1); }
#define WREDMAX(x) { x = fmaxf(x, __shfl_xor(x, 32)); x = fmaxf(x, __shfl_xor(x, 16)); \
                     x = fmaxf(x, __shfl_xor(x, 8));  x = fmaxf(x, __shfl_xor(x, 4));  \
                     x = fmaxf(x, __shfl_xor(x, 2));  x = fmaxf(x, __shfl_xor(x, 1)); }

__device__ __forceinline__ ushort f2bf(float x) {
    uint u = __float_as_uint(x);
    u += 0x7FFF + ((u >> 16) & 1);
    return (ushort)(u >> 16);
}
__device__ __forceinline__ float bfs(ushort u) { return __uint_as_float(((uint)u) << 16); }
__device__ __forceinline__ float bflo(uint u) { return __uint_as_float(u << 16); }
__device__ __forceinline__ float bfhi(uint u) { return __uint_as_float(u & 0xFFFF0000u); }

// -------- h_orig (plane 3) = node_feats @ W_emb + b_emb ; fused p0/p1 ; fused init --------
__global__ void k_emb(const float* __restrict__ node_feats,
                      const float* __restrict__ W, const float* __restrict__ b,
                      const float* __restrict__ a0, const float* __restrict__ a1,
                      const float* __restrict__ a2) {
    __shared__ float Ws[9 * 64];
    __shared__ float fs[4][9];
    int tid = threadIdx.x;
    if (blockIdx.x < 129) {
        int i = blockIdx.x * 256 + tid;
        if (i < NSEG) { g_counts[i] = 0; g_cur[i] = 0; }
        if (blockIdx.x == 0 && tid < 128) { g_bc[tid] = 0; g_bcur[tid] = 0; }
    }
    for (int i = tid; i < 576; i += 256) Ws[i] = W[i];
    int r0 = blockIdx.x * 4;
    if (tid < 36) {
        int r = r0 + tid / 9, k = tid % 9;
        float v = 0.f;
        if (r >= 1 && r <= NNODES) v = node_feats[(size_t)(r - 1) * 9 + k];
        fs[tid / 9][k] = v;
    }
    __syncthreads();
    int r = tid >> 6, j = tid & 63;
    int row = r0 + r;
    if (row >= NSEG) return;
    float acc = b[j];
#pragma unroll
    for (int k = 0; k < 9; k++) acc += fs[r][k] * Ws[k * 64 + j];
    float v = (row == 0) ? 0.f : acc;
    g_tfp[3 * PSZ + (size_t)row * 64 + j] = f2bf(v);
    const float* A[3] = {a0, a1, a2};
#pragma unroll
    for (int i = 0; i < 3; i++) {
        float d0 = v * A[i][j];
        WREDUCE(d0);
        if (j == 0) g_p0[i][row] = d0;
        float d1 = v * A[i][64 + j];
        WREDUCE(d1);
        if (j == 0) g_p1[i][row] = d1;
    }
}

// ---- prep (grid 5): 0-2: w2[it]; 3: wq10/cq; 4: Wc/bcc ----
__global__ void k_prep_all(const float* __restrict__ W0, const float* __restrict__ W1,
                           const float* __restrict__ W2, const float* __restrict__ a0,
                           const float* __restrict__ a1, const float* __restrict__ a2,
                           const float* __restrict__ b0, const float* __restrict__ b1,
                           const float* __restrict__ b2,
                           const float* __restrict__ Wd, const float* __restrict__ bd) {
    int k = threadIdx.x;
    if (blockIdx.x < 3) {
        int it = blockIdx.x;
        const float* W = it == 0 ? W0 : (it == 1 ? W1 : W2);
        const float* a = it == 0 ? a0 : (it == 1 ? a1 : a2);
        const float* bias = it == 0 ? b0 : (it == 1 ? b1 : b2);
        int d = 64 * (it + 1);
        if (k < d) {
            float s = 0.f;
            for (int j = 0; j < d; j++) s += W[(size_t)k * d + j] * a[128 + j];
            g_w2[it][k] = s;
        } else if (k == 255) {
            float c = 0.f;
            for (int j = 0; j < d; j++) c += a[128 + j] * bias[j];
            g_w2[it][255] = c;
        }
    } else if (blockIdx.x == 3) {
        __shared__ float w2s[64];
        if (k < 64) {
            float s = 0.f;
            for (int j = 0; j < 64; j++) s += W0[(size_t)k * 64 + j] * a0[128 + j];
            w2s[k] = s;
        }
        __syncthreads();
        if (k < 10) {
            float s = 0.f;
            for (int j = 0; j < 64; j++) s += Wd[(size_t)k * 64 + j] * w2s[j];
            g_wq10[k] = s;
        } else if (k == 64) {
            float s = 0.f, c = 0.f;
            for (int j = 0; j < 64; j++) { s += bd[j] * w2s[j]; c += a0[128 + j] * b0[j]; }
            g_cq = s + c;
        }
    } else {
        // Wc = Wd @ W0 (10x64), bcc = bd @ W0 + b0
        for (int t = k; t < 640; t += 256) {
            int kk = t >> 6, j = t & 63;
            float s = 0.f;
            for (int m = 0; m < 64; m++) s += Wd[kk * 64 + m] * W0[(size_t)m * 64 + j];
            g_wc[t] = s;
        }
        if (k < 64) {
            float s = b0[k];
            for (int m = 0; m < 64; m++) s += bd[m] * W0[(size_t)m * 64 + k];
            g_bcc[k] = s;
        }
    }
}

// ---------------- CSR build over b_scope ----------------
__global__ void k_hist(const int* __restrict__ bs) {
    int e = blockIdx.x * 256 + threadIdx.x;
    if (e < NE) atomicAdd(&g_counts[bs[e]], 1);
}

__global__ void k_scan1() {
    __shared__ int s[256];
    int t = threadIdx.x, i = blockIdx.x * 256 + t;
    int v = (i < NSEG) ? g_counts[i] : 0;
    s[t] = v; __syncthreads();
    for (int off = 1; off < 256; off <<= 1) {
        int tmp = (t >= off) ? s[t - off] : 0;
        __syncthreads();
        s[t] += tmp;
        __syncthreads();
    }
    if (i < NSEG) g_excl[i] = s[t] - v;
    if (t == 255) g_bsum[blockIdx.x] = s[255];
}

__global__ void k_scan2(int nb) {
    __shared__ int s[256];
    int t = threadIdx.x;
    int v = (t < nb) ? g_bsum[t] : 0;
    s[t] = v; __syncthreads();
    for (int off = 1; off < 256; off <<= 1) {
        int tmp = (t >= off) ? s[t - off] : 0;
        __syncthreads();
        s[t] += tmp;
        __syncthreads();
    }
    if (t < nb) g_bsum[t] = s[t] - v;   // exclusive
}

// scan3 + fused bucket histogram
__global__ void k_scan3() {
    __shared__ int lh[128];
    int t = threadIdx.x;
    if (t < 128) lh[t] = 0;
    __syncthreads();
    int i = blockIdx.x * 256 + t;
    if (i < NSEG) {
        g_rowptr[i] = g_excl[i] + g_bsum[i >> 8];
        int cnt = g_counts[i];
        atomicAdd(&lh[cnt > 127 ? 127 : cnt], 1);
    }
    if (i == NSEG) g_rowptr[NSEG] = NE;
    __syncthreads();
    if (t < 128 && lh[t]) atomicAdd(&g_bc[t], lh[t]);
}

__global__ void k_scatter(const int* __restrict__ bs) {
    int e = blockIdx.x * 256 + threadIdx.x;
    if (e < NE) {
        int seg = bs[e];
        int pos = g_rowptr[seg] + atomicAdd(&g_cur[seg], 1);
        g_csr[pos] = e;
    }
}

// two-level scatter with per-block local scan of bucket starts
__global__ void k_bscatter() {
    __shared__ int sc[128];
    __shared__ int lh[128];
    __shared__ int lbase[128];
    int tid = threadIdx.x;
    int bcv = 0;
    if (tid < 128) { bcv = g_bc[tid]; sc[tid] = bcv; lh[tid] = 0; }
    __syncthreads();
    for (int off = 1; off < 128; off <<= 1) {
        int tmp = (tid >= off && tid < 128) ? sc[tid - off] : 0;
        __syncthreads();
        if (tid < 128) sc[tid] += tmp;
        __syncthreads();
    }
    int seg = blockIdx.x * 256 + tid;
    int bin = 0, lpos = 0;
    bool valid = seg < NSEG;
    if (valid) {
        int cnt = g_rowptr[seg + 1] - g_rowptr[seg];
        bin = cnt > 127 ? 127 : cnt;
        lpos = atomicAdd(&lh[bin], 1);
    }
    __syncthreads();
    if (tid < 128 && lh[tid] > 0)
        lbase[tid] = atomicAdd(&g_bcur[tid], lh[tid]);
    __syncthreads();
    if (valid) {
        int bstart = sc[bin] - g_bc[bin];
        g_sorder[bstart + lbase[bin] + lpos] = seg;
    }
}

// ---- sorted arrays: gather idx, pe1/pe2, edge features xs, iter-0 logit lb0 ----
__global__ void k_sortidx(const int* __restrict__ g1, const int* __restrict__ g2,
                          const int* __restrict__ see,
                          const float* __restrict__ fdg, const float* __restrict__ rij) {
    __shared__ float wq[10];
    __shared__ float cqs;
    if (threadIdx.x < 10) wq[threadIdx.x] = g_wq10[threadIdx.x];
    if (threadIdx.x == 10) cqs = g_cq;
    __syncthreads();
    int pos = blockIdx.x * 256 + threadIdx.x;
    if (pos >= NE) return;
    int e = g_csr[pos];
    g_g1s[pos] = g1[e]; g_g2s[pos] = g2[e];
    int s0 = see[2 * (size_t)e], s1 = see[2 * (size_t)e + 1];
    g_pe1[pos] = g_p0[1][s0] + g_p1[1][s1];
    g_pe2[pos] = g_p0[2][s0] + g_p1[2][s1];
    float x[10];
#pragma unroll
    for (int k = 0; k < 9; k++) x[k] = fdg[(size_t)e * 9 + k];
    x[9] = rij[e];
    float q = cqs;
#pragma unroll
    for (int k = 0; k < 10; k++) q += x[k] * wq[k];
    g_lb0[pos] = q + g_p0[0][s0] + g_p1[0][s1];
    g_xs0[pos] = make_float4(x[0], x[1], x[2], x[3]);
    g_xs1[pos] = make_float4(x[4], x[5], x[6], x[7]);
    g_xs2[pos] = make_float2(x[8], x[9]);
}

// -------- fused attend0 + iter-0 "GEMM": out0 = elu(y @ Wc + bcc), pack pkA, fused q --------
__global__ __launch_bounds__(256) void k_attend0() {
    __shared__ float Wcs[640];
    __shared__ float bcs[64];
    int tid = threadIdx.x;
    for (int i = tid; i < 640; i += 256) Wcs[i] = g_wc[i];
    if (tid < 64) bcs[tid] = g_bcc[tid];
    __syncthreads();
    int lane = tid & 63;
    int sidx = blockIdx.x * 4 + (tid >> 6);
    if (sidx >= NSEG) return;
    int seg = g_sorder[sidx];
    int beg = g_rowptr[seg], end = g_rowptr[seg + 1];
    int cnt = end - beg;
    float y[10];
#pragma unroll
    for (int k = 0; k < 10; k++) y[k] = 0.f;

    if (cnt > 0 && cnt <= 64) {
        float l = -1e30f;
        float x[10];
#pragma unroll
        for (int k = 0; k < 10; k++) x[k] = 0.f;
        if (lane < cnt) {
            l = g_lb0[beg + lane];
            l = l > 0.f ? l : 0.2f * l;
            f4 a = g_xs0[beg + lane];
            f4 b = g_xs1[beg + lane];
            float2 c = g_xs2[beg + lane];
            x[0] = a.x; x[1] = a.y; x[2] = a.z; x[3] = a.w;
            x[4] = b.x; x[5] = b.y; x[6] = b.z; x[7] = b.w;
            x[8] = c.x; x[9] = c.y;
        }
        float m = l;
        WREDMAX(m);
        float ex = (lane < cnt) ? __expf(l - m) : 0.f;
        float den = ex;
        WREDUCE(den);
        float w = ex / den;
#pragma unroll
        for (int k = 0; k < 10; k++) {
            float s = w * x[k];
            WREDUCE(s);
            y[k] = s;        // every lane now holds the full y
        }
    } else if (cnt > 64) {
        float m = -1e30f;
        for (int t = beg + lane; t < end; t += 64) {
            float l = g_lb0[t];
            l = l > 0.f ? l : 0.2f * l;
            m = fmaxf(m, l);
        }
        WREDMAX(m);
        float den = 0.f;
        for (int t = beg + lane; t < end; t += 64) {
            float l = g_lb0[t];
            l = l > 0.f ? l : 0.2f * l;
            den += __expf(l - m);
        }
        WREDUCE(den);
        float rden = 1.f / den;
        float part[10];
#pragma unroll
        for (int k = 0; k < 10; k++) part[k] = 0.f;
        for (int t = beg + lane; t < end; t += 64) {
            float l = g_lb0[t];
            l = l > 0.f ? l : 0.2f * l;
            float w = __expf(l - m) * rden;
            f4 a = g_xs0[t]; f4 b = g_xs1[t]; float2 c = g_xs2[t];
            part[0] += w * a.x; part[1] += w * a.y; part[2] += w * a.z; part[3] += w * a.w;
            part[4] += w * b.x; part[5] += w * b.y; part[6] += w * b.z; part[7] += w * b.w;
            part[8] += w * c.x; part[9] += w * c.y;
        }
#pragma unroll
        for (int k = 0; k < 10; k++) {
            WREDUCE(part[k]);
            y[k] = part[k];
        }
    }
    // out0 (lane = column), elu, mask empty, pack with h, fused q (w2[1])
    float o = bcs[lane];
#pragma unroll
    for (int k = 0; k < 10; k++) o += y[k] * Wcs[k * 64 + lane];
    if (cnt == 0) o = 0.f;
    o = o > 0.f ? o : (__expf(o) - 1.f);
    ushort h = g_tfp[3 * PSZ + (size_t)seg * 64 + lane];
    g_pkA[(size_t)seg * 64 + lane] = (uint)f2bf(o) | ((uint)h << 16);
    float qp = o * g_w2[1][lane] + bfs(h) * g_w2[1][64 + lane];
    WREDUCE(qp);
    if (lane == 0) g_q[seg] = qp + g_w2[1][255];
}

// -------- attend iters 1/2: sorted index arrays, packed gathers --------
template <int NCM>
__global__ __launch_bounds__(256) void k_attendG() {
    const float* __restrict__ pe = (NCM == 2) ? g_pe1 : g_pe2;
    int lane = threadIdx.x & 63;
    int sidx = blockIdx.x * 4 + (threadIdx.x >> 6);
    if (sidx >= NSEG) return;
    int seg = g_sorder[sidx];
    int beg = g_rowptr[seg], end = g_rowptr[seg + 1];
    int cnt = end - beg;
    float acc[NCM];
#pragma unroll
    for (int c = 0; c < NCM; c++) acc[c] = 0.f;

    if (cnt > 0 && cnt <= 64) {
        float l = -1e30f;
        int i1 = 0, i2 = 0;
        if (lane < cnt) {
            i1 = g_g1s[beg + lane]; i2 = g_g2s[beg + lane];
            l = 0.5f * (g_q[i1] + g_q[i2]) + pe[beg + lane];
            l = l > 0.f ? l : 0.2f * l;
        }
        float m = l;
        WREDMAX(m);
        float ex = (lane < cnt) ? __expf(l - m) : 0.f;
        float den = ex;
        WREDUCE(den);
        float w = ex / den;
        for (int t0 = 0; t0 < cnt; t0 += 8) {
            float wt[8]; int a1[8], a2[8];
#pragma unroll
            for (int u = 0; u < 8; u++) {
                int su = t0 + u; su = su > 63 ? 63 : su;
                wt[u] = __shfl(w, su);
                a1[u] = __shfl(i1, su);
                a2[u] = __shfl(i2, su);
            }
            if (NCM == 2) {
                uint ua[8], ub[8];
#pragma unroll
                for (int u = 0; u < 8; u++) {
                    ua[u] = g_pkA[(size_t)a1[u] * 64 + lane];
                    ub[u] = g_pkA[(size_t)a2[u] * 64 + lane];
                }
#pragma unroll
                for (int u = 0; u < 8; u++) {
                    float wh = 0.5f * wt[u];
                    acc[0] += wh * (bflo(ua[u]) + bflo(ub[u]));
                    acc[1] += wh * (bfhi(ua[u]) + bfhi(ub[u]));
                }
            } else {
                uint ua[8], ub[8];
                ushort ha[8], hb[8];
#pragma unroll
                for (int u = 0; u < 8; u++) {
                    size_t b1 = (size_t)a1[u] * 64 + lane, b2 = (size_t)a2[u] * 64 + lane;
                    ua[u] = g_pk01[b1]; ub[u] = g_pk01[b2];
                    ha[u] = g_tfp[3 * PSZ + b1]; hb[u] = g_tfp[3 * PSZ + b2];
                }
#pragma unroll
                for (int u = 0; u < 8; u++) {
                    float wh = 0.5f * wt[u];
                    acc[0] += wh * (bflo(ua[u]) + bflo(ub[u]));
                    acc[1] += wh * (bfhi(ua[u]) + bfhi(ub[u]));
                    acc[2] += wh * (bfs(ha[u]) + bfs(hb[u]));
                }
            }
        }
    } else if (cnt > 64) {
        float m = -1e30f;
        for (int t = beg + lane; t < end; t += 64) {
            float l = 0.5f * (g_q[g_g1s[t]] + g_q[g_g2s[t]]) + pe[t];
            l = l > 0.f ? l : 0.2f * l;
            m = fmaxf(m, l);
        }
        WREDMAX(m);
        float den = 0.f;
        for (int t = beg + lane; t < end; t += 64) {
            float l = 0.5f * (g_q[g_g1s[t]] + g_q[g_g2s[t]]) + pe[t];
            l = l > 0.f ? l : 0.2f * l;
            den += __expf(l - m);
        }
        WREDUCE(den);
        float rden = 1.f / den;
        for (int t = beg; t < end; t++) {
            float l = 0.5f * (g_q[g_g1s[t]] + g_q[g_g2s[t]]) + pe[t];
            l = l > 0.f ? l : 0.2f * l;
            float w = __expf(l - m) * rden;
            float wh = 0.5f * w;
            size_t b1 = (size_t)g_g1s[t] * 64 + lane, b2 = (size_t)g_g2s[t] * 64 + lane;
            if (NCM == 3) {
                uint ua = g_pk01[b1], ub = g_pk01[b2];
                acc[0] += wh * (bflo(ua) + bflo(ub));
                acc[1] += wh * (bfhi(ua) + bfhi(ub));
                acc[2] += wh * (bfs(g_tfp[3 * PSZ + b1]) + bfs(g_tfp[3 * PSZ + b2]));
            } else {
                uint ua = g_pkA[b1], ub = g_pkA[b2];
                acc[0] += wh * (bflo(ua) + bflo(ub));
                acc[1] += wh * (bfhi(ua) + bfhi(ub));
            }
        }
    }
#pragma unroll
    for (int c = 0; c < NCM; c++)
        g_msumh[(size_t)seg * 192 + lane + 64 * c] = f2bf(acc[c]);
}

// ----- iter1 GEMM: 32x128 tiles, K=128; writes pk01=(out0|out1); fused q (w2[2]) -----
__global__ __launch_bounds__(256) void k_gemmB(const float* __restrict__ W,
                                               const float* __restrict__ bias) {
    __shared__ float As[32][36];
    __shared__ float Bs[32][132];
    int tid = threadIdx.x;
    int rb0 = blockIdx.x * 32;
    int ty = tid >> 4, tx = tid & 15;
    float aclo[2][4] = {{0.f,0.f,0.f,0.f},{0.f,0.f,0.f,0.f}};
    float achi[2][4] = {{0.f,0.f,0.f,0.f},{0.f,0.f,0.f,0.f}};
    for (int kk = 0; kk < 128; kk += 32) {
        {
            int row = tid & 31, k4 = (tid >> 5) * 4;
            uint2 u = make_uint2(0, 0);
            if (rb0 + row < NSEG)
                u = *(const uint2*)&g_msumh[(size_t)(rb0 + row) * 192 + kk + k4];
            As[k4 + 0][row] = bfs((ushort)(u.x & 0xFFFF));
            As[k4 + 1][row] = bfs((ushort)(u.x >> 16));
            As[k4 + 2][row] = bfs((ushort)(u.y & 0xFFFF));
            As[k4 + 3][row] = bfs((ushort)(u.y >> 16));
        }
        {
            int bk = tid >> 3, bc = (tid & 7) * 16;
#pragma unroll
            for (int q = 0; q < 4; q++)
                *(f4*)&Bs[bk][bc + q * 4] = *(const f4*)&W[(size_t)(kk + bk) * 128 + bc + q * 4];
        }
        __syncthreads();
#pragma unroll
        for (int k = 0; k < 32; k++) {
            float a0 = As[k][ty * 2], a1 = As[k][ty * 2 + 1];
            f4 bl = *(const f4*)&Bs[k][tx * 4];
            f4 bh = *(const f4*)&Bs[k][64 + tx * 4];
            aclo[0][0] += a0 * bl.x; aclo[0][1] += a0 * bl.y; aclo[0][2] += a0 * bl.z; aclo[0][3] += a0 * bl.w;
            aclo[1][0] += a1 * bl.x; aclo[1][1] += a1 * bl.y; aclo[1][2] += a1 * bl.z; aclo[1][3] += a1 * bl.w;
            achi[0][0] += a0 * bh.x; achi[0][1] += a0 * bh.y; achi[0][2] += a0 * bh.z; achi[0][3] += a0 * bh.w;
            achi[1][0] += a1 * bh.x; achi[1][1] += a1 * bh.y; achi[1][2] += a1 * bh.z; achi[1][3] += a1 * bh.w;
        }
        __syncthreads();
    }
#pragma unroll
    for (int r = 0; r < 2; r++) {
        int row = rb0 + ty * 2 + r;
        bool valid = row < NSEG;
        bool nonempty = valid && (g_rowptr[row + 1] > g_rowptr[row]);
        ushort4 h4 = make_ushort4(0, 0, 0, 0);
        if (valid) h4 = *(const ushort4*)&g_tfp[3 * PSZ + (size_t)row * 64 + tx * 4];
        const ushort hb[4] = {h4.x, h4.y, h4.z, h4.w};
        uint pk[4];
        float qp = 0.f;
#pragma unroll
        for (int j = 0; j < 4; j++) {
            float vl = aclo[r][j] + bias[tx * 4 + j];
            float vh = achi[r][j] + bias[64 + tx * 4 + j];
            if (!nonempty) { vl = 0.f; vh = 0.f; }
            vl = vl > 0.f ? vl : (__expf(vl) - 1.f);
            vh = vh > 0.f ? vh : (__expf(vh) - 1.f);
            pk[j] = (uint)f2bf(vl) | ((uint)f2bf(vh) << 16);
            qp += vl * g_w2[2][tx * 4 + j] + vh * g_w2[2][64 + tx * 4 + j] +
                  bfs(hb[j]) * g_w2[2][128 + tx * 4 + j];
        }
        if (valid) {
            uint4 o; o.x = pk[0]; o.y = pk[1]; o.z = pk[2]; o.w = pk[3];
            *(uint4*)&g_pk01[(size_t)row * 64 + tx * 4] = o;
        }
        qp += __shfl_xor(qp, 1); qp += __shfl_xor(qp, 2);
        qp += __shfl_xor(qp, 4); qp += __shfl_xor(qp, 8);
        if (valid && tx == 0) g_q[row] = qp + g_w2[2][255];
    }
}

// ----- iter2 GEMM (64x64 col-split tiles, K=192): plane cslot = mask*elu(msumh @ W + b) -----
__global__ __launch_bounds__(256) void k_gemmC(const float* __restrict__ W,
                                               const float* __restrict__ bias) {
    constexpr int D = 192;
    __shared__ float As[32][68];
    __shared__ float Bs[32][68];
    int tid = threadIdx.x;
    int rb0 = blockIdx.x * 64;
    int cslot = blockIdx.y;
    int cb0 = cslot * 64;
    int ty = tid >> 4, tx = tid & 15;
    float acc[4][4];
#pragma unroll
    for (int r = 0; r < 4; r++)
#pragma unroll
        for (int j = 0; j < 4; j++) acc[r][j] = 0.f;

    int arow = tid & 63, aoct = tid >> 6;
    int bk = tid >> 3, bc8 = (tid & 7) * 8;
    for (int kk = 0; kk < D; kk += 32) {
        {
            uint4 u = make_uint4(0, 0, 0, 0);
            if (rb0 + arow < NSEG)
                u = *(const uint4*)&g_msumh[(size_t)(rb0 + arow) * 192 + kk + aoct * 8];
            int kb = aoct * 8;
            As[kb + 0][arow] = bfs((ushort)(u.x & 0xFFFF));
            As[kb + 1][arow] = bfs((ushort)(u.x >> 16));
            As[kb + 2][arow] = bfs((ushort)(u.y & 0xFFFF));
            As[kb + 3][arow] = bfs((ushort)(u.y >> 16));
            As[kb + 4][arow] = bfs((ushort)(u.z & 0xFFFF));
            As[kb + 5][arow] = bfs((ushort)(u.z >> 16));
            As[kb + 6][arow] = bfs((ushort)(u.w & 0xFFFF));
            As[kb + 7][arow] = bfs((ushort)(u.w >> 16));
        }
        {
            f4 b0 = *(const f4*)&W[(size_t)(kk + bk) * D + cb0 + bc8];
            f4 b1 = *(const f4*)&W[(size_t)(kk + bk) * D + cb0 + bc8 + 4];
            *(f4*)&Bs[bk][bc8] = b0;
            *(f4*)&Bs[bk][bc8 + 4] = b1;
        }
        __syncthreads();
#pragma unroll
        for (int k = 0; k < 32; k++) {
            f4 a = *(const f4*)&As[k][ty * 4];
            f4 b = *(const f4*)&Bs[k][tx * 4];
            acc[0][0] += a.x * b.x; acc[0][1] += a.x * b.y; acc[0][2] += a.x * b.z; acc[0][3] += a.x * b.w;
            acc[1][0] += a.y * b.x; acc[1][1] += a.y * b.y; acc[1][2] += a.y * b.z; acc[1][3] += a.y * b.w;
            acc[2][0] += a.z * b.x; acc[2][1] += a.z * b.y; acc[2][2] += a.z * b.z; acc[2][3] += a.z * b.w;
            acc[3][0] += a.w * b.x; acc[3][1] += a.w * b.y; acc[3][2] += a.w * b.z; acc[3][3] += a.w * b.w;
        }
        __syncthreads();
    }
#pragma unroll
    for (int r = 0; r < 4; r++) {
        int row = rb0 + ty * 4 + r;
        if (row >= NSEG) continue;
        bool nonempty = g_rowptr[row + 1] > g_rowptr[row];
        ushort4 pk;
        ushort* p = (ushort*)&pk;
#pragma unroll
        for (int j = 0; j < 4; j++) {
            float v = acc[r][j] + bias[cb0 + tx * 4 + j];
            if (!nonempty) v = 0.f;
            v = v > 0.f ? v : (__expf(v) - 1.f);
            p[j] = f2bf(v);
        }
        *(ushort4*)&g_tfp[(size_t)cslot * PSZ + (size_t)row * 64 + tx * 4] = pk;
    }
}

// ---------------- final: per-molecule gather-sum ----------------
__global__ void k_final(const int* __restrict__ lscope, float* __restrict__ out) {
    __shared__ int idx[32];
    __shared__ float sm[4][256];
    int m = blockIdx.x, tid = threadIdx.x, w = tid >> 6, lane = tid & 63;
    if (tid < 32) idx[tid] = lscope[m * 32 + tid];
    __syncthreads();
    float a0 = 0.f, a1 = 0.f, a2 = 0.f, a3 = 0.f;
#pragma unroll
    for (int j = w * 8; j < w * 8 + 8; j++) {
        size_t base = (size_t)idx[j] * 64 + lane;
        a0 += bfs(g_tfp[base]);
        a1 += bfs(g_tfp[PSZ + base]);
        a2 += bfs(g_tfp[2 * PSZ + base]);
        a3 += bfs(g_tfp[3 * PSZ + base]);
    }
    sm[w][lane] = a0; sm[w][64 + lane] = a1; sm[w][128 + lane] = a2; sm[w][192 + lane] = a3;
    __syncthreads();
    out[(size_t)m * 256 + tid] = sm[0][tid] + sm[1][tid] + sm[2][tid] + sm[3][tid];
}

extern "C" void kernel_launch(void* const* d_in, const int* in_sizes, int n_in,
                              void* d_out, int out_size, void* d_ws, size_t ws_size,
                              hipStream_t stream) {
    const float* node_feats = (const float*)d_in[0];
    const float* fdg        = (const float*)d_in[1];
    const float* rij        = (const float*)d_in[2];
    const int*   see        = (const int*)d_in[3];
    const int*   b_scope    = (const int*)d_in[4];
    const int*   scope_up   = (const int*)d_in[5];
    const int*   scope_lig  = (const int*)d_in[6];
    const int*   l_scope    = (const int*)d_in[7];
    const float* W_emb      = (const float*)d_in[8];
    const float* b_emb      = (const float*)d_in[9];
    const float* W_dist     = (const float*)d_in[10];
    const float* b_dist     = (const float*)d_in[11];
    const float* fc_W[3]   = {(const float*)d_in[12], (const float*)d_in[15], (const float*)d_in[18]};
    const float* fc_b[3]   = {(const float*)d_in[13], (const float*)d_in[16], (const float*)d_in[19]};
    const float* attn_a[3] = {(const float*)d_in[14], (const float*)d_in[17], (const float*)d_in[20]};

    k_emb<<<8193, 256, 0, stream>>>(node_feats, W_emb, b_emb,
                                    attn_a[0], attn_a[1], attn_a[2]);
    k_prep_all<<<5, 256, 0, stream>>>(fc_W[0], fc_W[1], fc_W[2],
                                      attn_a[0], attn_a[1], attn_a[2],
                                      fc_b[0], fc_b[1], fc_b[2], W_dist, b_dist);
    k_hist<<<NE / 256, 256, 0, stream>>>(b_scope);
    k_scan1<<<129, 256, 0, stream>>>();
    k_scan2<<<1, 256, 0, stream>>>(129);
    k_scan3<<<129, 256, 0, stream>>>();
    k_scatter<<<NE / 256, 256, 0, stream>>>(b_scope);
    k_bscatter<<<129, 256, 0, stream>>>();
    k_sortidx<<<NE / 256, 256, 0, stream>>>(scope_lig, scope_up, see, fdg, rij);

    // iter 0 (streaming, fully fused)
    k_attend0<<<8193, 256, 0, stream>>>();
    // iter 1
    k_attendG<2><<<8193, 256, 0, stream>>>();
    k_gemmB<<<1025, 256, 0, stream>>>(fc_W[1], fc_b[1]);
    // iter 2
    k_attendG<3><<<8193, 256, 0, stream>>>();
    k_gemmC<<<dim3(513, 3), 256, 0, stream>>>(fc_W[2], fc_b[2]);

    k_final<<<2048, 256, 0, stream>>>(l_scope, (float*)d_out);
}

// Round 14
// 278.712 us; speedup vs baseline: 1.5432x; 1.0557x over previous
//
#include <hip/hip_runtime.h>
#include <cstdint>
#include <cstddef>

#define NSEG 32769      // N_NODES + 1 (row 0 is the zero row)
#define NNODES 32768
#define NE 262144
#define PSZ ((size_t)NSEG * 64)   // one tf plane

using f4 = float4;

// ---------------- static device scratch (load-time zero-initialized) ----------------
__device__ ushort g_tfp[4 * PSZ];                 // planes 0..2 out cols (iter2), plane 3 h_orig
__device__ uint   g_pkA[PSZ];                     // (out0 | h)  after iter0
__device__ uint   g_pk01[PSZ];                    // (out0 | out1) after iter1 gemm
__device__ ushort g_msumh[(size_t)NSEG * 192];    // bf16 row-major (K width 192)
__device__ float  g_q[NSEG];
__device__ float  g_p0[3][NSEG];
__device__ float  g_p1[3][NSEG];
__device__ float  g_w2[3][256];                   // w2 = W @ a2 in [0,d); c = a2.b at [255]
__device__ float  g_wq10[10];                     // W_dist @ w2_0
__device__ float  g_cq;                           // b_dist.w2_0 + a0.b0
__device__ float  g_wc[640];                      // Wc = W_dist @ fc_W0 (10x64)
__device__ float  g_bcc[64];                      // b_dist @ fc_W0 + fc_b0
__device__ int    g_counts[NSEG];                 // zeroed by k_mid (prev call) / load
__device__ int    g_excl[NSEG];
__device__ int    g_bsum[1024];
__device__ int    g_rowptr[NSEG + 1];
__device__ int    g_cur[NSEG];                    // zeroed by k_mid (prev call) / load
__device__ int    g_csr[NE];
__device__ int    g_g1s[NE];                      // gather indices, CSR-sorted
__device__ int    g_g2s[NE];
__device__ float  g_pe1[NE];                      // p0[1][s0]+p1[1][s1], CSR-sorted
__device__ float  g_pe2[NE];                      // p0[2][s0]+p1[2][s1], CSR-sorted
__device__ int    g_bc[128];                      // zeroed by k_attend0 (prev call) / load
__device__ int    g_bcur[128];
__device__ int    g_sorder[NSEG];

#define WREDUCE(x) { x += __shfl_xor(x, 32); x += __shfl_xor(x, 16); \
                     x += __shfl_xor(x, 8);  x += __shfl_xor(x, 4);  \
                     x += __shfl_xor(x, 2);  x += __shfl_xor(x, 1); }
#define WREDMAX(x) { x = fmaxf(x, __shfl_xor(x, 32)); x = fmaxf(x, __shfl_xor(x, 16)); \
                     x = fmaxf(x, __shfl_xor(x, 8));  x = fmaxf(x, __shfl_xor(x, 4));  \
                     x = fmaxf(x, __shfl_xor(x, 2));  x = fmaxf(x, __shfl_xor(x, 1)); }

__device__ __forceinline__ ushort f2bf(float x) {
    uint u = __float_as_uint(x);
    u += 0x7FFF + ((u >> 16) & 1);
    return (ushort)(u >> 16);
}
__device__ __forceinline__ float bfs(ushort u) { return __uint_as_float(((uint)u) << 16); }
__device__ __forceinline__ float bflo(uint u) { return __uint_as_float(u << 16); }
__device__ __forceinline__ float bfhi(uint u) { return __uint_as_float(u & 0xFFFF0000u); }

// ===== k_front: emb (blocks 0..8192) | prep (8193..8197) | hist (8198..9221) =====
__global__ __launch_bounds__(256) void k_front(
    const float* __restrict__ node_feats, const float* __restrict__ We,
    const float* __restrict__ be,
    const float* __restrict__ a0, const float* __restrict__ a1, const float* __restrict__ a2,
    const float* __restrict__ W0, const float* __restrict__ W1, const float* __restrict__ W2,
    const float* __restrict__ b0, const float* __restrict__ b1, const float* __restrict__ b2,
    const float* __restrict__ Wd, const float* __restrict__ bd,
    const int* __restrict__ bscope) {
    int tid = threadIdx.x;
    if (blockIdx.x < 8193) {
        // ---- emb: h_orig (plane 3) + p0/p1 dots ----
        __shared__ float Ws[9 * 64];
        __shared__ float fs[4][9];
        for (int i = tid; i < 576; i += 256) Ws[i] = We[i];
        int r0 = blockIdx.x * 4;
        if (tid < 36) {
            int r = r0 + tid / 9, k = tid % 9;
            float v = 0.f;
            if (r >= 1 && r <= NNODES) v = node_feats[(size_t)(r - 1) * 9 + k];
            fs[tid / 9][k] = v;
        }
        __syncthreads();
        int r = tid >> 6, j = tid & 63;
        int row = r0 + r;
        if (row >= NSEG) return;
        float acc = be[j];
#pragma unroll
        for (int k = 0; k < 9; k++) acc += fs[r][k] * Ws[k * 64 + j];
        float v = (row == 0) ? 0.f : acc;
        g_tfp[3 * PSZ + (size_t)row * 64 + j] = f2bf(v);
        const float* A[3] = {a0, a1, a2};
#pragma unroll
        for (int i = 0; i < 3; i++) {
            float d0 = v * A[i][j];
            WREDUCE(d0);
            if (j == 0) g_p0[i][row] = d0;
            float d1 = v * A[i][64 + j];
            WREDUCE(d1);
            if (j == 0) g_p1[i][row] = d1;
        }
    } else if (blockIdx.x < 8198) {
        int pb = blockIdx.x - 8193;
        int k = tid;
        if (pb < 3) {
            int it = pb;
            const float* W = it == 0 ? W0 : (it == 1 ? W1 : W2);
            const float* a = it == 0 ? a0 : (it == 1 ? a1 : a2);
            const float* bias = it == 0 ? b0 : (it == 1 ? b1 : b2);
            int d = 64 * (it + 1);
            if (k < d) {
                float s = 0.f;
                for (int j = 0; j < d; j++) s += W[(size_t)k * d + j] * a[128 + j];
                g_w2[it][k] = s;
            } else if (k == 255) {
                float c = 0.f;
                for (int j = 0; j < d; j++) c += a[128 + j] * bias[j];
                g_w2[it][255] = c;
            }
        } else if (pb == 3) {
            __shared__ float w2s[64];
            if (k < 64) {
                float s = 0.f;
                for (int j = 0; j < 64; j++) s += W0[(size_t)k * 64 + j] * a0[128 + j];
                w2s[k] = s;
            }
            __syncthreads();
            if (k < 10) {
                float s = 0.f;
                for (int j = 0; j < 64; j++) s += Wd[(size_t)k * 64 + j] * w2s[j];
                g_wq10[k] = s;
            } else if (k == 64) {
                float s = 0.f, c = 0.f;
                for (int j = 0; j < 64; j++) { s += bd[j] * w2s[j]; c += a0[128 + j] * b0[j]; }
                g_cq = s + c;
            }
        } else {
            for (int t = k; t < 640; t += 256) {
                int kk = t >> 6, j = t & 63;
                float s = 0.f;
                for (int m = 0; m < 64; m++) s += Wd[kk * 64 + m] * W0[(size_t)m * 64 + j];
                g_wc[t] = s;
            }
            if (k < 64) {
                float s = b0[k];
                for (int m = 0; m < 64; m++) s += bd[m] * W0[(size_t)m * 64 + k];
                g_bcc[k] = s;
            }
        }
    } else {
        // ---- hist (g_counts zeroed by previous call's k_mid / load-time) ----
        int e = (blockIdx.x - 8198) * 256 + tid;
        if (e < NE) atomicAdd(&g_counts[bscope[e]], 1);
    }
}

// ---------------- scans ----------------
__global__ void k_scan1() {
    __shared__ int s[256];
    int t = threadIdx.x, i = blockIdx.x * 256 + t;
    int v = (i < NSEG) ? g_counts[i] : 0;
    s[t] = v; __syncthreads();
    for (int off = 1; off < 256; off <<= 1) {
        int tmp = (t >= off) ? s[t - off] : 0;
        __syncthreads();
        s[t] += tmp;
        __syncthreads();
    }
    if (i < NSEG) g_excl[i] = s[t] - v;
    if (t == 255) g_bsum[blockIdx.x] = s[255];
}

__global__ void k_scan2(int nb) {
    __shared__ int s[256];
    int t = threadIdx.x;
    int v = (t < nb) ? g_bsum[t] : 0;
    s[t] = v; __syncthreads();
    for (int off = 1; off < 256; off <<= 1) {
        int tmp = (t >= off) ? s[t - off] : 0;
        __syncthreads();
        s[t] += tmp;
        __syncthreads();
    }
    if (t < nb) g_bsum[t] = s[t] - v;   // exclusive
}

// scan3 + fused bucket histogram (g_bc zeroed by previous call's k_attend0 / load)
__global__ void k_scan3() {
    __shared__ int lh[128];
    int t = threadIdx.x;
    if (t < 128) lh[t] = 0;
    __syncthreads();
    int i = blockIdx.x * 256 + t;
    if (i < NSEG) {
        g_rowptr[i] = g_excl[i] + g_bsum[i >> 8];
        int cnt = g_counts[i];
        atomicAdd(&lh[cnt > 127 ? 127 : cnt], 1);
    }
    if (i == NSEG) g_rowptr[NSEG] = NE;
    __syncthreads();
    if (t < 128 && lh[t]) atomicAdd(&g_bc[t], lh[t]);
}

__global__ void k_scatter(const int* __restrict__ bs) {
    int e = blockIdx.x * 256 + threadIdx.x;
    if (e < NE) {
        int seg = bs[e];
        int pos = g_rowptr[seg] + atomicAdd(&g_cur[seg], 1);
        g_csr[pos] = e;
    }
}

// ===== k_mid: bscatter (blocks 0..128, + counts/cur cleanup) | sortidx (129..1152) =====
__global__ __launch_bounds__(256) void k_mid(const int* __restrict__ g1,
                                             const int* __restrict__ g2,
                                             const int* __restrict__ see) {
    int tid = threadIdx.x;
    if (blockIdx.x < 129) {
        __shared__ int sc[128];
        __shared__ int lh[128];
        __shared__ int lbase[128];
        if (tid < 128) { sc[tid] = g_bc[tid]; lh[tid] = 0; }
        __syncthreads();
        for (int off = 1; off < 128; off <<= 1) {
            int tmp = (tid >= off && tid < 128) ? sc[tid - off] : 0;
            __syncthreads();
            if (tid < 128) sc[tid] += tmp;
            __syncthreads();
        }
        int seg = blockIdx.x * 256 + tid;
        int bin = 0, lpos = 0;
        bool valid = seg < NSEG;
        if (valid) {
            int cnt = g_rowptr[seg + 1] - g_rowptr[seg];
            bin = cnt > 127 ? 127 : cnt;
            lpos = atomicAdd(&lh[bin], 1);
        }
        __syncthreads();
        if (tid < 128 && lh[tid] > 0)
            lbase[tid] = atomicAdd(&g_bcur[tid], lh[tid]);
        __syncthreads();
        if (valid) {
            int bstart = sc[bin] - g_bc[bin];
            g_sorder[bstart + lbase[bin] + lpos] = seg;
            // cleanup for next call (counts/cur no longer needed this call)
            g_counts[seg] = 0;
            g_cur[seg] = 0;
        }
    } else {
        int pos = (blockIdx.x - 129) * 256 + tid;
        if (pos >= NE) return;
        int e = g_csr[pos];
        g_g1s[pos] = g1[e]; g_g2s[pos] = g2[e];
        int s0 = see[2 * (size_t)e], s1 = see[2 * (size_t)e + 1];
        g_pe1[pos] = g_p0[1][s0] + g_p1[1][s1];
        g_pe2[pos] = g_p0[2][s0] + g_p1[2][s1];
    }
}

// ===== fused attend0: gathers edge features directly, computes logit inline,
//       out0 = elu(y @ Wc + bcc), packs pkA=(out0|h), fused next-iter q =====
__global__ __launch_bounds__(256) void k_attend0(const float* __restrict__ fdg,
                                                 const float* __restrict__ rij,
                                                 const int* __restrict__ see) {
    __shared__ float Wcs[640];
    __shared__ float bcs[64];
    __shared__ float wqs[10];
    int tid = threadIdx.x;
    if (blockIdx.x == 0 && tid < 128) { g_bc[tid] = 0; g_bcur[tid] = 0; }  // cleanup
    for (int i = tid; i < 640; i += 256) Wcs[i] = g_wc[i];
    if (tid < 64) bcs[tid] = g_bcc[tid];
    if (tid < 10) wqs[tid] = g_wq10[tid];
    __syncthreads();
    float cq = g_cq;
    int lane = tid & 63;
    int sidx = blockIdx.x * 4 + (tid >> 6);
    if (sidx >= NSEG) return;
    int seg = g_sorder[sidx];
    int beg = g_rowptr[seg], end = g_rowptr[seg + 1];
    int cnt = end - beg;
    float y[10];
#pragma unroll
    for (int k = 0; k < 10; k++) y[k] = 0.f;

    if (cnt > 0 && cnt <= 64) {
        float l = -1e30f;
        float x[10];
#pragma unroll
        for (int k = 0; k < 10; k++) x[k] = 0.f;
        if (lane < cnt) {
            int e = g_csr[beg + lane];
#pragma unroll
            for (int k = 0; k < 9; k++) x[k] = fdg[(size_t)e * 9 + k];
            x[9] = rij[e];
            int s0 = see[2 * (size_t)e], s1 = see[2 * (size_t)e + 1];
            float q = cq;
#pragma unroll
            for (int k = 0; k < 10; k++) q += x[k] * wqs[k];
            l = q + g_p0[0][s0] + g_p1[0][s1];
            l = l > 0.f ? l : 0.2f * l;
        }
        float m = l;
        WREDMAX(m);
        float ex = (lane < cnt) ? __expf(l - m) : 0.f;
        float den = ex;
        WREDUCE(den);
        float w = ex / den;
#pragma unroll
        for (int k = 0; k < 10; k++) {
            float s = w * x[k];
            WREDUCE(s);
            y[k] = s;        // every lane holds the full y
        }
    } else if (cnt > 64) {
        // rare fallback: recompute logit per pass
        float m = -1e30f;
        for (int t = beg + lane; t < end; t += 64) {
            int e = g_csr[t];
            float q = cq;
#pragma unroll
            for (int k = 0; k < 9; k++) q += fdg[(size_t)e * 9 + k] * wqs[k];
            q += rij[e] * wqs[9];
            float l = q + g_p0[0][see[2 * (size_t)e]] + g_p1[0][see[2 * (size_t)e + 1]];
            l = l > 0.f ? l : 0.2f * l;
            m = fmaxf(m, l);
        }
        WREDMAX(m);
        float den = 0.f;
        for (int t = beg + lane; t < end; t += 64) {
            int e = g_csr[t];
            float q = cq;
#pragma unroll
            for (int k = 0; k < 9; k++) q += fdg[(size_t)e * 9 + k] * wqs[k];
            q += rij[e] * wqs[9];
            float l = q + g_p0[0][see[2 * (size_t)e]] + g_p1[0][see[2 * (size_t)e + 1]];
            l = l > 0.f ? l : 0.2f * l;
            den += __expf(l - m);
        }
        WREDUCE(den);
        float rden = 1.f / den;
        float part[10];
#pragma unroll
        for (int k = 0; k < 10; k++) part[k] = 0.f;
        for (int t = beg + lane; t < end; t += 64) {
            int e = g_csr[t];
            float x[10];
#pragma unroll
            for (int k = 0; k < 9; k++) x[k] = fdg[(size_t)e * 9 + k];
            x[9] = rij[e];
            float q = cq;
#pragma unroll
            for (int k = 0; k < 10; k++) q += x[k] * wqs[k];
            float l = q + g_p0[0][see[2 * (size_t)e]] + g_p1[0][see[2 * (size_t)e + 1]];
            l = l > 0.f ? l : 0.2f * l;
            float w = __expf(l - m) * rden;
#pragma unroll
            for (int k = 0; k < 10; k++) part[k] += w * x[k];
        }
#pragma unroll
        for (int k = 0; k < 10; k++) {
            WREDUCE(part[k]);
            y[k] = part[k];
        }
    }
    float o = bcs[lane];
#pragma unroll
    for (int k = 0; k < 10; k++) o += y[k] * Wcs[k * 64 + lane];
    if (cnt == 0) o = 0.f;
    o = o > 0.f ? o : (__expf(o) - 1.f);
    ushort h = g_tfp[3 * PSZ + (size_t)seg * 64 + lane];
    g_pkA[(size_t)seg * 64 + lane] = (uint)f2bf(o) | ((uint)h << 16);
    float qp = o * g_w2[1][lane] + bfs(h) * g_w2[1][64 + lane];
    WREDUCE(qp);
    if (lane == 0) g_q[seg] = qp + g_w2[1][255];
}

// -------- attend iters 1/2: sorted index arrays, packed gathers --------
template <int NCM>
__global__ __launch_bounds__(256) void k_attendG() {
    const float* __restrict__ pe = (NCM == 2) ? g_pe1 : g_pe2;
    int lane = threadIdx.x & 63;
    int sidx = blockIdx.x * 4 + (threadIdx.x >> 6);
    if (sidx >= NSEG) return;
    int seg = g_sorder[sidx];
    int beg = g_rowptr[seg], end = g_rowptr[seg + 1];
    int cnt = end - beg;
    float acc[NCM];
#pragma unroll
    for (int c = 0; c < NCM; c++) acc[c] = 0.f;

    if (cnt > 0 && cnt <= 64) {
        float l = -1e30f;
        int i1 = 0, i2 = 0;
        if (lane < cnt) {
            i1 = g_g1s[beg + lane]; i2 = g_g2s[beg + lane];
            l = 0.5f * (g_q[i1] + g_q[i2]) + pe[beg + lane];
            l = l > 0.f ? l : 0.2f * l;
        }
        float m = l;
        WREDMAX(m);
        float ex = (lane < cnt) ? __expf(l - m) : 0.f;
        float den = ex;
        WREDUCE(den);
        float w = ex / den;
        for (int t0 = 0; t0 < cnt; t0 += 8) {
            float wt[8]; int a1[8], a2[8];
#pragma unroll
            for (int u = 0; u < 8; u++) {
                int su = t0 + u; su = su > 63 ? 63 : su;
                wt[u] = __shfl(w, su);
                a1[u] = __shfl(i1, su);
                a2[u] = __shfl(i2, su);
            }
            if (NCM == 2) {
                uint ua[8], ub[8];
#pragma unroll
                for (int u = 0; u < 8; u++) {
                    ua[u] = g_pkA[(size_t)a1[u] * 64 + lane];
                    ub[u] = g_pkA[(size_t)a2[u] * 64 + lane];
                }
#pragma unroll
                for (int u = 0; u < 8; u++) {
                    float wh = 0.5f * wt[u];
                    acc[0] += wh * (bflo(ua[u]) + bflo(ub[u]));
                    acc[1] += wh * (bfhi(ua[u]) + bfhi(ub[u]));
                }
            } else {
                uint ua[8], ub[8];
                ushort ha[8], hb[8];
#pragma unroll
                for (int u = 0; u < 8; u++) {
                    size_t b1 = (size_t)a1[u] * 64 + lane, b2 = (size_t)a2[u] * 64 + lane;
                    ua[u] = g_pk01[b1]; ub[u] = g_pk01[b2];
                    ha[u] = g_tfp[3 * PSZ + b1]; hb[u] = g_tfp[3 * PSZ + b2];
                }
#pragma unroll
                for (int u = 0; u < 8; u++) {
                    float wh = 0.5f * wt[u];
                    acc[0] += wh * (bflo(ua[u]) + bflo(ub[u]));
                    acc[1] += wh * (bfhi(ua[u]) + bfhi(ub[u]));
                    acc[2] += wh * (bfs(ha[u]) + bfs(hb[u]));
                }
            }
        }
    } else if (cnt > 64) {
        float m = -1e30f;
        for (int t = beg + lane; t < end; t += 64) {
            float l = 0.5f * (g_q[g_g1s[t]] + g_q[g_g2s[t]]) + pe[t];
            l = l > 0.f ? l : 0.2f * l;
            m = fmaxf(m, l);
        }
        WREDMAX(m);
        float den = 0.f;
        for (int t = beg + lane; t < end; t += 64) {
            float l = 0.5f * (g_q[g_g1s[t]] + g_q[g_g2s[t]]) + pe[t];
            l = l > 0.f ? l : 0.2f * l;
            den += __expf(l - m);
        }
        WREDUCE(den);
        float rden = 1.f / den;
        for (int t = beg; t < end; t++) {
            float l = 0.5f * (g_q[g_g1s[t]] + g_q[g_g2s[t]]) + pe[t];
            l = l > 0.f ? l : 0.2f * l;
            float w = __expf(l - m) * rden;
            float wh = 0.5f * w;
            size_t b1 = (size_t)g_g1s[t] * 64 + lane, b2 = (size_t)g_g2s[t] * 64 + lane;
            if (NCM == 3) {
                uint ua = g_pk01[b1], ub = g_pk01[b2];
                acc[0] += wh * (bflo(ua) + bflo(ub));
                acc[1] += wh * (bfhi(ua) + bfhi(ub));
                acc[2] += wh * (bfs(g_tfp[3 * PSZ + b1]) + bfs(g_tfp[3 * PSZ + b2]));
            } else {
                uint ua = g_pkA[b1], ub = g_pkA[b2];
                acc[0] += wh * (bflo(ua) + bflo(ub));
                acc[1] += wh * (bfhi(ua) + bfhi(ub));
            }
        }
    }
#pragma unroll
    for (int c = 0; c < NCM; c++)
        g_msumh[(size_t)seg * 192 + lane + 64 * c] = f2bf(acc[c]);
}

// ----- iter1 GEMM: 32x128 tiles, K=128; writes pk01=(out0|out1); fused q (w2[2]) -----
__global__ __launch_bounds__(256) void k_gemmB(const float* __restrict__ W,
                                               const float* __restrict__ bias) {
    __shared__ float As[32][36];
    __shared__ float Bs[32][132];
    int tid = threadIdx.x;
    int rb0 = blockIdx.x * 32;
    int ty = tid >> 4, tx = tid & 15;
    float aclo[2][4] = {{0.f,0.f,0.f,0.f},{0.f,0.f,0.f,0.f}};
    float achi[2][4] = {{0.f,0.f,0.f,0.f},{0.f,0.f,0.f,0.f}};
    for (int kk = 0; kk < 128; kk += 32) {
        {
            int row = tid & 31, k4 = (tid >> 5) * 4;
            uint2 u = make_uint2(0, 0);
            if (rb0 + row < NSEG)
                u = *(const uint2*)&g_msumh[(size_t)(rb0 + row) * 192 + kk + k4];
            As[k4 + 0][row] = bfs((ushort)(u.x & 0xFFFF));
            As[k4 + 1][row] = bfs((ushort)(u.x >> 16));
            As[k4 + 2][row] = bfs((ushort)(u.y & 0xFFFF));
            As[k4 + 3][row] = bfs((ushort)(u.y >> 16));
        }
        {
            int bk = tid >> 3, bc = (tid & 7) * 16;
#pragma unroll
            for (int q = 0; q < 4; q++)
                *(f4*)&Bs[bk][bc + q * 4] = *(const f4*)&W[(size_t)(kk + bk) * 128 + bc + q * 4];
        }
        __syncthreads();
#pragma unroll
        for (int k = 0; k < 32; k++) {
            float a0 = As[k][ty * 2], a1 = As[k][ty * 2 + 1];
            f4 bl = *(const f4*)&Bs[k][tx * 4];
            f4 bh = *(const f4*)&Bs[k][64 + tx * 4];
            aclo[0][0] += a0 * bl.x; aclo[0][1] += a0 * bl.y; aclo[0][2] += a0 * bl.z; aclo[0][3] += a0 * bl.w;
            aclo[1][0] += a1 * bl.x; aclo[1][1] += a1 * bl.y; aclo[1][2] += a1 * bl.z; aclo[1][3] += a1 * bl.w;
            achi[0][0] += a0 * bh.x; achi[0][1] += a0 * bh.y; achi[0][2] += a0 * bh.z; achi[0][3] += a0 * bh.w;
            achi[1][0] += a1 * bh.x; achi[1][1] += a1 * bh.y; achi[1][2] += a1 * bh.z; achi[1][3] += a1 * bh.w;
        }
        __syncthreads();
    }
#pragma unroll
    for (int r = 0; r < 2; r++) {
        int row = rb0 + ty * 2 + r;
        bool valid = row < NSEG;
        bool nonempty = valid && (g_rowptr[row + 1] > g_rowptr[row]);
        ushort4 h4 = make_ushort4(0, 0, 0, 0);
        if (valid) h4 = *(const ushort4*)&g_tfp[3 * PSZ + (size_t)row * 64 + tx * 4];
        const ushort hb[4] = {h4.x, h4.y, h4.z, h4.w};
        uint pk[4];
        float qp = 0.f;
#pragma unroll
        for (int j = 0; j < 4; j++) {
            float vl = aclo[r][j] + bias[tx * 4 + j];
            float vh = achi[r][j] + bias[64 + tx * 4 + j];
            if (!nonempty) { vl = 0.f; vh = 0.f; }
            vl = vl > 0.f ? vl : (__expf(vl) - 1.f);
            vh = vh > 0.f ? vh : (__expf(vh) - 1.f);
            pk[j] = (uint)f2bf(vl) | ((uint)f2bf(vh) << 16);
            qp += vl * g_w2[2][tx * 4 + j] + vh * g_w2[2][64 + tx * 4 + j] +
                  bfs(hb[j]) * g_w2[2][128 + tx * 4 + j];
        }
        if (valid) {
            uint4 o; o.x = pk[0]; o.y = pk[1]; o.z = pk[2]; o.w = pk[3];
            *(uint4*)&g_pk01[(size_t)row * 64 + tx * 4] = o;
        }
        qp += __shfl_xor(qp, 1); qp += __shfl_xor(qp, 2);
        qp += __shfl_xor(qp, 4); qp += __shfl_xor(qp, 8);
        if (valid && tx == 0) g_q[row] = qp + g_w2[2][255];
    }
}

// ----- iter2 GEMM (64x64 col-split tiles, K=192): plane cslot = mask*elu(msumh @ W + b) -----
__global__ __launch_bounds__(256) void k_gemmC(const float* __restrict__ W,
                                               const float* __restrict__ bias) {
    constexpr int D = 192;
    __shared__ float As[32][68];
    __shared__ float Bs[32][68];
    int tid = threadIdx.x;
    int rb0 = blockIdx.x * 64;
    int cslot = blockIdx.y;
    int cb0 = cslot * 64;
    int ty = tid >> 4, tx = tid & 15;
    float acc[4][4];
#pragma unroll
    for (int r = 0; r < 4; r++)
#pragma unroll
        for (int j = 0; j < 4; j++) acc[r][j] = 0.f;

    int arow = tid & 63, aoct = tid >> 6;
    int bk = tid >> 3, bc8 = (tid & 7) * 8;
    for (int kk = 0; kk < D; kk += 32) {
        {
            uint4 u = make_uint4(0, 0, 0, 0);
            if (rb0 + arow < NSEG)
                u = *(const uint4*)&g_msumh[(size_t)(rb0 + arow) * 192 + kk + aoct * 8];
            int kb = aoct * 8;
            As[kb + 0][arow] = bfs((ushort)(u.x & 0xFFFF));
            As[kb + 1][arow] = bfs((ushort)(u.x >> 16));
            As[kb + 2][arow] = bfs((ushort)(u.y & 0xFFFF));
            As[kb + 3][arow] = bfs((ushort)(u.y >> 16));
            As[kb + 4][arow] = bfs((ushort)(u.z & 0xFFFF));
            As[kb + 5][arow] = bfs((ushort)(u.z >> 16));
            As[kb + 6][arow] = bfs((ushort)(u.w & 0xFFFF));
            As[kb + 7][arow] = bfs((ushort)(u.w >> 16));
        }
        {
            f4 b0 = *(const f4*)&W[(size_t)(kk + bk) * D + cb0 + bc8];
            f4 b1 = *(const f4*)&W[(size_t)(kk + bk) * D + cb0 + bc8 + 4];
            *(f4*)&Bs[bk][bc8] = b0;
            *(f4*)&Bs[bk][bc8 + 4] = b1;
        }
        __syncthreads();
#pragma unroll
        for (int k = 0; k < 32; k++) {
            f4 a = *(const f4*)&As[k][ty * 4];
            f4 b = *(const f4*)&Bs[k][tx * 4];
            acc[0][0] += a.x * b.x; acc[0][1] += a.x * b.y; acc[0][2] += a.x * b.z; acc[0][3] += a.x * b.w;
            acc[1][0] += a.y * b.x; acc[1][1] += a.y * b.y; acc[1][2] += a.y * b.z; acc[1][3] += a.y * b.w;
            acc[2][0] += a.z * b.x; acc[2][1] += a.z * b.y; acc[2][2] += a.z * b.z; acc[2][3] += a.z * b.w;
            acc[3][0] += a.w * b.x; acc[3][1] += a.w * b.y; acc[3][2] += a.w * b.z; acc[3][3] += a.w * b.w;
        }
        __syncthreads();
    }
#pragma unroll
    for (int r = 0; r < 4; r++) {
        int row = rb0 + ty * 4 + r;
        if (row >= NSEG) continue;
        bool nonempty = g_rowptr[row + 1] > g_rowptr[row];
        ushort4 pk;
        ushort* p = (ushort*)&pk;
#pragma unroll
        for (int j = 0; j < 4; j++) {
            float v = acc[r][j] + bias[cb0 + tx * 4 + j];
            if (!nonempty) v = 0.f;
            v = v > 0.f ? v : (__expf(v) - 1.f);
            p[j] = f2bf(v);
        }
        *(ushort4*)&g_tfp[(size_t)cslot * PSZ + (size_t)row * 64 + tx * 4] = pk;
    }
}

// ---------------- final: per-molecule gather-sum ----------------
__global__ void k_final(const int* __restrict__ lscope, float* __restrict__ out) {
    __shared__ int idx[32];
    __shared__ float sm[4][256];
    int m = blockIdx.x, tid = threadIdx.x, w = tid >> 6, lane = tid & 63;
    if (tid < 32) idx[tid] = lscope[m * 32 + tid];
    __syncthreads();
    float a0 = 0.f, a1 = 0.f, a2 = 0.f, a3 = 0.f;
#pragma unroll
    for (int j = w * 8; j < w * 8 + 8; j++) {
        size_t base = (size_t)idx[j] * 64 + lane;
        a0 += bfs(g_tfp[base]);
        a1 += bfs(g_tfp[PSZ + base]);
        a2 += bfs(g_tfp[2 * PSZ + base]);
        a3 += bfs(g_tfp[3 * PSZ + base]);
    }
    sm[w][lane] = a0; sm[w][64 + lane] = a1; sm[w][128 + lane] = a2; sm[w][192 + lane] = a3;
    __syncthreads();
    out[(size_t)m * 256 + tid] = sm[0][tid] + sm[1][tid] + sm[2][tid] + sm[3][tid];
}

extern "C" void kernel_launch(void* const* d_in, const int* in_sizes, int n_in,
                              void* d_out, int out_size, void* d_ws, size_t ws_size,
                              hipStream_t stream) {
    const float* node_feats = (const float*)d_in[0];
    const float* fdg        = (const float*)d_in[1];
    const float* rij        = (const float*)d_in[2];
    const int*   see        = (const int*)d_in[3];
    const int*   b_scope    = (const int*)d_in[4];
    const int*   scope_up   = (const int*)d_in[5];
    const int*   scope_lig  = (const int*)d_in[6];
    const int*   l_scope    = (const int*)d_in[7];
    const float* W_emb      = (const float*)d_in[8];
    const float* b_emb      = (const float*)d_in[9];
    const float* W_dist     = (const float*)d_in[10];
    const float* b_dist     = (const float*)d_in[11];
    const float* fc_W[3]   = {(const float*)d_in[12], (const float*)d_in[15], (const float*)d_in[18]};
    const float* fc_b[3]   = {(const float*)d_in[13], (const float*)d_in[16], (const float*)d_in[19]};
    const float* attn_a[3] = {(const float*)d_in[14], (const float*)d_in[17], (const float*)d_in[20]};

    k_front<<<9222, 256, 0, stream>>>(node_feats, W_emb, b_emb,
                                      attn_a[0], attn_a[1], attn_a[2],
                                      fc_W[0], fc_W[1], fc_W[2],
                                      fc_b[0], fc_b[1], fc_b[2],
                                      W_dist, b_dist, b_scope);
    k_scan1<<<129, 256, 0, stream>>>();
    k_scan2<<<1, 256, 0, stream>>>(129);
    k_scan3<<<129, 256, 0, stream>>>();
    k_scatter<<<NE / 256, 256, 0, stream>>>(b_scope);
    k_mid<<<1153, 256, 0, stream>>>(scope_lig, scope_up, see);

    // iter 0 (streaming, fully fused)
    k_attend0<<<8193, 256, 0, stream>>>(fdg, rij, see);
    // iter 1
    k_attendG<2><<<8193, 256, 0, stream>>>();
    k_gemmB<<<1025, 256, 0, stream>>>(fc_W[1], fc_b[1]);
    // iter 2
    k_attendG<3><<<8193, 256, 0, stream>>>();
    k_gemmC<<<dim3(513, 3), 256, 0, stream>>>(fc_W[2], fc_b[2]);

    k_final<<<2048, 256, 0, stream>>>(l_scope, (float*)d_out);
}

// Round 15
// 267.539 us; speedup vs baseline: 1.6076x; 1.0418x over previous
//
#include <hip/hip_runtime.h>
#include <cstdint>
#include <cstddef>

#define NSEG 32769      // N_NODES + 1 (row 0 is the zero row)
#define NNODES 32768
#define NE 262144
#define PSZ ((size_t)NSEG * 64)   // one tf plane

using f4 = float4;

// ---------------- static device scratch (load-time zero-initialized) ----------------
__device__ ushort g_tfp[4 * PSZ];                 // planes 0..2 out cols (iter2), plane 3 h_orig
__device__ uint   g_pkA[PSZ];                     // (out0 | h)  after iter0
__device__ uint   g_pk01[PSZ];                    // (out0 | out1) after iter1 gemm
__device__ ushort g_msumh[(size_t)NSEG * 192];    // bf16 row-major (K width 192)
__device__ float  g_q[NSEG];
__device__ float  g_p0[3][NSEG];
__device__ float  g_p1[3][NSEG];
__device__ float  g_w2[3][256];                   // w2 = W @ a2 in [0,d); c = a2.b at [255]
__device__ float  g_wq10[10];                     // W_dist @ w2_0
__device__ float  g_cq;                           // b_dist.w2_0 + a0.b0
__device__ float  g_wc[640];                      // Wc = W_dist @ fc_W0 (10x64)
__device__ float  g_bcc[64];                      // b_dist @ fc_W0 + fc_b0
__device__ int    g_counts[NSEG];                 // zeroed by k_mid (prev call) / load
__device__ int    g_excl[NSEG];
__device__ int    g_bsum[1024];
__device__ int    g_rowptr[NSEG + 1];
__device__ int    g_cur[NSEG];                    // zeroed by k_mid (prev call) / load
__device__ int    g_csr[NE];
__device__ int    g_g1s[NE];                      // gather indices, CSR-sorted
__device__ int    g_g2s[NE];
__device__ float  g_pe1[NE];                      // p0[1][s0]+p1[1][s1], CSR-sorted
__device__ float  g_pe2[NE];                      // p0[2][s0]+p1[2][s1], CSR-sorted
__device__ int    g_bc[128];                      // zeroed by k_attend0 (prev call) / load
__device__ int    g_bcur[128];
__device__ int    g_sorder[NSEG];

#define WREDUCE(x) { x += __shfl_xor(x, 32); x += __shfl_xor(x, 16); \
                     x += __shfl_xor(x, 8);  x += __shfl_xor(x, 4);  \
                     x += __shfl_xor(x, 2);  x += __shfl_xor(x, 1); }
#define WREDMAX(x) { x = fmaxf(x, __shfl_xor(x, 32)); x = fmaxf(x, __shfl_xor(x, 16)); \
                     x = fmaxf(x, __shfl_xor(x, 8));  x = fmaxf(x, __shfl_xor(x, 4));  \
                     x = fmaxf(x, __shfl_xor(x, 2));  x = fmaxf(x, __shfl_xor(x, 1)); }

__device__ __forceinline__ ushort f2bf(float x) {
    uint u = __float_as_uint(x);
    u += 0x7FFF + ((u >> 16) & 1);
    return (ushort)(u >> 16);
}
__device__ __forceinline__ float bfs(ushort u) { return __uint_as_float(((uint)u) << 16); }
__device__ __forceinline__ float bflo(uint u) { return __uint_as_float(u << 16); }
__device__ __forceinline__ float bfhi(uint u) { return __uint_as_float(u & 0xFFFF0000u); }

// ===== k_front: emb (blocks 0..8192) | prep (8193..8197) | hist (8198..9221) =====
__global__ __launch_bounds__(256) void k_front(
    const float* __restrict__ node_feats, const float* __restrict__ We,
    const float* __restrict__ be,
    const float* __restrict__ a0, const float* __restrict__ a1, const float* __restrict__ a2,
    const float* __restrict__ W0, const float* __restrict__ W1, const float* __restrict__ W2,
    const float* __restrict__ b0, const float* __restrict__ b1, const float* __restrict__ b2,
    const float* __restrict__ Wd, const float* __restrict__ bd,
    const int* __restrict__ bscope) {
    int tid = threadIdx.x;
    if (blockIdx.x < 8193) {
        // ---- emb: h_orig (plane 3) + p0/p1 dots via LDS + 8-lane reduce ----
        __shared__ float Ws[576];
        __shared__ float fs[4][9];
        __shared__ float hs[4][64];
        __shared__ float As6[6][64];
        for (int i = tid; i < 576; i += 256) Ws[i] = We[i];
        for (int t = tid; t < 384; t += 256) {
            int vec = t >> 6, j = t & 63;
            const float* Av = (vec >> 1) == 0 ? a0 : ((vec >> 1) == 1 ? a1 : a2);
            As6[vec][j] = Av[((vec & 1) << 6) + j];
        }
        int r0 = blockIdx.x * 4;
        if (tid < 36) {
            int r = r0 + tid / 9, k = tid % 9;
            float v = 0.f;
            if (r >= 1 && r <= NNODES) v = node_feats[(size_t)(r - 1) * 9 + k];
            fs[tid / 9][k] = v;
        }
        __syncthreads();
        int r = tid >> 6, j = tid & 63;
        int row = r0 + r;
        float acc = be[j];
#pragma unroll
        for (int k = 0; k < 9; k++) acc += fs[r][k] * Ws[k * 64 + j];
        float v = (row == 0 || row >= NSEG) ? 0.f : acc;
        if (row < NSEG) g_tfp[3 * PSZ + (size_t)row * 64 + j] = f2bf(v);
        hs[r][j] = v;
        __syncthreads();
        if (tid < 192) {
            int d = tid >> 3, g = tid & 7;      // 24 dots x 8 lanes
            int dr = d / 6, vec = d % 6;
            float s = 0.f;
#pragma unroll
            for (int jj = 0; jj < 8; jj++)
                s += hs[dr][g * 8 + jj] * As6[vec][g * 8 + jj];
            s += __shfl_xor(s, 1); s += __shfl_xor(s, 2); s += __shfl_xor(s, 4);
            int prow = r0 + dr;
            if (g == 0 && prow < NSEG) {
                int i = vec >> 1;
                if ((vec & 1) == 0) g_p0[i][prow] = s;
                else                g_p1[i][prow] = s;
            }
        }
    } else if (blockIdx.x < 8198) {
        int pb = blockIdx.x - 8193;
        int k = tid;
        if (pb < 3) {
            int it = pb;
            const float* W = it == 0 ? W0 : (it == 1 ? W1 : W2);
            const float* a = it == 0 ? a0 : (it == 1 ? a1 : a2);
            const float* bias = it == 0 ? b0 : (it == 1 ? b1 : b2);
            int d = 64 * (it + 1);
            if (k < d) {
                float s = 0.f;
                for (int j = 0; j < d; j++) s += W[(size_t)k * d + j] * a[128 + j];
                g_w2[it][k] = s;
            } else if (k == 255) {
                float c = 0.f;
                for (int j = 0; j < d; j++) c += a[128 + j] * bias[j];
                g_w2[it][255] = c;
            }
        } else if (pb == 3) {
            __shared__ float w2s[64];
            if (k < 64) {
                float s = 0.f;
                for (int j = 0; j < 64; j++) s += W0[(size_t)k * 64 + j] * a0[128 + j];
                w2s[k] = s;
            }
            __syncthreads();
            if (k < 10) {
                float s = 0.f;
                for (int j = 0; j < 64; j++) s += Wd[(size_t)k * 64 + j] * w2s[j];
                g_wq10[k] = s;
            } else if (k == 64) {
                float s = 0.f, c = 0.f;
                for (int j = 0; j < 64; j++) { s += bd[j] * w2s[j]; c += a0[128 + j] * b0[j]; }
                g_cq = s + c;
            }
        } else {
            for (int t = k; t < 640; t += 256) {
                int kk = t >> 6, j = t & 63;
                float s = 0.f;
                for (int m = 0; m < 64; m++) s += Wd[kk * 64 + m] * W0[(size_t)m * 64 + j];
                g_wc[t] = s;
            }
            if (k < 64) {
                float s = b0[k];
                for (int m = 0; m < 64; m++) s += bd[m] * W0[(size_t)m * 64 + k];
                g_bcc[k] = s;
            }
        }
    } else {
        // ---- hist (g_counts zeroed by previous call's k_mid / load-time) ----
        int e = (blockIdx.x - 8198) * 256 + tid;
        if (e < NE) atomicAdd(&g_counts[bscope[e]], 1);
    }
}

// ---------------- scans ----------------
__global__ void k_scan1() {
    __shared__ int s[256];
    int t = threadIdx.x, i = blockIdx.x * 256 + t;
    int v = (i < NSEG) ? g_counts[i] : 0;
    s[t] = v; __syncthreads();
    for (int off = 1; off < 256; off <<= 1) {
        int tmp = (t >= off) ? s[t - off] : 0;
        __syncthreads();
        s[t] += tmp;
        __syncthreads();
    }
    if (i < NSEG) g_excl[i] = s[t] - v;
    if (t == 255) g_bsum[blockIdx.x] = s[255];
}

__global__ void k_scan2(int nb) {
    __shared__ int s[256];
    int t = threadIdx.x;
    int v = (t < nb) ? g_bsum[t] : 0;
    s[t] = v; __syncthreads();
    for (int off = 1; off < 256; off <<= 1) {
        int tmp = (t >= off) ? s[t - off] : 0;
        __syncthreads();
        s[t] += tmp;
        __syncthreads();
    }
    if (t < nb) g_bsum[t] = s[t] - v;   // exclusive
}

// scan3 + fused bucket histogram (g_bc zeroed by previous call's k_attend0 / load)
__global__ void k_scan3() {
    __shared__ int lh[128];
    int t = threadIdx.x;
    if (t < 128) lh[t] = 0;
    __syncthreads();
    int i = blockIdx.x * 256 + t;
    if (i < NSEG) {
        g_rowptr[i] = g_excl[i] + g_bsum[i >> 8];
        int cnt = g_counts[i];
        atomicAdd(&lh[cnt > 127 ? 127 : cnt], 1);
    }
    if (i == NSEG) g_rowptr[NSEG] = NE;
    __syncthreads();
    if (t < 128 && lh[t]) atomicAdd(&g_bc[t], lh[t]);
}

__global__ void k_scatter(const int* __restrict__ bs) {
    int e = blockIdx.x * 256 + threadIdx.x;
    if (e < NE) {
        int seg = bs[e];
        int pos = g_rowptr[seg] + atomicAdd(&g_cur[seg], 1);
        g_csr[pos] = e;
    }
}

// ===== k_mid: bscatter (blocks 0..128, + counts/cur cleanup) | sortidx (129..1152) =====
__global__ __launch_bounds__(256) void k_mid(const int* __restrict__ g1,
                                             const int* __restrict__ g2,
                                             const int* __restrict__ see) {
    int tid = threadIdx.x;
    if (blockIdx.x < 129) {
        __shared__ int sc[128];
        __shared__ int lh[128];
        __shared__ int lbase[128];
        if (tid < 128) { sc[tid] = g_bc[tid]; lh[tid] = 0; }
        __syncthreads();
        for (int off = 1; off < 128; off <<= 1) {
            int tmp = (tid >= off && tid < 128) ? sc[tid - off] : 0;
            __syncthreads();
            if (tid < 128) sc[tid] += tmp;
            __syncthreads();
        }
        int seg = blockIdx.x * 256 + tid;
        int bin = 0, lpos = 0;
        bool valid = seg < NSEG;
        if (valid) {
            int cnt = g_rowptr[seg + 1] - g_rowptr[seg];
            bin = cnt > 127 ? 127 : cnt;
            lpos = atomicAdd(&lh[bin], 1);
        }
        __syncthreads();
        if (tid < 128 && lh[tid] > 0)
            lbase[tid] = atomicAdd(&g_bcur[tid], lh[tid]);
        __syncthreads();
        if (valid) {
            int bstart = sc[bin] - g_bc[bin];
            g_sorder[bstart + lbase[bin] + lpos] = seg;
            g_counts[seg] = 0;
            g_cur[seg] = 0;
        }
    } else {
        int pos = (blockIdx.x - 129) * 256 + tid;
        if (pos >= NE) return;
        int e = g_csr[pos];
        g_g1s[pos] = g1[e]; g_g2s[pos] = g2[e];
        int s0 = see[2 * (size_t)e], s1 = see[2 * (size_t)e + 1];
        g_pe1[pos] = g_p0[1][s0] + g_p1[1][s1];
        g_pe2[pos] = g_p0[2][s0] + g_p1[2][s1];
    }
}

// ===== fused attend0: gathers edge features directly, computes logit inline,
//       out0 = elu(y @ Wc + bcc), packs pkA=(out0|h), fused next-iter q =====
__global__ __launch_bounds__(256) void k_attend0(const float* __restrict__ fdg,
                                                 const float* __restrict__ rij,
                                                 const int* __restrict__ see) {
    __shared__ float Wcs[640];
    __shared__ float bcs[64];
    __shared__ float wqs[10];
    int tid = threadIdx.x;
    if (blockIdx.x == 0 && tid < 128) { g_bc[tid] = 0; g_bcur[tid] = 0; }  // cleanup
    for (int i = tid; i < 640; i += 256) Wcs[i] = g_wc[i];
    if (tid < 64) bcs[tid] = g_bcc[tid];
    if (tid < 10) wqs[tid] = g_wq10[tid];
    __syncthreads();
    float cq = g_cq;
    int lane = tid & 63;
    int sidx = blockIdx.x * 4 + (tid >> 6);
    if (sidx >= NSEG) return;
    int seg = g_sorder[sidx];
    int beg = g_rowptr[seg], end = g_rowptr[seg + 1];
    int cnt = end - beg;
    float y[10];
#pragma unroll
    for (int k = 0; k < 10; k++) y[k] = 0.f;

    if (cnt > 0 && cnt <= 64) {
        float l = -1e30f;
        float x[10];
#pragma unroll
        for (int k = 0; k < 10; k++) x[k] = 0.f;
        if (lane < cnt) {
            int e = g_csr[beg + lane];
#pragma unroll
            for (int k = 0; k < 9; k++) x[k] = fdg[(size_t)e * 9 + k];
            x[9] = rij[e];
            int s0 = see[2 * (size_t)e], s1 = see[2 * (size_t)e + 1];
            float q = cq;
#pragma unroll
            for (int k = 0; k < 10; k++) q += x[k] * wqs[k];
            l = q + g_p0[0][s0] + g_p1[0][s1];
            l = l > 0.f ? l : 0.2f * l;
        }
        float m = l;
        WREDMAX(m);
        float ex = (lane < cnt) ? __expf(l - m) : 0.f;
        float den = ex;
        WREDUCE(den);
        float w = ex / den;
#pragma unroll
        for (int k = 0; k < 10; k++) {
            float s = w * x[k];
            WREDUCE(s);
            y[k] = s;        // every lane holds the full y
        }
    } else if (cnt > 64) {
        float m = -1e30f;
        for (int t = beg + lane; t < end; t += 64) {
            int e = g_csr[t];
            float q = cq;
#pragma unroll
            for (int k = 0; k < 9; k++) q += fdg[(size_t)e * 9 + k] * wqs[k];
            q += rij[e] * wqs[9];
            float l = q + g_p0[0][see[2 * (size_t)e]] + g_p1[0][see[2 * (size_t)e + 1]];
            l = l > 0.f ? l : 0.2f * l;
            m = fmaxf(m, l);
        }
        WREDMAX(m);
        float den = 0.f;
        for (int t = beg + lane; t < end; t += 64) {
            int e = g_csr[t];
            float q = cq;
#pragma unroll
            for (int k = 0; k < 9; k++) q += fdg[(size_t)e * 9 + k] * wqs[k];
            q += rij[e] * wqs[9];
            float l = q + g_p0[0][see[2 * (size_t)e]] + g_p1[0][see[2 * (size_t)e + 1]];
            l = l > 0.f ? l : 0.2f * l;
            den += __expf(l - m);
        }
        WREDUCE(den);
        float rden = 1.f / den;
        float part[10];
#pragma unroll
        for (int k = 0; k < 10; k++) part[k] = 0.f;
        for (int t = beg + lane; t < end; t += 64) {
            int e = g_csr[t];
            float x[10];
#pragma unroll
            for (int k = 0; k < 9; k++) x[k] = fdg[(size_t)e * 9 + k];
            x[9] = rij[e];
            float q = cq;
#pragma unroll
            for (int k = 0; k < 10; k++) q += x[k] * wqs[k];
            float l = q + g_p0[0][see[2 * (size_t)e]] + g_p1[0][see[2 * (size_t)e + 1]];
            l = l > 0.f ? l : 0.2f * l;
            float w = __expf(l - m) * rden;
#pragma unroll
            for (int k = 0; k < 10; k++) part[k] += w * x[k];
        }
#pragma unroll
        for (int k = 0; k < 10; k++) {
            WREDUCE(part[k]);
            y[k] = part[k];
        }
    }
    float o = bcs[lane];
#pragma unroll
    for (int k = 0; k < 10; k++) o += y[k] * Wcs[k * 64 + lane];
    if (cnt == 0) o = 0.f;
    o = o > 0.f ? o : (__expf(o) - 1.f);
    ushort h = g_tfp[3 * PSZ + (size_t)seg * 64 + lane];
    g_pkA[(size_t)seg * 64 + lane] = (uint)f2bf(o) | ((uint)h << 16);
    float qp = o * g_w2[1][lane] + bfs(h) * g_w2[1][64 + lane];
    WREDUCE(qp);
    if (lane == 0) g_q[seg] = qp + g_w2[1][255];
}

// -------- attend iters 1/2: sorted index arrays, packed gathers --------
template <int NCM>
__global__ __launch_bounds__(256) void k_attendG() {
    const float* __restrict__ pe = (NCM == 2) ? g_pe1 : g_pe2;
    int lane = threadIdx.x & 63;
    int sidx = blockIdx.x * 4 + (threadIdx.x >> 6);
    if (sidx >= NSEG) return;
    int seg = g_sorder[sidx];
    int beg = g_rowptr[seg], end = g_rowptr[seg + 1];
    int cnt = end - beg;
    float acc[NCM];
#pragma unroll
    for (int c = 0; c < NCM; c++) acc[c] = 0.f;

    if (cnt > 0 && cnt <= 64) {
        float l = -1e30f;
        int i1 = 0, i2 = 0;
        if (lane < cnt) {
            i1 = g_g1s[beg + lane]; i2 = g_g2s[beg + lane];
            l = 0.5f * (g_q[i1] + g_q[i2]) + pe[beg + lane];
            l = l > 0.f ? l : 0.2f * l;
        }
        float m = l;
        WREDMAX(m);
        float ex = (lane < cnt) ? __expf(l - m) : 0.f;
        float den = ex;
        WREDUCE(den);
        float w = ex / den;
        for (int t0 = 0; t0 < cnt; t0 += 8) {
            float wt[8]; int a1[8], a2[8];
#pragma unroll
            for (int u = 0; u < 8; u++) {
                int su = t0 + u; su = su > 63 ? 63 : su;
                wt[u] = __shfl(w, su);
                a1[u] = __shfl(i1, su);
                a2[u] = __shfl(i2, su);
            }
            if (NCM == 2) {
                uint ua[8], ub[8];
#pragma unroll
                for (int u = 0; u < 8; u++) {
                    ua[u] = g_pkA[(size_t)a1[u] * 64 + lane];
                    ub[u] = g_pkA[(size_t)a2[u] * 64 + lane];
                }
#pragma unroll
                for (int u = 0; u < 8; u++) {
                    float wh = 0.5f * wt[u];
                    acc[0] += wh * (bflo(ua[u]) + bflo(ub[u]));
                    acc[1] += wh * (bfhi(ua[u]) + bfhi(ub[u]));
                }
            } else {
                uint ua[8], ub[8];
                ushort ha[8], hb[8];
#pragma unroll
                for (int u = 0; u < 8; u++) {
                    size_t b1 = (size_t)a1[u] * 64 + lane, b2 = (size_t)a2[u] * 64 + lane;
                    ua[u] = g_pk01[b1]; ub[u] = g_pk01[b2];
                    ha[u] = g_tfp[3 * PSZ + b1]; hb[u] = g_tfp[3 * PSZ + b2];
                }
#pragma unroll
                for (int u = 0; u < 8; u++) {
                    float wh = 0.5f * wt[u];
                    acc[0] += wh * (bflo(ua[u]) + bflo(ub[u]));
                    acc[1] += wh * (bfhi(ua[u]) + bfhi(ub[u]));
                    acc[2] += wh * (bfs(ha[u]) + bfs(hb[u]));
                }
            }
        }
    } else if (cnt > 64) {
        float m = -1e30f;
        for (int t = beg + lane; t < end; t += 64) {
            float l = 0.5f * (g_q[g_g1s[t]] + g_q[g_g2s[t]]) + pe[t];
            l = l > 0.f ? l : 0.2f * l;
            m = fmaxf(m, l);
        }
        WREDMAX(m);
        float den = 0.f;
        for (int t = beg + lane; t < end; t += 64) {
            float l = 0.5f * (g_q[g_g1s[t]] + g_q[g_g2s[t]]) + pe[t];
            l = l > 0.f ? l : 0.2f * l;
            den += __expf(l - m);
        }
        WREDUCE(den);
        float rden = 1.f / den;
        for (int t = beg; t < end; t++) {
            float l = 0.5f * (g_q[g_g1s[t]] + g_q[g_g2s[t]]) + pe[t];
            l = l > 0.f ? l : 0.2f * l;
            float w = __expf(l - m) * rden;
            float wh = 0.5f * w;
            size_t b1 = (size_t)g_g1s[t] * 64 + lane, b2 = (size_t)g_g2s[t] * 64 + lane;
            if (NCM == 3) {
                uint ua = g_pk01[b1], ub = g_pk01[b2];
                acc[0] += wh * (bflo(ua) + bflo(ub));
                acc[1] += wh * (bfhi(ua) + bfhi(ub));
                acc[2] += wh * (bfs(g_tfp[3 * PSZ + b1]) + bfs(g_tfp[3 * PSZ + b2]));
            } else {
                uint ua = g_pkA[b1], ub = g_pkA[b2];
                acc[0] += wh * (bflo(ua) + bflo(ub));
                acc[1] += wh * (bfhi(ua) + bfhi(ub));
            }
        }
    }
#pragma unroll
    for (int c = 0; c < NCM; c++)
        g_msumh[(size_t)seg * 192 + lane + 64 * c] = f2bf(acc[c]);
}

// ----- iter1 GEMM: 32x128 tiles, K=128; writes pk01=(out0|out1); fused q (w2[2]) -----
__global__ __launch_bounds__(256) void k_gemmB(const float* __restrict__ W,
                                               const float* __restrict__ bias) {
    __shared__ float As[32][36];
    __shared__ float Bs[32][132];
    int tid = threadIdx.x;
    int rb0 = blockIdx.x * 32;
    int ty = tid >> 4, tx = tid & 15;
    float aclo[2][4] = {{0.f,0.f,0.f,0.f},{0.f,0.f,0.f,0.f}};
    float achi[2][4] = {{0.f,0.f,0.f,0.f},{0.f,0.f,0.f,0.f}};
    for (int kk = 0; kk < 128; kk += 32) {
        {
            int row = tid & 31, k4 = (tid >> 5) * 4;
            uint2 u = make_uint2(0, 0);
            if (rb0 + row < NSEG)
                u = *(const uint2*)&g_msumh[(size_t)(rb0 + row) * 192 + kk + k4];
            As[k4 + 0][row] = bfs((ushort)(u.x & 0xFFFF));
            As[k4 + 1][row] = bfs((ushort)(u.x >> 16));
            As[k4 + 2][row] = bfs((ushort)(u.y & 0xFFFF));
            As[k4 + 3][row] = bfs((ushort)(u.y >> 16));
        }
        {
            int bk = tid >> 3, bc = (tid & 7) * 16;
#pragma unroll
            for (int q = 0; q < 4; q++)
                *(f4*)&Bs[bk][bc + q * 4] = *(const f4*)&W[(size_t)(kk + bk) * 128 + bc + q * 4];
        }
        __syncthreads();
#pragma unroll
        for (int k = 0; k < 32; k++) {
            float a0 = As[k][ty * 2], a1 = As[k][ty * 2 + 1];
            f4 bl = *(const f4*)&Bs[k][tx * 4];
            f4 bh = *(const f4*)&Bs[k][64 + tx * 4];
            aclo[0][0] += a0 * bl.x; aclo[0][1] += a0 * bl.y; aclo[0][2] += a0 * bl.z; aclo[0][3] += a0 * bl.w;
            aclo[1][0] += a1 * bl.x; aclo[1][1] += a1 * bl.y; aclo[1][2] += a1 * bl.z; aclo[1][3] += a1 * bl.w;
            achi[0][0] += a0 * bh.x; achi[0][1] += a0 * bh.y; achi[0][2] += a0 * bh.z; achi[0][3] += a0 * bh.w;
            achi[1][0] += a1 * bh.x; achi[1][1] += a1 * bh.y; achi[1][2] += a1 * bh.z; achi[1][3] += a1 * bh.w;
        }
        __syncthreads();
    }
#pragma unroll
    for (int r = 0; r < 2; r++) {
        int row = rb0 + ty * 2 + r;
        bool valid = row < NSEG;
        bool nonempty = valid && (g_rowptr[row + 1] > g_rowptr[row]);
        ushort4 h4 = make_ushort4(0, 0, 0, 0);
        if (valid) h4 = *(const ushort4*)&g_tfp[3 * PSZ + (size_t)row * 64 + tx * 4];
        const ushort hb[4] = {h4.x, h4.y, h4.z, h4.w};
        uint pk[4];
        float qp = 0.f;
#pragma unroll
        for (int j = 0; j < 4; j++) {
            float vl = aclo[r][j] + bias[tx * 4 + j];
            float vh = achi[r][j] + bias[64 + tx * 4 + j];
            if (!nonempty) { vl = 0.f; vh = 0.f; }
            vl = vl > 0.f ? vl : (__expf(vl) - 1.f);
            vh = vh > 0.f ? vh : (__expf(vh) - 1.f);
            pk[j] = (uint)f2bf(vl) | ((uint)f2bf(vh) << 16);
            qp += vl * g_w2[2][tx * 4 + j] + vh * g_w2[2][64 + tx * 4 + j] +
                  bfs(hb[j]) * g_w2[2][128 + tx * 4 + j];
        }
        if (valid) {
            uint4 o; o.x = pk[0]; o.y = pk[1]; o.z = pk[2]; o.w = pk[3];
            *(uint4*)&g_pk01[(size_t)row * 64 + tx * 4] = o;
        }
        qp += __shfl_xor(qp, 1); qp += __shfl_xor(qp, 2);
        qp += __shfl_xor(qp, 4); qp += __shfl_xor(qp, 8);
        if (valid && tx == 0) g_q[row] = qp + g_w2[2][255];
    }
}

// ----- iter2 GEMM (64x64 col-split tiles, K=192): plane cslot = mask*elu(msumh @ W + b) -----
__global__ __launch_bounds__(256) void k_gemmC(const float* __restrict__ W,
                                               const float* __restrict__ bias) {
    constexpr int D = 192;
    __shared__ float As[32][68];
    __shared__ float Bs[32][68];
    int tid = threadIdx.x;
    int rb0 = blockIdx.x * 64;
    int cslot = blockIdx.y;
    int cb0 = cslot * 64;
    int ty = tid >> 4, tx = tid & 15;
    float acc[4][4];
#pragma unroll
    for (int r = 0; r < 4; r++)
#pragma unroll
        for (int j = 0; j < 4; j++) acc[r][j] = 0.f;

    int arow = tid & 63, aoct = tid >> 6;
    int bk = tid >> 3, bc8 = (tid & 7) * 8;
    for (int kk = 0; kk < D; kk += 32) {
        {
            uint4 u = make_uint4(0, 0, 0, 0);
            if (rb0 + arow < NSEG)
                u = *(const uint4*)&g_msumh[(size_t)(rb0 + arow) * 192 + kk + aoct * 8];
            int kb = aoct * 8;
            As[kb + 0][arow] = bfs((ushort)(u.x & 0xFFFF));
            As[kb + 1][arow] = bfs((ushort)(u.x >> 16));
            As[kb + 2][arow] = bfs((ushort)(u.y & 0xFFFF));
            As[kb + 3][arow] = bfs((ushort)(u.y >> 16));
            As[kb + 4][arow] = bfs((ushort)(u.z & 0xFFFF));
            As[kb + 5][arow] = bfs((ushort)(u.z >> 16));
            As[kb + 6][arow] = bfs((ushort)(u.w & 0xFFFF));
            As[kb + 7][arow] = bfs((ushort)(u.w >> 16));
        }
        {
            f4 b0 = *(const f4*)&W[(size_t)(kk + bk) * D + cb0 + bc8];
            f4 b1 = *(const f4*)&W[(size_t)(kk + bk) * D + cb0 + bc8 + 4];
            *(f4*)&Bs[bk][bc8] = b0;
            *(f4*)&Bs[bk][bc8 + 4] = b1;
        }
        __syncthreads();
#pragma unroll
        for (int k = 0; k < 32; k++) {
            f4 a = *(const f4*)&As[k][ty * 4];
            f4 b = *(const f4*)&Bs[k][tx * 4];
            acc[0][0] += a.x * b.x; acc[0][1] += a.x * b.y; acc[0][2] += a.x * b.z; acc[0][3] += a.x * b.w;
            acc[1][0] += a.y * b.x; acc[1][1] += a.y * b.y; acc[1][2] += a.y * b.z; acc[1][3] += a.y * b.w;
            acc[2][0] += a.z * b.x; acc[2][1] += a.z * b.y; acc[2][2] += a.z * b.z; acc[2][3] += a.z * b.w;
            acc[3][0] += a.w * b.x; acc[3][1] += a.w * b.y; acc[3][2] += a.w * b.z; acc[3][3] += a.w * b.w;
        }
        __syncthreads();
    }
#pragma unroll
    for (int r = 0; r < 4; r++) {
        int row = rb0 + ty * 4 + r;
        if (row >= NSEG) continue;
        bool nonempty = g_rowptr[row + 1] > g_rowptr[row];
        ushort4 pk;
        ushort* p = (ushort*)&pk;
#pragma unroll
        for (int j = 0; j < 4; j++) {
            float v = acc[r][j] + bias[cb0 + tx * 4 + j];
            if (!nonempty) v = 0.f;
            v = v > 0.f ? v : (__expf(v) - 1.f);
            p[j] = f2bf(v);
        }
        *(ushort4*)&g_tfp[(size_t)cslot * PSZ + (size_t)row * 64 + tx * 4] = pk;
    }
}

// ---------------- final: per-molecule gather-sum ----------------
__global__ void k_final(const int* __restrict__ lscope, float* __restrict__ out) {
    __shared__ int idx[32];
    __shared__ float sm[4][256];
    int m = blockIdx.x, tid = threadIdx.x, w = tid >> 6, lane = tid & 63;
    if (tid < 32) idx[tid] = lscope[m * 32 + tid];
    __syncthreads();
    float a0 = 0.f, a1 = 0.f, a2 = 0.f, a3 = 0.f;
#pragma unroll
    for (int j = w * 8; j < w * 8 + 8; j++) {
        size_t base = (size_t)idx[j] * 64 + lane;
        a0 += bfs(g_tfp[base]);
        a1 += bfs(g_tfp[PSZ + base]);
        a2 += bfs(g_tfp[2 * PSZ + base]);
        a3 += bfs(g_tfp[3 * PSZ + base]);
    }
    sm[w][lane] = a0; sm[w][64 + lane] = a1; sm[w][128 + lane] = a2; sm[w][192 + lane] = a3;
    __syncthreads();
    out[(size_t)m * 256 + tid] = sm[0][tid] + sm[1][tid] + sm[2][tid] + sm[3][tid];
}

extern "C" void kernel_launch(void* const* d_in, const int* in_sizes, int n_in,
                              void* d_out, int out_size, void* d_ws, size_t ws_size,
                              hipStream_t stream) {
    const float* node_feats = (const float*)d_in[0];
    const float* fdg        = (const float*)d_in[1];
    const float* rij        = (const float*)d_in[2];
    const int*   see        = (const int*)d_in[3];
    const int*   b_scope    = (const int*)d_in[4];
    const int*   scope_up   = (const int*)d_in[5];
    const int*   scope_lig  = (const int*)d_in[6];
    const int*   l_scope    = (const int*)d_in[7];
    const float* W_emb      = (const float*)d_in[8];
    const float* b_emb      = (const float*)d_in[9];
    const float* W_dist     = (const float*)d_in[10];
    const float* b_dist     = (const float*)d_in[11];
    const float* fc_W[3]   = {(const float*)d_in[12], (const float*)d_in[15], (const float*)d_in[18]};
    const float* fc_b[3]   = {(const float*)d_in[13], (const float*)d_in[16], (const float*)d_in[19]};
    const float* attn_a[3] = {(const float*)d_in[14], (const float*)d_in[17], (const float*)d_in[20]};

    k_front<<<9222, 256, 0, stream>>>(node_feats, W_emb, b_emb,
                                      attn_a[0], attn_a[1], attn_a[2],
                                      fc_W[0], fc_W[1], fc_W[2],
                                      fc_b[0], fc_b[1], fc_b[2],
                                      W_dist, b_dist, b_scope);
    k_scan1<<<129, 256, 0, stream>>>();
    k_scan2<<<1, 256, 0, stream>>>(129);
    k_scan3<<<129, 256, 0, stream>>>();
    k_scatter<<<NE / 256, 256, 0, stream>>>(b_scope);
    k_mid<<<1153, 256, 0, stream>>>(scope_lig, scope_up, see);

    // iter 0 (streaming, fully fused)
    k_attend0<<<8193, 256, 0, stream>>>(fdg, rij, see);
    // iter 1
    k_attendG<2><<<8193, 256, 0, stream>>>();
    k_gemmB<<<1025, 256, 0, stream>>>(fc_W[1], fc_b[1]);
    // iter 2
    k_attendG<3><<<8193, 256, 0, stream>>>();
    k_gemmC<<<dim3(513, 3), 256, 0, stream>>>(fc_W[2], fc_b[2]);

    k_final<<<2048, 256, 0, stream>>>(l_scope, (float*)d_out);
}

// Round 16
// 260.534 us; speedup vs baseline: 1.6509x; 1.0269x over previous
//
#include <hip/hip_runtime.h>
#include <cstdint>
#include <cstddef>

#define NSEG 32769      // N_NODES + 1 (row 0 is the zero row)
#define NNODES 32768
#define NE 262144
#define PSZ ((size_t)NSEG * 64)   // one tf plane

using f4 = float4;

// ---------------- static device scratch (load-time zero-initialized) ----------------
__device__ ushort g_tfp[4 * PSZ];                 // planes 0..2 out cols (iter2), plane 3 h_orig
__device__ uint   g_pkA[PSZ];                     // (out0 | h)  after iter0
__device__ uint   g_pk01[PSZ];                    // (out0 | out1) after iter1 gemm
__device__ ushort g_msumh[(size_t)NSEG * 192];    // bf16 row-major (K width 192)
__device__ float  g_q[NSEG];
__device__ float  g_p0[3][NSEG];
__device__ float  g_p1[3][NSEG];
__device__ float  g_w2[3][256];                   // w2 = W @ a2 in [0,d); c = a2.b at [255]
__device__ float  g_wq10[10];                     // W_dist @ w2_0
__device__ float  g_cq;                           // b_dist.w2_0 + a0.b0
__device__ float  g_wc[640];                      // Wc = W_dist @ fc_W0 (10x64)
__device__ float  g_bcc[64];                      // b_dist @ fc_W0 + fc_b0
__device__ int    g_counts[NSEG];                 // zeroed by k_mid (prev call) / load
__device__ int    g_excl[NSEG];
__device__ int    g_bsum[1024];
__device__ int    g_rowptr[NSEG + 1];
__device__ int    g_cur[NSEG];                    // zeroed by k_mid (prev call) / load
__device__ int    g_csr[NE];
__device__ int    g_g1s[NE];                      // gather indices, CSR-sorted
__device__ int    g_g2s[NE];
__device__ float  g_pe1[NE];                      // p0[1][s0]+p1[1][s1], CSR-sorted
__device__ float  g_pe2[NE];                      // p0[2][s0]+p1[2][s1], CSR-sorted
__device__ int    g_bc[128];                      // zeroed by k_attend0 (prev call) / load
__device__ int    g_bcur[128];
__device__ int    g_sorder[NSEG];

#define WREDUCE(x) { x += __shfl_xor(x, 32); x += __shfl_xor(x, 16); \
                     x += __shfl_xor(x, 8);  x += __shfl_xor(x, 4);  \
                     x += __shfl_xor(x, 2);  x += __shfl_xor(x, 1); }
#define WREDMAX(x) { x = fmaxf(x, __shfl_xor(x, 32)); x = fmaxf(x, __shfl_xor(x, 16)); \
                     x = fmaxf(x, __shfl_xor(x, 8));  x = fmaxf(x, __shfl_xor(x, 4));  \
                     x = fmaxf(x, __shfl_xor(x, 2));  x = fmaxf(x, __shfl_xor(x, 1)); }

__device__ __forceinline__ ushort f2bf(float x) {
    uint u = __float_as_uint(x);
    u += 0x7FFF + ((u >> 16) & 1);
    return (ushort)(u >> 16);
}
__device__ __forceinline__ float bfs(ushort u) { return __uint_as_float(((uint)u) << 16); }
__device__ __forceinline__ float bflo(uint u) { return __uint_as_float(u << 16); }
__device__ __forceinline__ float bfhi(uint u) { return __uint_as_float(u & 0xFFFF0000u); }

// ===== k_front: emb 64-rows/block (0..512) | prep (513..517) | hist (518..1541) =====
__global__ __launch_bounds__(256) void k_front(
    const float* __restrict__ node_feats, const float* __restrict__ We,
    const float* __restrict__ be,
    const float* __restrict__ a0, const float* __restrict__ a1, const float* __restrict__ a2,
    const float* __restrict__ W0, const float* __restrict__ W1, const float* __restrict__ W2,
    const float* __restrict__ b0, const float* __restrict__ b1, const float* __restrict__ b2,
    const float* __restrict__ Wd, const float* __restrict__ bd,
    const int* __restrict__ bscope) {
    int tid = threadIdx.x;
    if (blockIdx.x < 513) {
        // ---- emb: 64 rows/block; h_orig (plane 3) + p0/p1 dots ----
        __shared__ float Ws[576];
        __shared__ float As6[6][68];
        __shared__ float fsAll[576];      // 64 rows x 9 feats
        __shared__ float hsAll[64][68];
        int r0 = blockIdx.x * 64;
        for (int i = tid; i < 576; i += 256) Ws[i] = We[i];
        for (int t = tid; t < 384; t += 256) {
            int vec = t >> 6, j = t & 63;
            const float* Av = (vec >> 1) == 0 ? a0 : ((vec >> 1) == 1 ? a1 : a2);
            As6[vec][j] = Av[((vec & 1) << 6) + j];
        }
        for (int t = tid; t < 576; t += 256) {
            int row = r0 + t / 9;
            float v = 0.f;
            if (row >= 1 && row <= NNODES) v = node_feats[(size_t)(row - 1) * 9 + (t % 9)];
            fsAll[t] = v;
        }
        __syncthreads();
        int j = tid & 63;
        float bj = be[j];
#pragma unroll 4
        for (int p = 0; p < 16; p++) {
            int lr = p * 4 + (tid >> 6);     // local row 0..63
            int row = r0 + lr;
            float acc = bj;
#pragma unroll
            for (int k = 0; k < 9; k++) acc += fsAll[lr * 9 + k] * Ws[k * 64 + j];
            float v = (row == 0 || row >= NSEG) ? 0.f : acc;
            if (row < NSEG) g_tfp[3 * PSZ + (size_t)row * 64 + j] = f2bf(v);
            hsAll[lr][j] = v;
        }
        __syncthreads();
        // 384 dots (64 rows x 6 vecs) x 8-lane groups = 3072 tasks / 256 thr = 12 iters
#pragma unroll
        for (int i = 0; i < 12; i++) {
            int task = i * 256 + tid;
            int d = task >> 3, g = tid & 7;
            int lr = d / 6, vec = d % 6;
            float s = 0.f;
#pragma unroll
            for (int jj = 0; jj < 8; jj++)
                s += hsAll[lr][g * 8 + jj] * As6[vec][g * 8 + jj];
            s += __shfl_xor(s, 1); s += __shfl_xor(s, 2); s += __shfl_xor(s, 4);
            int prow = r0 + lr;
            if (g == 0 && prow < NSEG) {
                int iv = vec >> 1;
                if ((vec & 1) == 0) g_p0[iv][prow] = s;
                else                g_p1[iv][prow] = s;
            }
        }
    } else if (blockIdx.x < 518) {
        int pb = blockIdx.x - 513;
        int k = tid;
        if (pb < 3) {
            int it = pb;
            const float* W = it == 0 ? W0 : (it == 1 ? W1 : W2);
            const float* a = it == 0 ? a0 : (it == 1 ? a1 : a2);
            const float* bias = it == 0 ? b0 : (it == 1 ? b1 : b2);
            int d = 64 * (it + 1);
            if (k < d) {
                float s = 0.f;
                for (int jj = 0; jj < d; jj++) s += W[(size_t)k * d + jj] * a[128 + jj];
                g_w2[it][k] = s;
            } else if (k == 255) {
                float c = 0.f;
                for (int jj = 0; jj < d; jj++) c += a[128 + jj] * bias[jj];
                g_w2[it][255] = c;
            }
        } else if (pb == 3) {
            __shared__ float w2s[64];
            if (k < 64) {
                float s = 0.f;
                for (int jj = 0; jj < 64; jj++) s += W0[(size_t)k * 64 + jj] * a0[128 + jj];
                w2s[k] = s;
            }
            __syncthreads();
            if (k < 10) {
                float s = 0.f;
                for (int jj = 0; jj < 64; jj++) s += Wd[(size_t)k * 64 + jj] * w2s[jj];
                g_wq10[k] = s;
            } else if (k == 64) {
                float s = 0.f, c = 0.f;
                for (int jj = 0; jj < 64; jj++) { s += bd[jj] * w2s[jj]; c += a0[128 + jj] * b0[jj]; }
                g_cq = s + c;
            }
        } else {
            for (int t = k; t < 640; t += 256) {
                int kk = t >> 6, jj = t & 63;
                float s = 0.f;
                for (int m = 0; m < 64; m++) s += Wd[kk * 64 + m] * W0[(size_t)m * 64 + jj];
                g_wc[t] = s;
            }
            if (k < 64) {
                float s = b0[k];
                for (int m = 0; m < 64; m++) s += bd[m] * W0[(size_t)m * 64 + k];
                g_bcc[k] = s;
            }
        }
    } else {
        // ---- hist (g_counts zeroed by previous call's k_mid / load-time) ----
        int e = (blockIdx.x - 518) * 256 + tid;
        if (e < NE) atomicAdd(&g_counts[bscope[e]], 1);
    }
}

// ---------------- scans ----------------
__global__ void k_scan1() {
    __shared__ int s[256];
    int t = threadIdx.x, i = blockIdx.x * 256 + t;
    int v = (i < NSEG) ? g_counts[i] : 0;
    s[t] = v; __syncthreads();
    for (int off = 1; off < 256; off <<= 1) {
        int tmp = (t >= off) ? s[t - off] : 0;
        __syncthreads();
        s[t] += tmp;
        __syncthreads();
    }
    if (i < NSEG) g_excl[i] = s[t] - v;
    if (t == 255) g_bsum[blockIdx.x] = s[255];
}

__global__ void k_scan2(int nb) {
    __shared__ int s[256];
    int t = threadIdx.x;
    int v = (t < nb) ? g_bsum[t] : 0;
    s[t] = v; __syncthreads();
    for (int off = 1; off < 256; off <<= 1) {
        int tmp = (t >= off) ? s[t - off] : 0;
        __syncthreads();
        s[t] += tmp;
        __syncthreads();
    }
    if (t < nb) g_bsum[t] = s[t] - v;   // exclusive
}

// scan3 + fused bucket histogram (g_bc zeroed by previous call's k_attend0 / load)
__global__ void k_scan3() {
    __shared__ int lh[128];
    int t = threadIdx.x;
    if (t < 128) lh[t] = 0;
    __syncthreads();
    int i = blockIdx.x * 256 + t;
    if (i < NSEG) {
        g_rowptr[i] = g_excl[i] + g_bsum[i >> 8];
        int cnt = g_counts[i];
        atomicAdd(&lh[cnt > 127 ? 127 : cnt], 1);
    }
    if (i == NSEG) g_rowptr[NSEG] = NE;
    __syncthreads();
    if (t < 128 && lh[t]) atomicAdd(&g_bc[t], lh[t]);
}

__global__ void k_scatter(const int* __restrict__ bs) {
    int e = blockIdx.x * 256 + threadIdx.x;
    if (e < NE) {
        int seg = bs[e];
        int pos = g_rowptr[seg] + atomicAdd(&g_cur[seg], 1);
        g_csr[pos] = e;
    }
}

// ===== k_mid: bscatter (blocks 0..128, + counts/cur cleanup) | sortidx (129..1152) =====
__global__ __launch_bounds__(256) void k_mid(const int* __restrict__ g1,
                                             const int* __restrict__ g2,
                                             const int* __restrict__ see) {
    int tid = threadIdx.x;
    if (blockIdx.x < 129) {
        __shared__ int sc[128];
        __shared__ int lh[128];
        __shared__ int lbase[128];
        if (tid < 128) { sc[tid] = g_bc[tid]; lh[tid] = 0; }
        __syncthreads();
        for (int off = 1; off < 128; off <<= 1) {
            int tmp = (tid >= off && tid < 128) ? sc[tid - off] : 0;
            __syncthreads();
            if (tid < 128) sc[tid] += tmp;
            __syncthreads();
        }
        int seg = blockIdx.x * 256 + tid;
        int bin = 0, lpos = 0;
        bool valid = seg < NSEG;
        if (valid) {
            int cnt = g_rowptr[seg + 1] - g_rowptr[seg];
            bin = cnt > 127 ? 127 : cnt;
            lpos = atomicAdd(&lh[bin], 1);
        }
        __syncthreads();
        if (tid < 128 && lh[tid] > 0)
            lbase[tid] = atomicAdd(&g_bcur[tid], lh[tid]);
        __syncthreads();
        if (valid) {
            int bstart = sc[bin] - g_bc[bin];
            g_sorder[bstart + lbase[bin] + lpos] = seg;
            g_counts[seg] = 0;
            g_cur[seg] = 0;
        }
    } else {
        int pos = (blockIdx.x - 129) * 256 + tid;
        if (pos >= NE) return;
        int e = g_csr[pos];
        g_g1s[pos] = g1[e]; g_g2s[pos] = g2[e];
        int s0 = see[2 * (size_t)e], s1 = see[2 * (size_t)e + 1];
        g_pe1[pos] = g_p0[1][s0] + g_p1[1][s1];
        g_pe2[pos] = g_p0[2][s0] + g_p1[2][s1];
    }
}

// ===== fused attend0: gathers edge features directly, computes logit inline,
//       out0 = elu(y @ Wc + bcc), packs pkA=(out0|h), fused next-iter q =====
__global__ __launch_bounds__(256) void k_attend0(const float* __restrict__ fdg,
                                                 const float* __restrict__ rij,
                                                 const int* __restrict__ see) {
    __shared__ float Wcs[640];
    __shared__ float bcs[64];
    __shared__ float wqs[10];
    int tid = threadIdx.x;
    if (blockIdx.x == 0 && tid < 128) { g_bc[tid] = 0; g_bcur[tid] = 0; }  // cleanup
    for (int i = tid; i < 640; i += 256) Wcs[i] = g_wc[i];
    if (tid < 64) bcs[tid] = g_bcc[tid];
    if (tid < 10) wqs[tid] = g_wq10[tid];
    __syncthreads();
    float cq = g_cq;
    int lane = tid & 63;
    int sidx = blockIdx.x * 4 + (tid >> 6);
    if (sidx >= NSEG) return;
    int seg = g_sorder[sidx];
    int beg = g_rowptr[seg], end = g_rowptr[seg + 1];
    int cnt = end - beg;
    float y[10];
#pragma unroll
    for (int k = 0; k < 10; k++) y[k] = 0.f;

    if (cnt > 0 && cnt <= 64) {
        float l = -1e30f;
        float x[10];
#pragma unroll
        for (int k = 0; k < 10; k++) x[k] = 0.f;
        if (lane < cnt) {
            int e = g_csr[beg + lane];
#pragma unroll
            for (int k = 0; k < 9; k++) x[k] = fdg[(size_t)e * 9 + k];
            x[9] = rij[e];
            int s0 = see[2 * (size_t)e], s1 = see[2 * (size_t)e + 1];
            float q = cq;
#pragma unroll
            for (int k = 0; k < 10; k++) q += x[k] * wqs[k];
            l = q + g_p0[0][s0] + g_p1[0][s1];
            l = l > 0.f ? l : 0.2f * l;
        }
        float m = l;
        WREDMAX(m);
        float ex = (lane < cnt) ? __expf(l - m) : 0.f;
        float den = ex;
        WREDUCE(den);
        float w = ex / den;
#pragma unroll
        for (int k = 0; k < 10; k++) {
            float s = w * x[k];
            WREDUCE(s);
            y[k] = s;        // every lane holds the full y
        }
    } else if (cnt > 64) {
        float m = -1e30f;
        for (int t = beg + lane; t < end; t += 64) {
            int e = g_csr[t];
            float q = cq;
#pragma unroll
            for (int k = 0; k < 9; k++) q += fdg[(size_t)e * 9 + k] * wqs[k];
            q += rij[e] * wqs[9];
            float l = q + g_p0[0][see[2 * (size_t)e]] + g_p1[0][see[2 * (size_t)e + 1]];
            l = l > 0.f ? l : 0.2f * l;
            m = fmaxf(m, l);
        }
        WREDMAX(m);
        float den = 0.f;
        for (int t = beg + lane; t < end; t += 64) {
            int e = g_csr[t];
            float q = cq;
#pragma unroll
            for (int k = 0; k < 9; k++) q += fdg[(size_t)e * 9 + k] * wqs[k];
            q += rij[e] * wqs[9];
            float l = q + g_p0[0][see[2 * (size_t)e]] + g_p1[0][see[2 * (size_t)e + 1]];
            l = l > 0.f ? l : 0.2f * l;
            den += __expf(l - m);
        }
        WREDUCE(den);
        float rden = 1.f / den;
        float part[10];
#pragma unroll
        for (int k = 0; k < 10; k++) part[k] = 0.f;
        for (int t = beg + lane; t < end; t += 64) {
            int e = g_csr[t];
            float x[10];
#pragma unroll
            for (int k = 0; k < 9; k++) x[k] = fdg[(size_t)e * 9 + k];
            x[9] = rij[e];
            float q = cq;
#pragma unroll
            for (int k = 0; k < 10; k++) q += x[k] * wqs[k];
            float l = q + g_p0[0][see[2 * (size_t)e]] + g_p1[0][see[2 * (size_t)e + 1]];
            l = l > 0.f ? l : 0.2f * l;
            float w = __expf(l - m) * rden;
#pragma unroll
            for (int k = 0; k < 10; k++) part[k] += w * x[k];
        }
#pragma unroll
        for (int k = 0; k < 10; k++) {
            WREDUCE(part[k]);
            y[k] = part[k];
        }
    }
    float o = bcs[lane];
#pragma unroll
    for (int k = 0; k < 10; k++) o += y[k] * Wcs[k * 64 + lane];
    if (cnt == 0) o = 0.f;
    o = o > 0.f ? o : (__expf(o) - 1.f);
    ushort h = g_tfp[3 * PSZ + (size_t)seg * 64 + lane];
    g_pkA[(size_t)seg * 64 + lane] = (uint)f2bf(o) | ((uint)h << 16);
    float qp = o * g_w2[1][lane] + bfs(h) * g_w2[1][64 + lane];
    WREDUCE(qp);
    if (lane == 0) g_q[seg] = qp + g_w2[1][255];
}

// -------- attend iters 1/2: sorted index arrays, packed gathers --------
template <int NCM>
__global__ __launch_bounds__(256) void k_attendG() {
    const float* __restrict__ pe = (NCM == 2) ? g_pe1 : g_pe2;
    int lane = threadIdx.x & 63;
    int sidx = blockIdx.x * 4 + (threadIdx.x >> 6);
    if (sidx >= NSEG) return;
    int seg = g_sorder[sidx];
    int beg = g_rowptr[seg], end = g_rowptr[seg + 1];
    int cnt = end - beg;
    float acc[NCM];
#pragma unroll
    for (int c = 0; c < NCM; c++) acc[c] = 0.f;

    if (cnt > 0 && cnt <= 64) {
        float l = -1e30f;
        int i1 = 0, i2 = 0;
        if (lane < cnt) {
            i1 = g_g1s[beg + lane]; i2 = g_g2s[beg + lane];
            l = 0.5f * (g_q[i1] + g_q[i2]) + pe[beg + lane];
            l = l > 0.f ? l : 0.2f * l;
        }
        float m = l;
        WREDMAX(m);
        float ex = (lane < cnt) ? __expf(l - m) : 0.f;
        float den = ex;
        WREDUCE(den);
        float w = ex / den;
        for (int t0 = 0; t0 < cnt; t0 += 8) {
            float wt[8]; int a1[8], a2[8];
#pragma unroll
            for (int u = 0; u < 8; u++) {
                int su = t0 + u; su = su > 63 ? 63 : su;
                wt[u] = __shfl(w, su);
                a1[u] = __shfl(i1, su);
                a2[u] = __shfl(i2, su);
            }
            if (NCM == 2) {
                uint ua[8], ub[8];
#pragma unroll
                for (int u = 0; u < 8; u++) {
                    ua[u] = g_pkA[(size_t)a1[u] * 64 + lane];
                    ub[u] = g_pkA[(size_t)a2[u] * 64 + lane];
                }
#pragma unroll
                for (int u = 0; u < 8; u++) {
                    float wh = 0.5f * wt[u];
                    acc[0] += wh * (bflo(ua[u]) + bflo(ub[u]));
                    acc[1] += wh * (bfhi(ua[u]) + bfhi(ub[u]));
                }
            } else {
                uint ua[8], ub[8];
                ushort ha[8], hb[8];
#pragma unroll
                for (int u = 0; u < 8; u++) {
                    size_t b1 = (size_t)a1[u] * 64 + lane, b2 = (size_t)a2[u] * 64 + lane;
                    ua[u] = g_pk01[b1]; ub[u] = g_pk01[b2];
                    ha[u] = g_tfp[3 * PSZ + b1]; hb[u] = g_tfp[3 * PSZ + b2];
                }
#pragma unroll
                for (int u = 0; u < 8; u++) {
                    float wh = 0.5f * wt[u];
                    acc[0] += wh * (bflo(ua[u]) + bflo(ub[u]));
                    acc[1] += wh * (bfhi(ua[u]) + bfhi(ub[u]));
                    acc[2] += wh * (bfs(ha[u]) + bfs(hb[u]));
                }
            }
        }
    } else if (cnt > 64) {
        float m = -1e30f;
        for (int t = beg + lane; t < end; t += 64) {
            float l = 0.5f * (g_q[g_g1s[t]] + g_q[g_g2s[t]]) + pe[t];
            l = l > 0.f ? l : 0.2f * l;
            m = fmaxf(m, l);
        }
        WREDMAX(m);
        float den = 0.f;
        for (int t = beg + lane; t < end; t += 64) {
            float l = 0.5f * (g_q[g_g1s[t]] + g_q[g_g2s[t]]) + pe[t];
            l = l > 0.f ? l : 0.2f * l;
            den += __expf(l - m);
        }
        WREDUCE(den);
        float rden = 1.f / den;
        for (int t = beg; t < end; t++) {
            float l = 0.5f * (g_q[g_g1s[t]] + g_q[g_g2s[t]]) + pe[t];
            l = l > 0.f ? l : 0.2f * l;
            float w = __expf(l - m) * rden;
            float wh = 0.5f * w;
            size_t b1 = (size_t)g_g1s[t] * 64 + lane, b2 = (size_t)g_g2s[t] * 64 + lane;
            if (NCM == 3) {
                uint ua = g_pk01[b1], ub = g_pk01[b2];
                acc[0] += wh * (bflo(ua) + bflo(ub));
                acc[1] += wh * (bfhi(ua) + bfhi(ub));
                acc[2] += wh * (bfs(g_tfp[3 * PSZ + b1]) + bfs(g_tfp[3 * PSZ + b2]));
            } else {
                uint ua = g_pkA[b1], ub = g_pkA[b2];
                acc[0] += wh * (bflo(ua) + bflo(ub));
                acc[1] += wh * (bfhi(ua) + bfhi(ub));
            }
        }
    }
#pragma unroll
    for (int c = 0; c < NCM; c++)
        g_msumh[(size_t)seg * 192 + lane + 64 * c] = f2bf(acc[c]);
}

// ----- iter1 GEMM: 32x128 tiles, K=128; writes pk01=(out0|out1); fused q (w2[2]) -----
__global__ __launch_bounds__(256) void k_gemmB(const float* __restrict__ W,
                                               const float* __restrict__ bias) {
    __shared__ float As[32][36];
    __shared__ float Bs[32][132];
    int tid = threadIdx.x;
    int rb0 = blockIdx.x * 32;
    int ty = tid >> 4, tx = tid & 15;
    float aclo[2][4] = {{0.f,0.f,0.f,0.f},{0.f,0.f,0.f,0.f}};
    float achi[2][4] = {{0.f,0.f,0.f,0.f},{0.f,0.f,0.f,0.f}};
    for (int kk = 0; kk < 128; kk += 32) {
        {
            int row = tid & 31, k4 = (tid >> 5) * 4;
            uint2 u = make_uint2(0, 0);
            if (rb0 + row < NSEG)
                u = *(const uint2*)&g_msumh[(size_t)(rb0 + row) * 192 + kk + k4];
            As[k4 + 0][row] = bfs((ushort)(u.x & 0xFFFF));
            As[k4 + 1][row] = bfs((ushort)(u.x >> 16));
            As[k4 + 2][row] = bfs((ushort)(u.y & 0xFFFF));
            As[k4 + 3][row] = bfs((ushort)(u.y >> 16));
        }
        {
            int bk = tid >> 3, bc = (tid & 7) * 16;
#pragma unroll
            for (int q = 0; q < 4; q++)
                *(f4*)&Bs[bk][bc + q * 4] = *(const f4*)&W[(size_t)(kk + bk) * 128 + bc + q * 4];
        }
        __syncthreads();
#pragma unroll
        for (int k = 0; k < 32; k++) {
            float a0 = As[k][ty * 2], a1 = As[k][ty * 2 + 1];
            f4 bl = *(const f4*)&Bs[k][tx * 4];
            f4 bh = *(const f4*)&Bs[k][64 + tx * 4];
            aclo[0][0] += a0 * bl.x; aclo[0][1] += a0 * bl.y; aclo[0][2] += a0 * bl.z; aclo[0][3] += a0 * bl.w;
            aclo[1][0] += a1 * bl.x; aclo[1][1] += a1 * bl.y; aclo[1][2] += a1 * bl.z; aclo[1][3] += a1 * bl.w;
            achi[0][0] += a0 * bh.x; achi[0][1] += a0 * bh.y; achi[0][2] += a0 * bh.z; achi[0][3] += a0 * bh.w;
            achi[1][0] += a1 * bh.x; achi[1][1] += a1 * bh.y; achi[1][2] += a1 * bh.z; achi[1][3] += a1 * bh.w;
        }
        __syncthreads();
    }
#pragma unroll
    for (int r = 0; r < 2; r++) {
        int row = rb0 + ty * 2 + r;
        bool valid = row < NSEG;
        bool nonempty = valid && (g_rowptr[row + 1] > g_rowptr[row]);
        ushort4 h4 = make_ushort4(0, 0, 0, 0);
        if (valid) h4 = *(const ushort4*)&g_tfp[3 * PSZ + (size_t)row * 64 + tx * 4];
        const ushort hb[4] = {h4.x, h4.y, h4.z, h4.w};
        uint pk[4];
        float qp = 0.f;
#pragma unroll
        for (int j = 0; j < 4; j++) {
            float vl = aclo[r][j] + bias[tx * 4 + j];
            float vh = achi[r][j] + bias[64 + tx * 4 + j];
            if (!nonempty) { vl = 0.f; vh = 0.f; }
            vl = vl > 0.f ? vl : (__expf(vl) - 1.f);
            vh = vh > 0.f ? vh : (__expf(vh) - 1.f);
            pk[j] = (uint)f2bf(vl) | ((uint)f2bf(vh) << 16);
            qp += vl * g_w2[2][tx * 4 + j] + vh * g_w2[2][64 + tx * 4 + j] +
                  bfs(hb[j]) * g_w2[2][128 + tx * 4 + j];
        }
        if (valid) {
            uint4 o; o.x = pk[0]; o.y = pk[1]; o.z = pk[2]; o.w = pk[3];
            *(uint4*)&g_pk01[(size_t)row * 64 + tx * 4] = o;
        }
        qp += __shfl_xor(qp, 1); qp += __shfl_xor(qp, 2);
        qp += __shfl_xor(qp, 4); qp += __shfl_xor(qp, 8);
        if (valid && tx == 0) g_q[row] = qp + g_w2[2][255];
    }
}

// ----- iter2 GEMM (64x64 col-split tiles, K=192): plane cslot = mask*elu(msumh @ W + b) -----
__global__ __launch_bounds__(256) void k_gemmC(const float* __restrict__ W,
                                               const float* __restrict__ bias) {
    constexpr int D = 192;
    __shared__ float As[32][68];
    __shared__ float Bs[32][68];
    int tid = threadIdx.x;
    int rb0 = blockIdx.x * 64;
    int cslot = blockIdx.y;
    int cb0 = cslot * 64;
    int ty = tid >> 4, tx = tid & 15;
    float acc[4][4];
#pragma unroll
    for (int r = 0; r < 4; r++)
#pragma unroll
        for (int j = 0; j < 4; j++) acc[r][j] = 0.f;

    int arow = tid & 63, aoct = tid >> 6;
    int bk = tid >> 3, bc8 = (tid & 7) * 8;
    for (int kk = 0; kk < D; kk += 32) {
        {
            uint4 u = make_uint4(0, 0, 0, 0);
            if (rb0 + arow < NSEG)
                u = *(const uint4*)&g_msumh[(size_t)(rb0 + arow) * 192 + kk + aoct * 8];
            int kb = aoct * 8;
            As[kb + 0][arow] = bfs((ushort)(u.x & 0xFFFF));
            As[kb + 1][arow] = bfs((ushort)(u.x >> 16));
            As[kb + 2][arow] = bfs((ushort)(u.y & 0xFFFF));
            As[kb + 3][arow] = bfs((ushort)(u.y >> 16));
            As[kb + 4][arow] = bfs((ushort)(u.z & 0xFFFF));
            As[kb + 5][arow] = bfs((ushort)(u.z >> 16));
            As[kb + 6][arow] = bfs((ushort)(u.w & 0xFFFF));
            As[kb + 7][arow] = bfs((ushort)(u.w >> 16));
        }
        {
            f4 b0 = *(const f4*)&W[(size_t)(kk + bk) * D + cb0 + bc8];
            f4 b1 = *(const f4*)&W[(size_t)(kk + bk) * D + cb0 + bc8 + 4];
            *(f4*)&Bs[bk][bc8] = b0;
            *(f4*)&Bs[bk][bc8 + 4] = b1;
        }
        __syncthreads();
#pragma unroll
        for (int k = 0; k < 32; k++) {
            f4 a = *(const f4*)&As[k][ty * 4];
            f4 b = *(const f4*)&Bs[k][tx * 4];
            acc[0][0] += a.x * b.x; acc[0][1] += a.x * b.y; acc[0][2] += a.x * b.z; acc[0][3] += a.x * b.w;
            acc[1][0] += a.y * b.x; acc[1][1] += a.y * b.y; acc[1][2] += a.y * b.z; acc[1][3] += a.y * b.w;
            acc[2][0] += a.z * b.x; acc[2][1] += a.z * b.y; acc[2][2] += a.z * b.z; acc[2][3] += a.z * b.w;
            acc[3][0] += a.w * b.x; acc[3][1] += a.w * b.y; acc[3][2] += a.w * b.z; acc[3][3] += a.w * b.w;
        }
        __syncthreads();
    }
#pragma unroll
    for (int r = 0; r < 4; r++) {
        int row = rb0 + ty * 4 + r;
        if (row >= NSEG) continue;
        bool nonempty = g_rowptr[row + 1] > g_rowptr[row];
        ushort4 pk;
        ushort* p = (ushort*)&pk;
#pragma unroll
        for (int j = 0; j < 4; j++) {
            float v = acc[r][j] + bias[cb0 + tx * 4 + j];
            if (!nonempty) v = 0.f;
            v = v > 0.f ? v : (__expf(v) - 1.f);
            p[j] = f2bf(v);
        }
        *(ushort4*)&g_tfp[(size_t)cslot * PSZ + (size_t)row * 64 + tx * 4] = pk;
    }
}

// ---------------- final: per-molecule gather-sum ----------------
__global__ void k_final(const int* __restrict__ lscope, float* __restrict__ out) {
    __shared__ int idx[32];
    __shared__ float sm[4][256];
    int m = blockIdx.x, tid = threadIdx.x, w = tid >> 6, lane = tid & 63;
    if (tid < 32) idx[tid] = lscope[m * 32 + tid];
    __syncthreads();
    float a0 = 0.f, a1 = 0.f, a2 = 0.f, a3 = 0.f;
#pragma unroll
    for (int j = w * 8; j < w * 8 + 8; j++) {
        size_t base = (size_t)idx[j] * 64 + lane;
        a0 += bfs(g_tfp[base]);
        a1 += bfs(g_tfp[PSZ + base]);
        a2 += bfs(g_tfp[2 * PSZ + base]);
        a3 += bfs(g_tfp[3 * PSZ + base]);
    }
    sm[w][lane] = a0; sm[w][64 + lane] = a1; sm[w][128 + lane] = a2; sm[w][192 + lane] = a3;
    __syncthreads();
    out[(size_t)m * 256 + tid] = sm[0][tid] + sm[1][tid] + sm[2][tid] + sm[3][tid];
}

extern "C" void kernel_launch(void* const* d_in, const int* in_sizes, int n_in,
                              void* d_out, int out_size, void* d_ws, size_t ws_size,
                              hipStream_t stream) {
    const float* node_feats = (const float*)d_in[0];
    const float* fdg        = (const float*)d_in[1];
    const float* rij        = (const float*)d_in[2];
    const int*   see        = (const int*)d_in[3];
    const int*   b_scope    = (const int*)d_in[4];
    const int*   scope_up   = (const int*)d_in[5];
    const int*   scope_lig  = (const int*)d_in[6];
    const int*   l_scope    = (const int*)d_in[7];
    const float* W_emb      = (const float*)d_in[8];
    const float* b_emb      = (const float*)d_in[9];
    const float* W_dist     = (const float*)d_in[10];
    const float* b_dist     = (const float*)d_in[11];
    const float* fc_W[3]   = {(const float*)d_in[12], (const float*)d_in[15], (const float*)d_in[18]};
    const float* fc_b[3]   = {(const float*)d_in[13], (const float*)d_in[16], (const float*)d_in[19]};
    const float* attn_a[3] = {(const float*)d_in[14], (const float*)d_in[17], (const float*)d_in[20]};

    k_front<<<1542, 256, 0, stream>>>(node_feats, W_emb, b_emb,
                                      attn_a[0], attn_a[1], attn_a[2],
                                      fc_W[0], fc_W[1], fc_W[2],
                                      fc_b[0], fc_b[1], fc_b[2],
                                      W_dist, b_dist, b_scope);
    k_scan1<<<129, 256, 0, stream>>>();
    k_scan2<<<1, 256, 0, stream>>>(129);
    k_scan3<<<129, 256, 0, stream>>>();
    k_scatter<<<NE / 256, 256, 0, stream>>>(b_scope);
    k_mid<<<1153, 256, 0, stream>>>(scope_lig, scope_up, see);

    // iter 0 (streaming, fully fused)
    k_attend0<<<8193, 256, 0, stream>>>(fdg, rij, see);
    // iter 1
    k_attendG<2><<<8193, 256, 0, stream>>>();
    k_gemmB<<<1025, 256, 0, stream>>>(fc_W[1], fc_b[1]);
    // iter 2
    k_attendG<3><<<8193, 256, 0, stream>>>();
    k_gemmC<<<dim3(513, 3), 256, 0, stream>>>(fc_W[2], fc_b[2]);

    k_final<<<2048, 256, 0, stream>>>(l_scope, (float*)d_out);
}

// Round 17
// 207.778 us; speedup vs baseline: 2.0700x; 1.2539x over previous
//
#include <hip/hip_runtime.h>
#include <cstdint>
#include <cstddef>

#define NSEG 32769      // N_NODES + 1 (row 0 is the zero row)
#define NNODES 32768
#define NE 262144
#define PSZ ((size_t)NSEG * 64)   // one tf plane

using f4 = float4;
typedef __attribute__((ext_vector_type(8))) short bf16x8;
typedef __attribute__((ext_vector_type(4))) float f32x4;

// ---------------- static device scratch (load-time zero-initialized) ----------------
__device__ ushort g_tfp[4 * PSZ];                 // planes 0..2 out cols (iter2), plane 3 h_orig
__device__ uint   g_pkA[PSZ];                     // (out0 | h)  after iter0
__device__ uint   g_pk01[PSZ];                    // (out0 | out1) after iter1 gemm
__device__ ushort g_msumh[(size_t)NSEG * 192];    // bf16 row-major (K width 192)
__device__ float  g_q[NSEG];
__device__ float  g_p0[3][NSEG];
__device__ float  g_p1[3][NSEG];
__device__ float  g_w2[3][256];                   // w2 = W @ a2 in [0,d); c = a2.b at [255]
__device__ float  g_wq10[10];                     // W_dist @ w2_0
__device__ float  g_cq;                           // b_dist.w2_0 + a0.b0
__device__ float  g_wc[640];                      // Wc = W_dist @ fc_W0 (10x64)
__device__ float  g_bcc[64];                      // b_dist @ fc_W0 + fc_b0
__device__ ushort g_wbB[16384];                   // fc_W1 in MFMA B-frag layout (8nt x 4ks x 64l x 8)
__device__ ushort g_wbC[36864];                   // fc_W2 in MFMA B-frag layout (12nt x 6ks x 64l x 8)
__device__ int    g_counts[NSEG];                 // zeroed by k_mid (prev call) / load
__device__ int    g_excl[NSEG];
__device__ int    g_bsum[1024];
__device__ int    g_rowptr[NSEG + 1];
__device__ int    g_cur[NSEG];                    // zeroed by k_mid (prev call) / load
__device__ int    g_csr[NE];
__device__ int    g_g1s[NE];                      // gather indices, CSR-sorted
__device__ int    g_g2s[NE];
__device__ float  g_pe1[NE];                      // p0[1][s0]+p1[1][s1], CSR-sorted
__device__ float  g_pe2[NE];                      // p0[2][s0]+p1[2][s1], CSR-sorted
__device__ int    g_bc[128];                      // zeroed by k_gemmB (prev call) / load
__device__ int    g_bcur[128];
__device__ int    g_sorder[NSEG];

#define WREDUCE(x) { x += __shfl_xor(x, 32); x += __shfl_xor(x, 16); \
                     x += __shfl_xor(x, 8);  x += __shfl_xor(x, 4);  \
                     x += __shfl_xor(x, 2);  x += __shfl_xor(x, 1); }
#define WREDMAX(x) { x = fmaxf(x, __shfl_xor(x, 32)); x = fmaxf(x, __shfl_xor(x, 16)); \
                     x = fmaxf(x, __shfl_xor(x, 8));  x = fmaxf(x, __shfl_xor(x, 4));  \
                     x = fmaxf(x, __shfl_xor(x, 2));  x = fmaxf(x, __shfl_xor(x, 1)); }

__device__ __forceinline__ ushort f2bf(float x) {
    uint u = __float_as_uint(x);
    u += 0x7FFF + ((u >> 16) & 1);
    return (ushort)(u >> 16);
}
__device__ __forceinline__ float bfs(ushort u) { return __uint_as_float(((uint)u) << 16); }
__device__ __forceinline__ float bflo(uint u) { return __uint_as_float(u << 16); }
__device__ __forceinline__ float bfhi(uint u) { return __uint_as_float(u & 0xFFFF0000u); }

// ===== k_front: emb 64-rows/block (0..512) | prep (513..517) | fragB (518) |
//                fragC (519..520) | hist (521..1544) =====
__global__ __launch_bounds__(256) void k_front(
    const float* __restrict__ node_feats, const float* __restrict__ We,
    const float* __restrict__ be,
    const float* __restrict__ a0, const float* __restrict__ a1, const float* __restrict__ a2,
    const float* __restrict__ W0, const float* __restrict__ W1, const float* __restrict__ W2,
    const float* __restrict__ b0, const float* __restrict__ b1, const float* __restrict__ b2,
    const float* __restrict__ Wd, const float* __restrict__ bd,
    const int* __restrict__ bscope) {
    int tid = threadIdx.x;
    if (blockIdx.x < 513) {
        // ---- emb: 64 rows/block; h_orig (plane 3) + p0/p1 dots ----
        __shared__ float Ws[576];
        __shared__ float As6[6][68];
        __shared__ float fsAll[576];
        __shared__ float hsAll[64][68];
        int r0 = blockIdx.x * 64;
        for (int i = tid; i < 576; i += 256) Ws[i] = We[i];
        for (int t = tid; t < 384; t += 256) {
            int vec = t >> 6, j = t & 63;
            const float* Av = (vec >> 1) == 0 ? a0 : ((vec >> 1) == 1 ? a1 : a2);
            As6[vec][j] = Av[((vec & 1) << 6) + j];
        }
        for (int t = tid; t < 576; t += 256) {
            int row = r0 + t / 9;
            float v = 0.f;
            if (row >= 1 && row <= NNODES) v = node_feats[(size_t)(row - 1) * 9 + (t % 9)];
            fsAll[t] = v;
        }
        __syncthreads();
        int j = tid & 63;
        float bj = be[j];
#pragma unroll 4
        for (int p = 0; p < 16; p++) {
            int lr = p * 4 + (tid >> 6);
            int row = r0 + lr;
            float acc = bj;
#pragma unroll
            for (int k = 0; k < 9; k++) acc += fsAll[lr * 9 + k] * Ws[k * 64 + j];
            float v = (row == 0 || row >= NSEG) ? 0.f : acc;
            if (row < NSEG) g_tfp[3 * PSZ + (size_t)row * 64 + j] = f2bf(v);
            hsAll[lr][j] = v;
        }
        __syncthreads();
#pragma unroll
        for (int i = 0; i < 12; i++) {
            int task = i * 256 + tid;
            int d = task >> 3, g = tid & 7;
            int lr = d / 6, vec = d % 6;
            float s = 0.f;
#pragma unroll
            for (int jj = 0; jj < 8; jj++)
                s += hsAll[lr][g * 8 + jj] * As6[vec][g * 8 + jj];
            s += __shfl_xor(s, 1); s += __shfl_xor(s, 2); s += __shfl_xor(s, 4);
            int prow = r0 + lr;
            if (g == 0 && prow < NSEG) {
                int iv = vec >> 1;
                if ((vec & 1) == 0) g_p0[iv][prow] = s;
                else                g_p1[iv][prow] = s;
            }
        }
    } else if (blockIdx.x < 518) {
        int pb = blockIdx.x - 513;
        int k = tid;
        if (pb < 3) {
            int it = pb;
            const float* W = it == 0 ? W0 : (it == 1 ? W1 : W2);
            const float* a = it == 0 ? a0 : (it == 1 ? a1 : a2);
            const float* bias = it == 0 ? b0 : (it == 1 ? b1 : b2);
            int d = 64 * (it + 1);
            if (k < d) {
                float s = 0.f;
                for (int jj = 0; jj < d; jj++) s += W[(size_t)k * d + jj] * a[128 + jj];
                g_w2[it][k] = s;
            } else if (k == 255) {
                float c = 0.f;
                for (int jj = 0; jj < d; jj++) c += a[128 + jj] * bias[jj];
                g_w2[it][255] = c;
            }
        } else if (pb == 3) {
            __shared__ float w2s[64];
            if (k < 64) {
                float s = 0.f;
                for (int jj = 0; jj < 64; jj++) s += W0[(size_t)k * 64 + jj] * a0[128 + jj];
                w2s[k] = s;
            }
            __syncthreads();
            if (k < 10) {
                float s = 0.f;
                for (int jj = 0; jj < 64; jj++) s += Wd[(size_t)k * 64 + jj] * w2s[jj];
                g_wq10[k] = s;
            } else if (k == 64) {
                float s = 0.f, c = 0.f;
                for (int jj = 0; jj < 64; jj++) { s += bd[jj] * w2s[jj]; c += a0[128 + jj] * b0[jj]; }
                g_cq = s + c;
            }
        } else {
            for (int t = k; t < 640; t += 256) {
                int kk = t >> 6, jj = t & 63;
                float s = 0.f;
                for (int m = 0; m < 64; m++) s += Wd[kk * 64 + m] * W0[(size_t)m * 64 + jj];
                g_wc[t] = s;
            }
            if (k < 64) {
                float s = b0[k];
                for (int m = 0; m < 64; m++) s += bd[m] * W0[(size_t)m * 64 + k];
                g_bcc[k] = s;
            }
        }
    } else if (blockIdx.x == 518) {
        // fragB: W1 (128x128) -> MFMA B-frag layout. t = nt*256 + ks*64 + l
        for (int t = tid; t < 2048; t += 256) {
            int nt = t >> 8, ks = (t >> 6) & 3, l = t & 63;
            int n = nt * 16 + (l & 15);
            int kb = ks * 32 + ((l >> 4) << 3);
            ushort* dst = &g_wbB[(size_t)t * 8];
#pragma unroll
            for (int i = 0; i < 8; i++)
                dst[i] = f2bf(W1[(size_t)(kb + i) * 128 + n]);
        }
    } else if (blockIdx.x <= 520) {
        int half = blockIdx.x - 519;
        for (int t = tid; t < 2304; t += 256) {
            int nt = half * 6 + t / 384;
            int rem = t % 384;
            int ks = rem >> 6, l = rem & 63;
            int n = nt * 16 + (l & 15);
            int kb = ks * 32 + ((l >> 4) << 3);
            ushort* dst = &g_wbC[((size_t)(nt * 6 + ks) * 64 + l) * 8];
#pragma unroll
            for (int i = 0; i < 8; i++)
                dst[i] = f2bf(W2[(size_t)(kb + i) * 192 + n]);
        }
    } else {
        int e = (blockIdx.x - 521) * 256 + tid;
        if (e < NE) atomicAdd(&g_counts[bscope[e]], 1);
    }
}

// ---------------- scans ----------------
__global__ void k_scan1() {
    __shared__ int s[256];
    int t = threadIdx.x, i = blockIdx.x * 256 + t;
    int v = (i < NSEG) ? g_counts[i] : 0;
    s[t] = v; __syncthreads();
    for (int off = 1; off < 256; off <<= 1) {
        int tmp = (t >= off) ? s[t - off] : 0;
        __syncthreads();
        s[t] += tmp;
        __syncthreads();
    }
    if (i < NSEG) g_excl[i] = s[t] - v;
    if (t == 255) g_bsum[blockIdx.x] = s[255];
}

__global__ void k_scan2(int nb) {
    __shared__ int s[256];
    int t = threadIdx.x;
    int v = (t < nb) ? g_bsum[t] : 0;
    s[t] = v; __syncthreads();
    for (int off = 1; off < 256; off <<= 1) {
        int tmp = (t >= off) ? s[t - off] : 0;
        __syncthreads();
        s[t] += tmp;
        __syncthreads();
    }
    if (t < nb) g_bsum[t] = s[t] - v;   // exclusive
}

__global__ void k_scan3() {
    __shared__ int lh[128];
    int t = threadIdx.x;
    if (t < 128) lh[t] = 0;
    __syncthreads();
    int i = blockIdx.x * 256 + t;
    if (i < NSEG) {
        g_rowptr[i] = g_excl[i] + g_bsum[i >> 8];
        int cnt = g_counts[i];
        atomicAdd(&lh[cnt > 127 ? 127 : cnt], 1);
    }
    if (i == NSEG) g_rowptr[NSEG] = NE;
    __syncthreads();
    if (t < 128 && lh[t]) atomicAdd(&g_bc[t], lh[t]);
}

__global__ void k_scatter(const int* __restrict__ bs) {
    int e = blockIdx.x * 256 + threadIdx.x;
    if (e < NE) {
        int seg = bs[e];
        int pos = g_rowptr[seg] + atomicAdd(&g_cur[seg], 1);
        g_csr[pos] = e;
    }
}

// ===== k_mid: bscatter (0..128, + counts/cur cleanup) | sortidx (129..1152) |
//              attend0 unsorted (1153..9345) =====
__global__ __launch_bounds__(256) void k_mid(const int* __restrict__ g1,
                                             const int* __restrict__ g2,
                                             const int* __restrict__ see,
                                             const float* __restrict__ fdg,
                                             const float* __restrict__ rij) {
    int tid = threadIdx.x;
    if (blockIdx.x < 129) {
        __shared__ int sc[128];
        __shared__ int lh[128];
        __shared__ int lbase[128];
        if (tid < 128) { sc[tid] = g_bc[tid]; lh[tid] = 0; }
        __syncthreads();
        for (int off = 1; off < 128; off <<= 1) {
            int tmp = (tid >= off && tid < 128) ? sc[tid - off] : 0;
            __syncthreads();
            if (tid < 128) sc[tid] += tmp;
            __syncthreads();
        }
        int seg = blockIdx.x * 256 + tid;
        int bin = 0, lpos = 0;
        bool valid = seg < NSEG;
        if (valid) {
            int cnt = g_rowptr[seg + 1] - g_rowptr[seg];
            bin = cnt > 127 ? 127 : cnt;
            lpos = atomicAdd(&lh[bin], 1);
        }
        __syncthreads();
        if (tid < 128 && lh[tid] > 0)
            lbase[tid] = atomicAdd(&g_bcur[tid], lh[tid]);
        __syncthreads();
        if (valid) {
            int bstart = sc[bin] - g_bc[bin];
            g_sorder[bstart + lbase[bin] + lpos] = seg;
            g_counts[seg] = 0;
            g_cur[seg] = 0;
        }
    } else if (blockIdx.x < 1153) {
        int pos = (blockIdx.x - 129) * 256 + tid;
        if (pos >= NE) return;
        int e = g_csr[pos];
        g_g1s[pos] = g1[e]; g_g2s[pos] = g2[e];
        int s0 = see[2 * (size_t)e], s1 = see[2 * (size_t)e + 1];
        g_pe1[pos] = g_p0[1][s0] + g_p1[1][s1];
        g_pe2[pos] = g_p0[2][s0] + g_p1[2][s1];
    } else {
        // ---- attend0 (unsorted): softmax over edge feats, out0 = elu(y@Wc+bcc),
        //      pack pkA=(out0|h), fused next-iter q ----
        __shared__ float Wcs[640];
        __shared__ float bcs[64];
        __shared__ float wqs[10];
        for (int i = tid; i < 640; i += 256) Wcs[i] = g_wc[i];
        if (tid < 64) bcs[tid] = g_bcc[tid];
        if (tid < 10) wqs[tid] = g_wq10[tid];
        __syncthreads();
        float cq = g_cq;
        int lane = tid & 63;
        int seg = (blockIdx.x - 1153) * 4 + (tid >> 6);
        if (seg >= NSEG) return;
        int beg = g_rowptr[seg], end = g_rowptr[seg + 1];
        int cnt = end - beg;
        float y[10];
#pragma unroll
        for (int k = 0; k < 10; k++) y[k] = 0.f;

        if (cnt > 0 && cnt <= 64) {
            float l = -1e30f;
            float x[10];
#pragma unroll
            for (int k = 0; k < 10; k++) x[k] = 0.f;
            if (lane < cnt) {
                int e = g_csr[beg + lane];
#pragma unroll
                for (int k = 0; k < 9; k++) x[k] = fdg[(size_t)e * 9 + k];
                x[9] = rij[e];
                int s0 = see[2 * (size_t)e], s1 = see[2 * (size_t)e + 1];
                float q = cq;
#pragma unroll
                for (int k = 0; k < 10; k++) q += x[k] * wqs[k];
                l = q + g_p0[0][s0] + g_p1[0][s1];
                l = l > 0.f ? l : 0.2f * l;
            }
            float m = l;
            WREDMAX(m);
            float ex = (lane < cnt) ? __expf(l - m) : 0.f;
            float den = ex;
            WREDUCE(den);
            float w = ex / den;
#pragma unroll
            for (int k = 0; k < 10; k++) {
                float s = w * x[k];
                WREDUCE(s);
                y[k] = s;
            }
        } else if (cnt > 64) {
            float m = -1e30f;
            for (int t = beg + lane; t < end; t += 64) {
                int e = g_csr[t];
                float q = cq;
#pragma unroll
                for (int k = 0; k < 9; k++) q += fdg[(size_t)e * 9 + k] * wqs[k];
                q += rij[e] * wqs[9];
                float l = q + g_p0[0][see[2 * (size_t)e]] + g_p1[0][see[2 * (size_t)e + 1]];
                l = l > 0.f ? l : 0.2f * l;
                m = fmaxf(m, l);
            }
            WREDMAX(m);
            float den = 0.f;
            for (int t = beg + lane; t < end; t += 64) {
                int e = g_csr[t];
                float q = cq;
#pragma unroll
                for (int k = 0; k < 9; k++) q += fdg[(size_t)e * 9 + k] * wqs[k];
                q += rij[e] * wqs[9];
                float l = q + g_p0[0][see[2 * (size_t)e]] + g_p1[0][see[2 * (size_t)e + 1]];
                l = l > 0.f ? l : 0.2f * l;
                den += __expf(l - m);
            }
            WREDUCE(den);
            float rden = 1.f / den;
            float part[10];
#pragma unroll
            for (int k = 0; k < 10; k++) part[k] = 0.f;
            for (int t = beg + lane; t < end; t += 64) {
                int e = g_csr[t];
                float x[10];
#pragma unroll
                for (int k = 0; k < 9; k++) x[k] = fdg[(size_t)e * 9 + k];
                x[9] = rij[e];
                float q = cq;
#pragma unroll
                for (int k = 0; k < 10; k++) q += x[k] * wqs[k];
                float l = q + g_p0[0][see[2 * (size_t)e]] + g_p1[0][see[2 * (size_t)e + 1]];
                l = l > 0.f ? l : 0.2f * l;
                float w = __expf(l - m) * rden;
#pragma unroll
                for (int k = 0; k < 10; k++) part[k] += w * x[k];
            }
#pragma unroll
            for (int k = 0; k < 10; k++) {
                WREDUCE(part[k]);
                y[k] = part[k];
            }
        }
        float o = bcs[lane];
#pragma unroll
        for (int k = 0; k < 10; k++) o += y[k] * Wcs[k * 64 + lane];
        if (cnt == 0) o = 0.f;
        o = o > 0.f ? o : (__expf(o) - 1.f);
        ushort h = g_tfp[3 * PSZ + (size_t)seg * 64 + lane];
        g_pkA[(size_t)seg * 64 + lane] = (uint)f2bf(o) | ((uint)h << 16);
        float qp = o * g_w2[1][lane] + bfs(h) * g_w2[1][64 + lane];
        WREDUCE(qp);
        if (lane == 0) g_q[seg] = qp + g_w2[1][255];
    }
}

// -------- attend iters 1/2: sorted index arrays, packed gathers --------
template <int NCM>
__global__ __launch_bounds__(256) void k_attendG() {
    const float* __restrict__ pe = (NCM == 2) ? g_pe1 : g_pe2;
    int lane = threadIdx.x & 63;
    int sidx = blockIdx.x * 4 + (threadIdx.x >> 6);
    if (sidx >= NSEG) return;
    int seg = g_sorder[sidx];
    int beg = g_rowptr[seg], end = g_rowptr[seg + 1];
    int cnt = end - beg;
    float acc[NCM];
#pragma unroll
    for (int c = 0; c < NCM; c++) acc[c] = 0.f;

    if (cnt > 0 && cnt <= 64) {
        float l = -1e30f;
        int i1 = 0, i2 = 0;
        if (lane < cnt) {
            i1 = g_g1s[beg + lane]; i2 = g_g2s[beg + lane];
            l = 0.5f * (g_q[i1] + g_q[i2]) + pe[beg + lane];
            l = l > 0.f ? l : 0.2f * l;
        }
        float m = l;
        WREDMAX(m);
        float ex = (lane < cnt) ? __expf(l - m) : 0.f;
        float den = ex;
        WREDUCE(den);
        float w = ex / den;
        for (int t0 = 0; t0 < cnt; t0 += 8) {
            float wt[8]; int a1[8], a2[8];
#pragma unroll
            for (int u = 0; u < 8; u++) {
                int su = t0 + u; su = su > 63 ? 63 : su;
                wt[u] = __shfl(w, su);
                a1[u] = __shfl(i1, su);
                a2[u] = __shfl(i2, su);
            }
            if (NCM == 2) {
                uint ua[8], ub[8];
#pragma unroll
                for (int u = 0; u < 8; u++) {
                    ua[u] = g_pkA[(size_t)a1[u] * 64 + lane];
                    ub[u] = g_pkA[(size_t)a2[u] * 64 + lane];
                }
#pragma unroll
                for (int u = 0; u < 8; u++) {
                    float wh = 0.5f * wt[u];
                    acc[0] += wh * (bflo(ua[u]) + bflo(ub[u]));
                    acc[1] += wh * (bfhi(ua[u]) + bfhi(ub[u]));
                }
            } else {
                uint ua[8], ub[8];
                ushort ha[8], hb[8];
#pragma unroll
                for (int u = 0; u < 8; u++) {
                    size_t b1 = (size_t)a1[u] * 64 + lane, b2 = (size_t)a2[u] * 64 + lane;
                    ua[u] = g_pk01[b1]; ub[u] = g_pk01[b2];
                    ha[u] = g_tfp[3 * PSZ + b1]; hb[u] = g_tfp[3 * PSZ + b2];
                }
#pragma unroll
                for (int u = 0; u < 8; u++) {
                    float wh = 0.5f * wt[u];
                    acc[0] += wh * (bflo(ua[u]) + bflo(ub[u]));
                    acc[1] += wh * (bfhi(ua[u]) + bfhi(ub[u]));
                    acc[2] += wh * (bfs(ha[u]) + bfs(hb[u]));
                }
            }
        }
    } else if (cnt > 64) {
        float m = -1e30f;
        for (int t = beg + lane; t < end; t += 64) {
            float l = 0.5f * (g_q[g_g1s[t]] + g_q[g_g2s[t]]) + pe[t];
            l = l > 0.f ? l : 0.2f * l;
            m = fmaxf(m, l);
        }
        WREDMAX(m);
        float den = 0.f;
        for (int t = beg + lane; t < end; t += 64) {
            float l = 0.5f * (g_q[g_g1s[t]] + g_q[g_g2s[t]]) + pe[t];
            l = l > 0.f ? l : 0.2f * l;
            den += __expf(l - m);
        }
        WREDUCE(den);
        float rden = 1.f / den;
        for (int t = beg; t < end; t++) {
            float l = 0.5f * (g_q[g_g1s[t]] + g_q[g_g2s[t]]) + pe[t];
            l = l > 0.f ? l : 0.2f * l;
            float w = __expf(l - m) * rden;
            float wh = 0.5f * w;
            size_t b1 = (size_t)g_g1s[t] * 64 + lane, b2 = (size_t)g_g2s[t] * 64 + lane;
            if (NCM == 3) {
                uint ua = g_pk01[b1], ub = g_pk01[b2];
                acc[0] += wh * (bflo(ua) + bflo(ub));
                acc[1] += wh * (bfhi(ua) + bfhi(ub));
                acc[2] += wh * (bfs(g_tfp[3 * PSZ + b1]) + bfs(g_tfp[3 * PSZ + b2]));
            } else {
                uint ua = g_pkA[b1], ub = g_pkA[b2];
                acc[0] += wh * (bflo(ua) + bflo(ub));
                acc[1] += wh * (bfhi(ua) + bfhi(ub));
            }
        }
    }
#pragma unroll
    for (int c = 0; c < NCM; c++)
        g_msumh[(size_t)seg * 192 + lane + 64 * c] = f2bf(acc[c]);
}

// ----- iter1 GEMM (MFMA): 64 rows/block, 4 waves x (16 rows x 128 cols); K=128 -----
// writes pk01=(out0|out1); fused q (w2[2]); block 0 also cleans g_bc/g_bcur
__global__ __launch_bounds__(256) void k_gemmB(const float* __restrict__ bias) {
    int tid = threadIdx.x;
    if (blockIdx.x == 0 && tid < 128) { g_bc[tid] = 0; g_bcur[tid] = 0; }
    int w = tid >> 6, l = tid & 63;
    int lm = l & 15, lk = l >> 4;
    int r0 = blockIdx.x * 64 + w * 16;
    int arow = r0 + lm;
    size_t abase = (size_t)(arow < NSEG ? arow : 0) * 192;
    f32x4 acc[8];
#pragma unroll
    for (int nt = 0; nt < 8; nt++) acc[nt] = (f32x4){0.f, 0.f, 0.f, 0.f};
#pragma unroll
    for (int ks = 0; ks < 4; ks++) {
        bf16x8 af = *(const bf16x8*)&g_msumh[abase + ks * 32 + lk * 8];
#pragma unroll
        for (int nt = 0; nt < 8; nt++) {
            bf16x8 bf = *(const bf16x8*)&g_wbB[((size_t)(nt * 4 + ks) * 64 + l) * 8];
            acc[nt] = __builtin_amdgcn_mfma_f32_16x16x32_bf16(af, bf, acc[nt], 0, 0, 0);
        }
    }
#pragma unroll
    for (int j = 0; j < 4; j++) {
        int row = r0 + lk * 4 + j;
        bool valid = row < NSEG;
        int rr = valid ? row : 0;
        bool nonempty = valid && (g_rowptr[row + 1] > g_rowptr[row]);
        float qp = 0.f;
#pragma unroll
        for (int nt = 0; nt < 4; nt++) {
            int c = nt * 16 + lm;
            float vl = acc[nt][j] + bias[c];
            float vh = acc[nt + 4][j] + bias[64 + c];
            if (!nonempty) { vl = 0.f; vh = 0.f; }
            vl = vl > 0.f ? vl : (__expf(vl) - 1.f);
            vh = vh > 0.f ? vh : (__expf(vh) - 1.f);
            float hc = bfs(g_tfp[3 * PSZ + (size_t)rr * 64 + c]);
            if (valid) g_pk01[(size_t)row * 64 + c] = (uint)f2bf(vl) | ((uint)f2bf(vh) << 16);
            qp += vl * g_w2[2][c] + vh * g_w2[2][64 + c] + hc * g_w2[2][128 + c];
        }
        qp += __shfl_xor(qp, 1); qp += __shfl_xor(qp, 2);
        qp += __shfl_xor(qp, 4); qp += __shfl_xor(qp, 8);
        if (valid && lm == 0) g_q[row] = qp + g_w2[2][255];
    }
}

// ----- iter2 GEMM (MFMA): 64 rows/block, 4 waves x (16 rows x 192 cols); K=192 -----
__global__ __launch_bounds__(256) void k_gemmC(const float* __restrict__ bias) {
    int tid = threadIdx.x;
    int w = tid >> 6, l = tid & 63;
    int lm = l & 15, lk = l >> 4;
    int r0 = blockIdx.x * 64 + w * 16;
    int arow = r0 + lm;
    size_t abase = (size_t)(arow < NSEG ? arow : 0) * 192;
    f32x4 acc[12];
#pragma unroll
    for (int nt = 0; nt < 12; nt++) acc[nt] = (f32x4){0.f, 0.f, 0.f, 0.f};
#pragma unroll
    for (int ks = 0; ks < 6; ks++) {
        bf16x8 af = *(const bf16x8*)&g_msumh[abase + ks * 32 + lk * 8];
#pragma unroll
        for (int nt = 0; nt < 12; nt++) {
            bf16x8 bf = *(const bf16x8*)&g_wbC[((size_t)(nt * 6 + ks) * 64 + l) * 8];
            acc[nt] = __builtin_amdgcn_mfma_f32_16x16x32_bf16(af, bf, acc[nt], 0, 0, 0);
        }
    }
#pragma unroll
    for (int j = 0; j < 4; j++) {
        int row = r0 + lk * 4 + j;
        if (row >= NSEG) continue;
        bool nonempty = g_rowptr[row + 1] > g_rowptr[row];
#pragma unroll
        for (int nt = 0; nt < 12; nt++) {
            int col = nt * 16 + lm;
            float v = acc[nt][j] + bias[col];
            if (!nonempty) v = 0.f;
            v = v > 0.f ? v : (__expf(v) - 1.f);
            int plane = nt >> 2, c = col & 63;
            g_tfp[(size_t)plane * PSZ + (size_t)row * 64 + c] = f2bf(v);
        }
    }
}

// ---------------- final: per-molecule gather-sum ----------------
__global__ void k_final(const int* __restrict__ lscope, float* __restrict__ out) {
    __shared__ int idx[32];
    __shared__ float sm[4][256];
    int m = blockIdx.x, tid = threadIdx.x, w = tid >> 6, lane = tid & 63;
    if (tid < 32) idx[tid] = lscope[m * 32 + tid];
    __syncthreads();
    float a0 = 0.f, a1 = 0.f, a2 = 0.f, a3 = 0.f;
#pragma unroll
    for (int j = w * 8; j < w * 8 + 8; j++) {
        size_t base = (size_t)idx[j] * 64 + lane;
        a0 += bfs(g_tfp[base]);
        a1 += bfs(g_tfp[PSZ + base]);
        a2 += bfs(g_tfp[2 * PSZ + base]);
        a3 += bfs(g_tfp[3 * PSZ + base]);
    }
    sm[w][lane] = a0; sm[w][64 + lane] = a1; sm[w][128 + lane] = a2; sm[w][192 + lane] = a3;
    __syncthreads();
    out[(size_t)m * 256 + tid] = sm[0][tid] + sm[1][tid] + sm[2][tid] + sm[3][tid];
}

extern "C" void kernel_launch(void* const* d_in, const int* in_sizes, int n_in,
                              void* d_out, int out_size, void* d_ws, size_t ws_size,
                              hipStream_t stream) {
    const float* node_feats = (const float*)d_in[0];
    const float* fdg        = (const float*)d_in[1];
    const float* rij        = (const float*)d_in[2];
    const int*   see        = (const int*)d_in[3];
    const int*   b_scope    = (const int*)d_in[4];
    const int*   scope_up   = (const int*)d_in[5];
    const int*   scope_lig  = (const int*)d_in[6];
    const int*   l_scope    = (const int*)d_in[7];
    const float* W_emb      = (const float*)d_in[8];
    const float* b_emb      = (const float*)d_in[9];
    const float* W_dist     = (const float*)d_in[10];
    const float* b_dist     = (const float*)d_in[11];
    const float* fc_W[3]   = {(const float*)d_in[12], (const float*)d_in[15], (const float*)d_in[18]};
    const float* fc_b[3]   = {(const float*)d_in[13], (const float*)d_in[16], (const float*)d_in[19]};
    const float* attn_a[3] = {(const float*)d_in[14], (const float*)d_in[17], (const float*)d_in[20]};

    k_front<<<1545, 256, 0, stream>>>(node_feats, W_emb, b_emb,
                                      attn_a[0], attn_a[1], attn_a[2],
                                      fc_W[0], fc_W[1], fc_W[2],
                                      fc_b[0], fc_b[1], fc_b[2],
                                      W_dist, b_dist, b_scope);
    k_scan1<<<129, 256, 0, stream>>>();
    k_scan2<<<1, 256, 0, stream>>>(129);
    k_scan3<<<129, 256, 0, stream>>>();
    k_scatter<<<NE / 256, 256, 0, stream>>>(b_scope);
    k_mid<<<9346, 256, 0, stream>>>(scope_lig, scope_up, see, fdg, rij);

    // iter 1
    k_attendG<2><<<8193, 256, 0, stream>>>();
    k_gemmB<<<513, 256, 0, stream>>>(fc_b[1]);
    // iter 2
    k_attendG<3><<<8193, 256, 0, stream>>>();
    k_gemmC<<<513, 256, 0, stream>>>(fc_b[2]);

    k_final<<<2048, 256, 0, stream>>>(l_scope, (float*)d_out);
}

// Round 18
// 203.944 us; speedup vs baseline: 2.1089x; 1.0188x over previous
//
#include <hip/hip_runtime.h>
#include <cstdint>
#include <cstddef>

#define NSEG 32769      // N_NODES + 1 (row 0 is the zero row)
#define NNODES 32768
#define NE 262144
#define PSZ ((size_t)NSEG * 64)   // one tf plane

using f4 = float4;
typedef __attribute__((ext_vector_type(8))) short bf16x8;
typedef __attribute__((ext_vector_type(4))) float f32x4;

// ---------------- static device scratch (load-time zero-initialized) ----------------
__device__ ushort g_tfp[4 * PSZ];                 // planes 0..2 out cols (iter2), plane 3 h_orig
__device__ uint   g_pkA[PSZ];                     // (out0 | h)  after iter0
__device__ uint   g_pk01[PSZ];                    // (out0 | out1) after iter1 gemm
__device__ ushort g_msumh[(size_t)NSEG * 192];    // bf16 row-major (K width 192)
__device__ float  g_q[NSEG];
__device__ float  g_p0[3][NSEG];
__device__ float  g_p1[3][NSEG];
__device__ float  g_w2[3][256];                   // w2 = W @ a2 in [0,d); c = a2.b at [255]
__device__ float  g_wq10[10];                     // W_dist @ w2_0
__device__ float  g_cq;                           // b_dist.w2_0 + a0.b0
__device__ float  g_wc[640];                      // Wc = W_dist @ fc_W0 (10x64)
__device__ float  g_bcc[64];                      // b_dist @ fc_W0 + fc_b0
__device__ ushort g_wbB[16384];                   // fc_W1 in MFMA B-frag layout
__device__ ushort g_wbC[36864];                   // fc_W2 in MFMA B-frag layout
__device__ f4     g_rec[(size_t)NE * 4];          // per-edge: {x0..3}{x4..7}{x8,x9,lb0,_}{pe1,pe2,g1,g2}
__device__ int    g_counts[NSEG];                 // zeroed by k_mid (prev call) / load
__device__ int    g_excl[NSEG];
__device__ int    g_bsum[1024];
__device__ int    g_rowptr[NSEG + 1];
__device__ int    g_cur[NSEG];                    // zeroed by k_mid (prev call) / load
__device__ int    g_csr[NE];
__device__ int    g_g1s[NE];                      // gather indices, CSR-sorted
__device__ int    g_g2s[NE];
__device__ float  g_pe1[NE];                      // p0[1][s0]+p1[1][s1], CSR-sorted
__device__ float  g_pe2[NE];                      // p0[2][s0]+p1[2][s1], CSR-sorted
__device__ int    g_bc[128];                      // zeroed by k_gemmB (prev call) / load
__device__ int    g_bcur[128];
__device__ int    g_sorder[NSEG];

#define WREDUCE(x) { x += __shfl_xor(x, 32); x += __shfl_xor(x, 16); \
                     x += __shfl_xor(x, 8);  x += __shfl_xor(x, 4);  \
                     x += __shfl_xor(x, 2);  x += __shfl_xor(x, 1); }
#define WREDMAX(x) { x = fmaxf(x, __shfl_xor(x, 32)); x = fmaxf(x, __shfl_xor(x, 16)); \
                     x = fmaxf(x, __shfl_xor(x, 8));  x = fmaxf(x, __shfl_xor(x, 4));  \
                     x = fmaxf(x, __shfl_xor(x, 2));  x = fmaxf(x, __shfl_xor(x, 1)); }

__device__ __forceinline__ ushort f2bf(float x) {
    uint u = __float_as_uint(x);
    u += 0x7FFF + ((u >> 16) & 1);
    return (ushort)(u >> 16);
}
__device__ __forceinline__ float bfs(ushort u) { return __uint_as_float(((uint)u) << 16); }
__device__ __forceinline__ float bflo(uint u) { return __uint_as_float(u << 16); }
__device__ __forceinline__ float bfhi(uint u) { return __uint_as_float(u & 0xFFFF0000u); }

// ===== k_front: emb 64-rows/block (0..512) | prep (513..517) | fragB (518) |
//                fragC (519..520) | hist (521..1544) =====
__global__ __launch_bounds__(256) void k_front(
    const float* __restrict__ node_feats, const float* __restrict__ We,
    const float* __restrict__ be,
    const float* __restrict__ a0, const float* __restrict__ a1, const float* __restrict__ a2,
    const float* __restrict__ W0, const float* __restrict__ W1, const float* __restrict__ W2,
    const float* __restrict__ b0, const float* __restrict__ b1, const float* __restrict__ b2,
    const float* __restrict__ Wd, const float* __restrict__ bd,
    const int* __restrict__ bscope) {
    int tid = threadIdx.x;
    if (blockIdx.x < 513) {
        __shared__ float Ws[576];
        __shared__ float As6[6][68];
        __shared__ float fsAll[576];
        __shared__ float hsAll[64][68];
        int r0 = blockIdx.x * 64;
        for (int i = tid; i < 576; i += 256) Ws[i] = We[i];
        for (int t = tid; t < 384; t += 256) {
            int vec = t >> 6, j = t & 63;
            const float* Av = (vec >> 1) == 0 ? a0 : ((vec >> 1) == 1 ? a1 : a2);
            As6[vec][j] = Av[((vec & 1) << 6) + j];
        }
        for (int t = tid; t < 576; t += 256) {
            int row = r0 + t / 9;
            float v = 0.f;
            if (row >= 1 && row <= NNODES) v = node_feats[(size_t)(row - 1) * 9 + (t % 9)];
            fsAll[t] = v;
        }
        __syncthreads();
        int j = tid & 63;
        float bj = be[j];
#pragma unroll 4
        for (int p = 0; p < 16; p++) {
            int lr = p * 4 + (tid >> 6);
            int row = r0 + lr;
            float acc = bj;
#pragma unroll
            for (int k = 0; k < 9; k++) acc += fsAll[lr * 9 + k] * Ws[k * 64 + j];
            float v = (row == 0 || row >= NSEG) ? 0.f : acc;
            if (row < NSEG) g_tfp[3 * PSZ + (size_t)row * 64 + j] = f2bf(v);
            hsAll[lr][j] = v;
        }
        __syncthreads();
#pragma unroll
        for (int i = 0; i < 12; i++) {
            int task = i * 256 + tid;
            int d = task >> 3, g = tid & 7;
            int lr = d / 6, vec = d % 6;
            float s = 0.f;
#pragma unroll
            for (int jj = 0; jj < 8; jj++)
                s += hsAll[lr][g * 8 + jj] * As6[vec][g * 8 + jj];
            s += __shfl_xor(s, 1); s += __shfl_xor(s, 2); s += __shfl_xor(s, 4);
            int prow = r0 + lr;
            if (g == 0 && prow < NSEG) {
                int iv = vec >> 1;
                if ((vec & 1) == 0) g_p0[iv][prow] = s;
                else                g_p1[iv][prow] = s;
            }
        }
    } else if (blockIdx.x < 518) {
        int pb = blockIdx.x - 513;
        int k = tid;
        if (pb < 3) {
            int it = pb;
            const float* W = it == 0 ? W0 : (it == 1 ? W1 : W2);
            const float* a = it == 0 ? a0 : (it == 1 ? a1 : a2);
            const float* bias = it == 0 ? b0 : (it == 1 ? b1 : b2);
            int d = 64 * (it + 1);
            if (k < d) {
                float s = 0.f;
                for (int jj = 0; jj < d; jj++) s += W[(size_t)k * d + jj] * a[128 + jj];
                g_w2[it][k] = s;
            } else if (k == 255) {
                float c = 0.f;
                for (int jj = 0; jj < d; jj++) c += a[128 + jj] * bias[jj];
                g_w2[it][255] = c;
            }
        } else if (pb == 3) {
            __shared__ float w2s[64];
            if (k < 64) {
                float s = 0.f;
                for (int jj = 0; jj < 64; jj++) s += W0[(size_t)k * 64 + jj] * a0[128 + jj];
                w2s[k] = s;
            }
            __syncthreads();
            if (k < 10) {
                float s = 0.f;
                for (int jj = 0; jj < 64; jj++) s += Wd[(size_t)k * 64 + jj] * w2s[jj];
                g_wq10[k] = s;
            } else if (k == 64) {
                float s = 0.f, c = 0.f;
                for (int jj = 0; jj < 64; jj++) { s += bd[jj] * w2s[jj]; c += a0[128 + jj] * b0[jj]; }
                g_cq = s + c;
            }
        } else {
            for (int t = k; t < 640; t += 256) {
                int kk = t >> 6, jj = t & 63;
                float s = 0.f;
                for (int m = 0; m < 64; m++) s += Wd[kk * 64 + m] * W0[(size_t)m * 64 + jj];
                g_wc[t] = s;
            }
            if (k < 64) {
                float s = b0[k];
                for (int m = 0; m < 64; m++) s += bd[m] * W0[(size_t)m * 64 + k];
                g_bcc[k] = s;
            }
        }
    } else if (blockIdx.x == 518) {
        for (int t = tid; t < 2048; t += 256) {
            int nt = t >> 8, ks = (t >> 6) & 3, l = t & 63;
            int n = nt * 16 + (l & 15);
            int kb = ks * 32 + ((l >> 4) << 3);
            ushort* dst = &g_wbB[(size_t)t * 8];
#pragma unroll
            for (int i = 0; i < 8; i++)
                dst[i] = f2bf(W1[(size_t)(kb + i) * 128 + n]);
        }
    } else if (blockIdx.x <= 520) {
        int half = blockIdx.x - 519;
        for (int t = tid; t < 2304; t += 256) {
            int nt = half * 6 + t / 384;
            int rem = t % 384;
            int ks = rem >> 6, l = rem & 63;
            int n = nt * 16 + (l & 15);
            int kb = ks * 32 + ((l >> 4) << 3);
            ushort* dst = &g_wbC[((size_t)(nt * 6 + ks) * 64 + l) * 8];
#pragma unroll
            for (int i = 0; i < 8; i++)
                dst[i] = f2bf(W2[(size_t)(kb + i) * 192 + n]);
        }
    } else {
        int e = (blockIdx.x - 521) * 256 + tid;
        if (e < NE) atomicAdd(&g_counts[bscope[e]], 1);
    }
}

// ---------------- scans ----------------
__global__ void k_scan1() {
    __shared__ int s[256];
    int t = threadIdx.x, i = blockIdx.x * 256 + t;
    int v = (i < NSEG) ? g_counts[i] : 0;
    s[t] = v; __syncthreads();
    for (int off = 1; off < 256; off <<= 1) {
        int tmp = (t >= off) ? s[t - off] : 0;
        __syncthreads();
        s[t] += tmp;
        __syncthreads();
    }
    if (i < NSEG) g_excl[i] = s[t] - v;
    if (t == 255) g_bsum[blockIdx.x] = s[255];
}

__global__ void k_scan2(int nb) {
    __shared__ int s[256];
    int t = threadIdx.x;
    int v = (t < nb) ? g_bsum[t] : 0;
    s[t] = v; __syncthreads();
    for (int off = 1; off < 256; off <<= 1) {
        int tmp = (t >= off) ? s[t - off] : 0;
        __syncthreads();
        s[t] += tmp;
        __syncthreads();
    }
    if (t < nb) g_bsum[t] = s[t] - v;   // exclusive
}

__global__ void k_scan3() {
    __shared__ int lh[128];
    int t = threadIdx.x;
    if (t < 128) lh[t] = 0;
    __syncthreads();
    int i = blockIdx.x * 256 + t;
    if (i < NSEG) {
        g_rowptr[i] = g_excl[i] + g_bsum[i >> 8];
        int cnt = g_counts[i];
        atomicAdd(&lh[cnt > 127 ? 127 : cnt], 1);
    }
    if (i == NSEG) g_rowptr[NSEG] = NE;
    __syncthreads();
    if (t < 128 && lh[t]) atomicAdd(&g_bc[t], lh[t]);
}

// ---- scatter + per-edge 64B record build (coalesced reads, L2-resident gathers) ----
__global__ __launch_bounds__(256) void k_scatter(const int* __restrict__ bs,
                                                 const float* __restrict__ fdg,
                                                 const float* __restrict__ rij,
                                                 const int* __restrict__ see,
                                                 const int* __restrict__ g1,
                                                 const int* __restrict__ g2) {
    __shared__ float wqs[10];
    if (threadIdx.x < 10) wqs[threadIdx.x] = g_wq10[threadIdx.x];
    __syncthreads();
    int e = blockIdx.x * 256 + threadIdx.x;
    if (e >= NE) return;
    int seg = bs[e];
    int pos = g_rowptr[seg] + atomicAdd(&g_cur[seg], 1);
    g_csr[pos] = e;
    float x[10];
#pragma unroll
    for (int k = 0; k < 9; k++) x[k] = fdg[(size_t)e * 9 + k];
    x[9] = rij[e];
    int s0 = see[2 * (size_t)e], s1 = see[2 * (size_t)e + 1];
    float q = g_cq;
#pragma unroll
    for (int k = 0; k < 10; k++) q += x[k] * wqs[k];
    float lb0 = q + g_p0[0][s0] + g_p1[0][s1];
    float pe1 = g_p0[1][s0] + g_p1[1][s1];
    float pe2 = g_p0[2][s0] + g_p1[2][s1];
    size_t rb = (size_t)e * 4;
    g_rec[rb + 0] = make_float4(x[0], x[1], x[2], x[3]);
    g_rec[rb + 1] = make_float4(x[4], x[5], x[6], x[7]);
    g_rec[rb + 2] = make_float4(x[8], x[9], lb0, 0.f);
    g_rec[rb + 3] = make_float4(pe1, pe2, __int_as_float(g1[e]), __int_as_float(g2[e]));
}

// ===== k_mid: bscatter (0..128, + counts/cur cleanup) | sortidx (129..1152) |
//              attend0 unsorted (1153..9345) =====
__global__ __launch_bounds__(256) void k_mid() {
    int tid = threadIdx.x;
    if (blockIdx.x < 129) {
        __shared__ int sc[128];
        __shared__ int lh[128];
        __shared__ int lbase[128];
        if (tid < 128) { sc[tid] = g_bc[tid]; lh[tid] = 0; }
        __syncthreads();
        for (int off = 1; off < 128; off <<= 1) {
            int tmp = (tid >= off && tid < 128) ? sc[tid - off] : 0;
            __syncthreads();
            if (tid < 128) sc[tid] += tmp;
            __syncthreads();
        }
        int seg = blockIdx.x * 256 + tid;
        int bin = 0, lpos = 0;
        bool valid = seg < NSEG;
        if (valid) {
            int cnt = g_rowptr[seg + 1] - g_rowptr[seg];
            bin = cnt > 127 ? 127 : cnt;
            lpos = atomicAdd(&lh[bin], 1);
        }
        __syncthreads();
        if (tid < 128 && lh[tid] > 0)
            lbase[tid] = atomicAdd(&g_bcur[tid], lh[tid]);
        __syncthreads();
        if (valid) {
            int bstart = sc[bin] - g_bc[bin];
            g_sorder[bstart + lbase[bin] + lpos] = seg;
            g_counts[seg] = 0;
            g_cur[seg] = 0;
        }
    } else if (blockIdx.x < 1153) {
        int pos = (blockIdx.x - 129) * 256 + tid;
        if (pos >= NE) return;
        int e = g_csr[pos];
        f4 d = g_rec[(size_t)e * 4 + 3];
        g_pe1[pos] = d.x;
        g_pe2[pos] = d.y;
        g_g1s[pos] = __float_as_int(d.z);
        g_g2s[pos] = __float_as_int(d.w);
    } else {
        // ---- attend0 (unsorted): rec-based, softmax + out0 = elu(y@Wc+bcc) ----
        __shared__ float Wcs[640];
        __shared__ float bcs[64];
        for (int i = tid; i < 640; i += 256) Wcs[i] = g_wc[i];
        if (tid < 64) bcs[tid] = g_bcc[tid];
        __syncthreads();
        int lane = tid & 63;
        int seg = (blockIdx.x - 1153) * 4 + (tid >> 6);
        if (seg >= NSEG) return;
        int beg = g_rowptr[seg], end = g_rowptr[seg + 1];
        int cnt = end - beg;
        float y[10];
#pragma unroll
        for (int k = 0; k < 10; k++) y[k] = 0.f;

        if (cnt > 0 && cnt <= 64) {
            float l = -1e30f;
            float x[10];
#pragma unroll
            for (int k = 0; k < 10; k++) x[k] = 0.f;
            if (lane < cnt) {
                int e = g_csr[beg + lane];
                size_t rb = (size_t)e * 4;
                f4 r0 = g_rec[rb + 0];
                f4 r1 = g_rec[rb + 1];
                f4 r2 = g_rec[rb + 2];
                x[0] = r0.x; x[1] = r0.y; x[2] = r0.z; x[3] = r0.w;
                x[4] = r1.x; x[5] = r1.y; x[6] = r1.z; x[7] = r1.w;
                x[8] = r2.x; x[9] = r2.y;
                l = r2.z;
                l = l > 0.f ? l : 0.2f * l;
            }
            float m = l;
            WREDMAX(m);
            float ex = (lane < cnt) ? __expf(l - m) : 0.f;
            float den = ex;
            WREDUCE(den);
            float w = ex / den;
#pragma unroll
            for (int k = 0; k < 10; k++) {
                float s = w * x[k];
                WREDUCE(s);
                y[k] = s;
            }
        } else if (cnt > 64) {
            float m = -1e30f;
            for (int t = beg + lane; t < end; t += 64) {
                int e = g_csr[t];
                float l = g_rec[(size_t)e * 4 + 2].z;
                l = l > 0.f ? l : 0.2f * l;
                m = fmaxf(m, l);
            }
            WREDMAX(m);
            float den = 0.f;
            for (int t = beg + lane; t < end; t += 64) {
                int e = g_csr[t];
                float l = g_rec[(size_t)e * 4 + 2].z;
                l = l > 0.f ? l : 0.2f * l;
                den += __expf(l - m);
            }
            WREDUCE(den);
            float rden = 1.f / den;
            float part[10];
#pragma unroll
            for (int k = 0; k < 10; k++) part[k] = 0.f;
            for (int t = beg + lane; t < end; t += 64) {
                int e = g_csr[t];
                size_t rb = (size_t)e * 4;
                f4 r0 = g_rec[rb + 0];
                f4 r1 = g_rec[rb + 1];
                f4 r2 = g_rec[rb + 2];
                float l = r2.z;
                l = l > 0.f ? l : 0.2f * l;
                float w = __expf(l - m) * rden;
                part[0] += w * r0.x; part[1] += w * r0.y; part[2] += w * r0.z; part[3] += w * r0.w;
                part[4] += w * r1.x; part[5] += w * r1.y; part[6] += w * r1.z; part[7] += w * r1.w;
                part[8] += w * r2.x; part[9] += w * r2.y;
            }
#pragma unroll
            for (int k = 0; k < 10; k++) {
                WREDUCE(part[k]);
                y[k] = part[k];
            }
        }
        float o = bcs[lane];
#pragma unroll
        for (int k = 0; k < 10; k++) o += y[k] * Wcs[k * 64 + lane];
        if (cnt == 0) o = 0.f;
        o = o > 0.f ? o : (__expf(o) - 1.f);
        ushort h = g_tfp[3 * PSZ + (size_t)seg * 64 + lane];
        g_pkA[(size_t)seg * 64 + lane] = (uint)f2bf(o) | ((uint)h << 16);
        float qp = o * g_w2[1][lane] + bfs(h) * g_w2[1][64 + lane];
        WREDUCE(qp);
        if (lane == 0) g_q[seg] = qp + g_w2[1][255];
    }
}

// -------- attend iters 1/2: sorted index arrays, packed gathers --------
template <int NCM>
__global__ __launch_bounds__(256) void k_attendG() {
    const float* __restrict__ pe = (NCM == 2) ? g_pe1 : g_pe2;
    int lane = threadIdx.x & 63;
    int sidx = blockIdx.x * 4 + (threadIdx.x >> 6);
    if (sidx >= NSEG) return;
    int seg = g_sorder[sidx];
    int beg = g_rowptr[seg], end = g_rowptr[seg + 1];
    int cnt = end - beg;
    float acc[NCM];
#pragma unroll
    for (int c = 0; c < NCM; c++) acc[c] = 0.f;

    if (cnt > 0 && cnt <= 64) {
        float l = -1e30f;
        int i1 = 0, i2 = 0;
        if (lane < cnt) {
            i1 = g_g1s[beg + lane]; i2 = g_g2s[beg + lane];
            l = 0.5f * (g_q[i1] + g_q[i2]) + pe[beg + lane];
            l = l > 0.f ? l : 0.2f * l;
        }
        float m = l;
        WREDMAX(m);
        float ex = (lane < cnt) ? __expf(l - m) : 0.f;
        float den = ex;
        WREDUCE(den);
        float w = ex / den;
        for (int t0 = 0; t0 < cnt; t0 += 8) {
            float wt[8]; int a1[8], a2[8];
#pragma unroll
            for (int u = 0; u < 8; u++) {
                int su = t0 + u; su = su > 63 ? 63 : su;
                wt[u] = __shfl(w, su);
                a1[u] = __shfl(i1, su);
                a2[u] = __shfl(i2, su);
            }
            if (NCM == 2) {
                uint ua[8], ub[8];
#pragma unroll
                for (int u = 0; u < 8; u++) {
                    ua[u] = g_pkA[(size_t)a1[u] * 64 + lane];
                    ub[u] = g_pkA[(size_t)a2[u] * 64 + lane];
                }
#pragma unroll
                for (int u = 0; u < 8; u++) {
                    float wh = 0.5f * wt[u];
                    acc[0] += wh * (bflo(ua[u]) + bflo(ub[u]));
                    acc[1] += wh * (bfhi(ua[u]) + bfhi(ub[u]));
                }
            } else {
                uint ua[8], ub[8];
                ushort ha[8], hb[8];
#pragma unroll
                for (int u = 0; u < 8; u++) {
                    size_t b1 = (size_t)a1[u] * 64 + lane, b2 = (size_t)a2[u] * 64 + lane;
                    ua[u] = g_pk01[b1]; ub[u] = g_pk01[b2];
                    ha[u] = g_tfp[3 * PSZ + b1]; hb[u] = g_tfp[3 * PSZ + b2];
                }
#pragma unroll
                for (int u = 0; u < 8; u++) {
                    float wh = 0.5f * wt[u];
                    acc[0] += wh * (bflo(ua[u]) + bflo(ub[u]));
                    acc[1] += wh * (bfhi(ua[u]) + bfhi(ub[u]));
                    acc[2] += wh * (bfs(ha[u]) + bfs(hb[u]));
                }
            }
        }
    } else if (cnt > 64) {
        float m = -1e30f;
        for (int t = beg + lane; t < end; t += 64) {
            float l = 0.5f * (g_q[g_g1s[t]] + g_q[g_g2s[t]]) + pe[t];
            l = l > 0.f ? l : 0.2f * l;
            m = fmaxf(m, l);
        }
        WREDMAX(m);
        float den = 0.f;
        for (int t = beg + lane; t < end; t += 64) {
            float l = 0.5f * (g_q[g_g1s[t]] + g_q[g_g2s[t]]) + pe[t];
            l = l > 0.f ? l : 0.2f * l;
            den += __expf(l - m);
        }
        WREDUCE(den);
        float rden = 1.f / den;
        for (int t = beg; t < end; t++) {
            float l = 0.5f * (g_q[g_g1s[t]] + g_q[g_g2s[t]]) + pe[t];
            l = l > 0.f ? l : 0.2f * l;
            float w = __expf(l - m) * rden;
            float wh = 0.5f * w;
            size_t b1 = (size_t)g_g1s[t] * 64 + lane, b2 = (size_t)g_g2s[t] * 64 + lane;
            if (NCM == 3) {
                uint ua = g_pk01[b1], ub = g_pk01[b2];
                acc[0] += wh * (bflo(ua) + bflo(ub));
                acc[1] += wh * (bfhi(ua) + bfhi(ub));
                acc[2] += wh * (bfs(g_tfp[3 * PSZ + b1]) + bfs(g_tfp[3 * PSZ + b2]));
            } else {
                uint ua = g_pkA[b1], ub = g_pkA[b2];
                acc[0] += wh * (bflo(ua) + bflo(ub));
                acc[1] += wh * (bfhi(ua) + bfhi(ub));
            }
        }
    }
#pragma unroll
    for (int c = 0; c < NCM; c++)
        g_msumh[(size_t)seg * 192 + lane + 64 * c] = f2bf(acc[c]);
}

// ----- iter1 GEMM (MFMA): 64 rows/block, 4 waves x (16 rows x 128 cols); K=128 -----
__global__ __launch_bounds__(256) void k_gemmB(const float* __restrict__ bias) {
    int tid = threadIdx.x;
    if (blockIdx.x == 0 && tid < 128) { g_bc[tid] = 0; g_bcur[tid] = 0; }
    int w = tid >> 6, l = tid & 63;
    int lm = l & 15, lk = l >> 4;
    int r0 = blockIdx.x * 64 + w * 16;
    int arow = r0 + lm;
    size_t abase = (size_t)(arow < NSEG ? arow : 0) * 192;
    f32x4 acc[8];
#pragma unroll
    for (int nt = 0; nt < 8; nt++) acc[nt] = (f32x4){0.f, 0.f, 0.f, 0.f};
#pragma unroll
    for (int ks = 0; ks < 4; ks++) {
        bf16x8 af = *(const bf16x8*)&g_msumh[abase + ks * 32 + lk * 8];
#pragma unroll
        for (int nt = 0; nt < 8; nt++) {
            bf16x8 bf = *(const bf16x8*)&g_wbB[((size_t)(nt * 4 + ks) * 64 + l) * 8];
            acc[nt] = __builtin_amdgcn_mfma_f32_16x16x32_bf16(af, bf, acc[nt], 0, 0, 0);
        }
    }
#pragma unroll
    for (int j = 0; j < 4; j++) {
        int row = r0 + lk * 4 + j;
        bool valid = row < NSEG;
        int rr = valid ? row : 0;
        bool nonempty = valid && (g_rowptr[row + 1] > g_rowptr[row]);
        float qp = 0.f;
#pragma unroll
        for (int nt = 0; nt < 4; nt++) {
            int c = nt * 16 + lm;
            float vl = acc[nt][j] + bias[c];
            float vh = acc[nt + 4][j] + bias[64 + c];
            if (!nonempty) { vl = 0.f; vh = 0.f; }
            vl = vl > 0.f ? vl : (__expf(vl) - 1.f);
            vh = vh > 0.f ? vh : (__expf(vh) - 1.f);
            float hc = bfs(g_tfp[3 * PSZ + (size_t)rr * 64 + c]);
            if (valid) g_pk01[(size_t)row * 64 + c] = (uint)f2bf(vl) | ((uint)f2bf(vh) << 16);
            qp += vl * g_w2[2][c] + vh * g_w2[2][64 + c] + hc * g_w2[2][128 + c];
        }
        qp += __shfl_xor(qp, 1); qp += __shfl_xor(qp, 2);
        qp += __shfl_xor(qp, 4); qp += __shfl_xor(qp, 8);
        if (valid && lm == 0) g_q[row] = qp + g_w2[2][255];
    }
}

// ----- iter2 GEMM (MFMA): 64 rows/block, 4 waves x (16 rows x 192 cols); K=192 -----
__global__ __launch_bounds__(256) void k_gemmC(const float* __restrict__ bias) {
    int tid = threadIdx.x;
    int w = tid >> 6, l = tid & 63;
    int lm = l & 15, lk = l >> 4;
    int r0 = blockIdx.x * 64 + w * 16;
    int arow = r0 + lm;
    size_t abase = (size_t)(arow < NSEG ? arow : 0) * 192;
    f32x4 acc[12];
#pragma unroll
    for (int nt = 0; nt < 12; nt++) acc[nt] = (f32x4){0.f, 0.f, 0.f, 0.f};
#pragma unroll
    for (int ks = 0; ks < 6; ks++) {
        bf16x8 af = *(const bf16x8*)&g_msumh[abase + ks * 32 + lk * 8];
#pragma unroll
        for (int nt = 0; nt < 12; nt++) {
            bf16x8 bf = *(const bf16x8*)&g_wbC[((size_t)(nt * 6 + ks) * 64 + l) * 8];
            acc[nt] = __builtin_amdgcn_mfma_f32_16x16x32_bf16(af, bf, acc[nt], 0, 0, 0);
        }
    }
#pragma unroll
    for (int j = 0; j < 4; j++) {
        int row = r0 + lk * 4 + j;
        if (row >= NSEG) continue;
        bool nonempty = g_rowptr[row + 1] > g_rowptr[row];
#pragma unroll
        for (int nt = 0; nt < 12; nt++) {
            int col = nt * 16 + lm;
            float v = acc[nt][j] + bias[col];
            if (!nonempty) v = 0.f;
            v = v > 0.f ? v : (__expf(v) - 1.f);
            int plane = nt >> 2, c = col & 63;
            g_tfp[(size_t)plane * PSZ + (size_t)row * 64 + c] = f2bf(v);
        }
    }
}

// ---------------- final: per-molecule gather-sum ----------------
__global__ void k_final(const int* __restrict__ lscope, float* __restrict__ out) {
    __shared__ int idx[32];
    __shared__ float sm[4][256];
    int m = blockIdx.x, tid = threadIdx.x, w = tid >> 6, lane = tid & 63;
    if (tid < 32) idx[tid] = lscope[m * 32 + tid];
    __syncthreads();
    float a0 = 0.f, a1 = 0.f, a2 = 0.f, a3 = 0.f;
#pragma unroll
    for (int j = w * 8; j < w * 8 + 8; j++) {
        size_t base = (size_t)idx[j] * 64 + lane;
        a0 += bfs(g_tfp[base]);
        a1 += bfs(g_tfp[PSZ + base]);
        a2 += bfs(g_tfp[2 * PSZ + base]);
        a3 += bfs(g_tfp[3 * PSZ + base]);
    }
    sm[w][lane] = a0; sm[w][64 + lane] = a1; sm[w][128 + lane] = a2; sm[w][192 + lane] = a3;
    __syncthreads();
    out[(size_t)m * 256 + tid] = sm[0][tid] + sm[1][tid] + sm[2][tid] + sm[3][tid];
}

extern "C" void kernel_launch(void* const* d_in, const int* in_sizes, int n_in,
                              void* d_out, int out_size, void* d_ws, size_t ws_size,
                              hipStream_t stream) {
    const float* node_feats = (const float*)d_in[0];
    const float* fdg        = (const float*)d_in[1];
    const float* rij        = (const float*)d_in[2];
    const int*   see        = (const int*)d_in[3];
    const int*   b_scope    = (const int*)d_in[4];
    const int*   scope_up   = (const int*)d_in[5];
    const int*   scope_lig  = (const int*)d_in[6];
    const int*   l_scope    = (const int*)d_in[7];
    const float* W_emb      = (const float*)d_in[8];
    const float* b_emb      = (const float*)d_in[9];
    const float* W_dist     = (const float*)d_in[10];
    const float* b_dist     = (const float*)d_in[11];
    const float* fc_W[3]   = {(const float*)d_in[12], (const float*)d_in[15], (const float*)d_in[18]};
    const float* fc_b[3]   = {(const float*)d_in[13], (const float*)d_in[16], (const float*)d_in[19]};
    const float* attn_a[3] = {(const float*)d_in[14], (const float*)d_in[17], (const float*)d_in[20]};

    k_front<<<1545, 256, 0, stream>>>(node_feats, W_emb, b_emb,
                                      attn_a[0], attn_a[1], attn_a[2],
                                      fc_W[0], fc_W[1], fc_W[2],
                                      fc_b[0], fc_b[1], fc_b[2],
                                      W_dist, b_dist, b_scope);
    k_scan1<<<129, 256, 0, stream>>>();
    k_scan2<<<1, 256, 0, stream>>>(129);
    k_scan3<<<129, 256, 0, stream>>>();
    k_scatter<<<NE / 256, 256, 0, stream>>>(b_scope, fdg, rij, see, scope_lig, scope_up);
    k_mid<<<9346, 256, 0, stream>>>();

    // iter 1
    k_attendG<2><<<8193, 256, 0, stream>>>();
    k_gemmB<<<513, 256, 0, stream>>>(fc_b[1]);
    // iter 2
    k_attendG<3><<<8193, 256, 0, stream>>>();
    k_gemmC<<<513, 256, 0, stream>>>(fc_b[2]);

    k_final<<<2048, 256, 0, stream>>>(l_scope, (float*)d_out);
}